// Round 11
// baseline (510.207 us; speedup 1.0000x reference)
//
#include <hip/hip_runtime.h>
#include <hip/hip_bf16.h>

__device__ __forceinline__ float lrelu(float x){ return x >= 0.f ? x : 0.2f*x; }
__device__ __forceinline__ float sigm(float x){ return 1.f/(1.f+__expf(-x)); }

typedef short short8 __attribute__((ext_vector_type(8)));
typedef float f32x16 __attribute__((ext_vector_type(16)));

// ---------------- workspace layout (float offsets) ----------------
static constexpr size_t OFF_X0    = 0;          // 89*4096 = 364544
static constexpr size_t OFF_POS   = 475712;     // 16384  [h][i][d]
static constexpr size_t OFF_WQT   = 492096;     // 12288  [s][c][o]
static constexpr size_t OFF_STATS = 504384;     // stage1 single-slot sums (768)
static constexpr size_t OFF_P1    = 507456;     // P1PACK: 89*34*34*128 ushorts (ends 7,092,032)
static constexpr size_t OFF_P2    = 7092224;    // P2PACK: 89*18*18*128 ushorts (ends 8,937,728)
static constexpr size_t OFF_S3    = 8937728;    // BN3 sums: 8 slots * 768
static constexpr size_t OFF_S4    = 8943872;    // BN4 sums: 8 slots * 768
static constexpr size_t OFF_WH3   = 8950016;    // conv3 w hi  [9][och][cin]  (36864 ushorts)
static constexpr size_t OFF_WL3   = 8968448;
static constexpr size_t OFF_WH4   = 8986880;
static constexpr size_t OFF_WL4   = 9005312;    // ends 9,023,744
static constexpr size_t OFF_PBS   = 9023744;    // conv2 per-block stats [1424 slots][64 och][2] = 182,272
static constexpr size_t OFF_S2    = 9206016;    // BN2 group sums: 768 (atomic-accum, zeroed in prep)
static constexpr size_t OFF_RES   = 10714688;   // 89*64*256 (only imgs 64+ written/read)
static constexpr size_t OFF_MU    = 12172864;   // 320
static constexpr size_t OFF_COV   = 12173184;   // 5*64*64 (atomic-accumulated, zeroed in prep)
static constexpr size_t OFF_SIM   = 12193664;   // 64*5*256
static constexpr size_t OFF_R1    = 12275584;   // big overlaid region
static constexpr size_t OFF_PMM   = OFF_R1;                 // 89*64*16*32 pooled {16max|16min}
static constexpr size_t OFF_MHRAW = OFF_R1;                 // 89*64*256 final attn (PMM dead by then)
static constexpr size_t OFF_C3    = OFF_R1 + 5832704;       // 89*64*256 (raw conv3)
static constexpr size_t OFF_C4    = OFF_R1 + 8749056;       // 89*64*256 (raw conv4)
static constexpr size_t OFF_CKV   = OFF_R1 + 10207232;      // 89*4*256*48 (packed {k,q,v})
static constexpr size_t OFF_C3P   = OFF_R1 + 10207232;      // C3PACK overlays CKV (dead until proj)
static constexpr size_t OFF_QN    = OFF_R1 + 17543680;      // 64*64*256 (written by post_k)
static constexpr size_t OFF_WH    = OFF_R1 + 21737984;      // conv2 w hi [9][och][cin]
static constexpr size_t OFF_WL    = OFF_WH + 18432;         // conv2 w lo

__device__ __forceinline__ int bn_group(int img){ return (img < 64) ? 0 : (1 + (img-64)/5); }

__device__ __forceinline__ void bn_ab(const float* __restrict__ sums, int g, int c, float n,
                                      float gw, float bw, float& a, float& b)
{
    const float sum = sums[(g*64+c)*2], ss = sums[(g*64+c)*2+1];
    const float m = sum/n;
    const float var = fmaxf(ss/n - m*m, 0.f);
    const float istd = 1.f/sqrtf(var + 1e-5f);
    a = gw*istd;
    b = bw - m*a;
}

// 8-slot variant (slots stride 768): BN3/BN4 accumulated by conv16mfma_k
__device__ __forceinline__ void bn_ab_s8(const float* __restrict__ sums, int g, int c, float n,
                                         float gw, float bw, float& a, float& b)
{
    float sum = 0.f, ss = 0.f;
#pragma unroll
    for (int s=0;s<8;s++){
        sum += sums[s*768 + (g*64+c)*2];
        ss  += sums[s*768 + (g*64+c)*2 + 1];
    }
    const float m = sum/n;
    const float var = fmaxf(ss/n - m*m, 0.f);
    const float istd = 1.f/sqrtf(var + 1e-5f);
    a = gw*istd;
    b = bw - m*a;
}

// ---------------- prep ----------------
__global__ __launch_bounds__(256) void prep_k(const float* __restrict__ in1, const float* __restrict__ in2,
        const float* __restrict__ relh, const float* __restrict__ relw,
        const float* __restrict__ wq, const float* __restrict__ wk, const float* __restrict__ wv,
        const float* __restrict__ cw2, const float* __restrict__ cw3, const float* __restrict__ cw4,
        float* __restrict__ ws)
{
    int idx = blockIdx.x*256 + threadIdx.x;
    if (idx < 364544) { ws[OFF_X0+idx] = (idx < 262144 ? in1[idx] : in2[idx-262144]); return; }
    idx -= 364544;
    if (idx < 16384) {
        const int h = idx>>12, r = idx&4095, i = r>>4, d = r&15;
        ws[OFF_POS+idx] = relh[h*256 + d*16 + (i&15)] + relw[h*256 + d*16 + (i>>4)];
        return;
    }
    idx -= 16384;
    if (idx < 12288) {
        const int s = idx/4096, r = idx%4096, c = r>>6, o = r&63;
        const float* wp = (s==0)?wq:((s==1)?wk:wv);
        ws[OFF_WQT+idx] = wp[o*64 + c];   // [s][c][o] = W[o][c]
        return;
    }
    idx -= 12288;
    if (idx < 3072) { ws[OFF_STATS+idx] = 0.f; return; }   // stage1 sums
    idx -= 3072;
    if (idx < 20480) { ws[OFF_COV+idx] = 0.f; return; }    // zero cov
    idx -= 20480;
    if (idx < 12288) { ws[OFF_S3+idx] = 0.f; return; }     // BN3 + BN4 8-slot sums (contiguous)
    idx -= 12288;
    if (idx < 768) { ws[OFF_S2+idx] = 0.f; return; }       // BN2 sums (atomic-accumulated by bnred_k)
    idx -= 768;
    if (idx < 110592) {                                    // conv2/3/4 weights -> bf16 hi/lo [k9][och][cin]
        const int which = idx / 36864, r0 = idx - which*36864;
        const int och = r0/576, rr = r0%576, cin = rr/9, k9 = rr%9;
        const float* cwp = (which==0)?cw2:((which==1)?cw3:cw4);
        const float v = cwp[r0];
        __hip_bfloat16 hb = __float2bfloat16(v);
        const float hv = __bfloat162float(hb);
        __hip_bfloat16 lb = __float2bfloat16(v - hv);
        const size_t oh = (which==0)?OFF_WH:((which==1)?OFF_WH3:OFF_WH4);
        const size_t ol = (which==0)?OFF_WL:((which==1)?OFF_WL3:OFF_WL4);
        unsigned short* WH = (unsigned short*)(ws + oh);
        unsigned short* WL = (unsigned short*)(ws + ol);
        const int d = k9*4096 + och*64 + cin;
        WH[d] = *(unsigned short*)&hb;
        WL[d] = *(unsigned short*)&lb;
        return;
    }
    idx -= 110592;
    if (idx < 751872) {                                    // zero P1PACK halo: 89 imgs * 132 pos * 64 floats
        const int img = idx/8448, r = idx%8448;
        const int pos = r>>6, d = r&63;
        int ypad, xpad;
        if (pos < 68){ ypad = (pos<34)?0:33; xpad = (pos<34)?pos:(pos-34); }
        else { const int q = pos-68; ypad = 1 + (q>>1); xpad = (q&1)*33; }
        ws[OFF_P1 + (((size_t)img*34 + ypad)*34 + xpad)*64 + d] = 0.f;
        return;
    }
    idx -= 751872;
    if (idx < 387328) {                                    // zero P2PACK halo: 89 imgs * 68 pos * 64 floats
        const int img = idx/4352, r = idx%4352;
        const int pos = r>>6, d = r&63;
        int ypad, xpad;
        if (pos < 36){ ypad = (pos<18)?0:17; xpad = (pos<18)?pos:(pos-18); }
        else { const int q = pos-36; ypad = 1 + (q>>1); xpad = (q&1)*17; }
        ws[OFF_P2 + (((size_t)img*18 + ypad)*18 + xpad)*64 + d] = 0.f;
        return;
    }
    idx -= 387328;
    if (idx < 387328) {                                    // zero C3PACK halo
        const int img = idx/4352, r = idx%4352;
        const int pos = r>>6, d = r&63;
        int ypad, xpad;
        if (pos < 36){ ypad = (pos<18)?0:17; xpad = (pos<18)?pos:(pos-18); }
        else { const int q = pos-36; ypad = 1 + (q>>1); xpad = (q&1)*17; }
        ws[OFF_C3P + (((size_t)img*18 + ypad)*18 + xpad)*64 + d] = 0.f;
    }
}

// ---------------- direct 3x3 conv (fp32) — now only conv1 stats -------------------
template<int H, int W, int CIN, int CH, int OCB, int PT, bool STORE, bool INBN>
__global__ __launch_bounds__(256) void conv3x3_k(const float* __restrict__ in,
                                                 const float* __restrict__ wt,
                                                 float* __restrict__ out,
                                                 float* __restrict__ bnsum,
                                                 const float* __restrict__ isums,
                                                 const float* __restrict__ igw,
                                                 const float* __restrict__ ibw,
                                                 int ihw)
{
    constexpr int P = W + 1;
    constexpr int PLANE = H * P;
    constexpr int HW = H * W;
    constexpr int PASSES = HW / (256 * PT);
    constexpr int NLD = CH * HW / 256;
    __shared__ float lds[CH * PLANE];
    __shared__ float redS[OCB*4], redQ[OCB*4];
    __shared__ float abA[64], abB[64];
    const int img = blockIdx.x;
    const int och0 = blockIdx.y * OCB;
    const int t = threadIdx.x;

    if constexpr (INBN) {
        if (t < CIN) {
            const int gi = bn_group(img);
            const float nin = (float)(((gi==0)?64:5) * ihw);
            float a, b;
            bn_ab(isums, gi, t, nin, igw[t], ibw[t], a, b);
            abA[t]=a; abB[t]=b;
        }
        __syncthreads();
    }

    float acc[PASSES][OCB][PT];
#pragma unroll
    for (int a=0;a<PASSES;a++)
#pragma unroll
      for (int o=0;o<OCB;o++)
#pragma unroll
        for (int p=0;p<PT;p++) acc[a][o][p]=0.f;

    for (int idx = t; idx < CH*HW; idx += 256) {
        const int c = idx / HW, p = idx % HW;
        float v = in[((size_t)img*CIN + c)*HW + p];
        if constexpr (INBN) v = lrelu(abA[c]*v + abB[c]);
        lds[c*PLANE + (p/W)*P + (p%W)] = v;
    }
    __syncthreads();

    for (int cc0 = 0; cc0 < CIN; cc0 += CH) {
        float pre[(CIN > CH) ? NLD : 1];
        if constexpr (CIN > CH) {
            if (cc0 + CH < CIN) {
#pragma unroll
                for (int j=0;j<NLD;j++){
                    const int idx = j*256 + t;
                    const int c = idx / HW, p = idx % HW;
                    pre[j] = in[((size_t)img*CIN + cc0 + CH + c)*HW + p];
                }
            }
        }
        for (int c = 0; c < CH; ++c) {
            float wr[OCB][9];
#pragma unroll
            for (int o=0;o<OCB;o++)
#pragma unroll
              for (int k=0;k<9;k++)
                wr[o][k] = wt[((size_t)(och0+o)*CIN + (cc0+c))*9 + k];
            const float* Lc = lds + c*PLANE;
#pragma unroll
            for (int ps=0; ps<PASSES; ++ps) {
                const int px0 = (ps*256 + t)*PT;
                const int y = px0 / W, x0 = px0 % W;
#pragma unroll
                for (int ky=0; ky<3; ++ky) {
                    const int yy = y + ky - 1;
                    if (yy >= 0 && yy < H) {
                        const float* Lr = Lc + yy*P;
                        float r[PT+2];
                        r[0] = (x0 > 0) ? Lr[x0-1] : 0.f;
#pragma unroll
                        for (int k2=0;k2<PT;k2++) r[k2+1] = Lr[x0+k2];
                        r[PT+1] = (x0+PT < W) ? Lr[x0+PT] : 0.f;
#pragma unroll
                        for (int p=0;p<PT;p++)
#pragma unroll
                          for (int kx=0;kx<3;kx++) {
                              const float v = r[p+kx];
#pragma unroll
                              for (int o=0;o<OCB;o++)
                                  acc[ps][o][p] += v * wr[o][ky*3+kx];
                          }
                    }
                }
            }
        }
        if constexpr (CIN > CH) {
            if (cc0 + CH < CIN) {
                __syncthreads();
#pragma unroll
                for (int j=0;j<NLD;j++){
                    const int idx = j*256 + t;
                    const int c = idx / HW, p = idx % HW;
                    float v = pre[j];
                    if constexpr (INBN) v = lrelu(abA[cc0+CH+c]*v + abB[cc0+CH+c]);
                    lds[c*PLANE + (p/W)*P + (p%W)] = v;
                }
                __syncthreads();
            }
        }
    }
    if constexpr (STORE) {
#pragma unroll
        for (int ps=0; ps<PASSES; ++ps) {
            const int px0 = (ps*256 + t)*PT;
#pragma unroll
            for (int o=0;o<OCB;o++)
#pragma unroll
              for (int p=0;p<PT;p++)
                out[((size_t)img*64 + och0+o)*HW + px0 + p] = acc[ps][o][p];
        }
    }
    const int g = bn_group(img);
    const int wv = t >> 6;
#pragma unroll
    for (int o=0;o<OCB;o++){
        float s=0.f, ss=0.f;
#pragma unroll
        for (int ps=0;ps<PASSES;ps++)
#pragma unroll
          for (int p=0;p<PT;p++){ const float v=acc[ps][o][p]; s+=v; ss+=v*v; }
#pragma unroll
        for (int off=32; off>0; off>>=1){ s += __shfl_xor(s, off); ss += __shfl_xor(ss, off); }
        if ((t&63)==0){ redS[o*4+wv]=s; redQ[o*4+wv]=ss; }
    }
    __syncthreads();
    if (t < OCB*2){
        const int o = t>>1, metric = t&1;
        const float v = metric ? (redQ[o*4]+redQ[o*4+1]+redQ[o*4+2]+redQ[o*4+3])
                               : (redS[o*4]+redS[o*4+1]+redS[o*4+2]+redS[o*4+3]);
        atomicAdd(&bnsum[(g*64 + och0+o)*2 + metric], v);
    }
}

// ---------------- stage 1 fused: conv1+BN+lrelu+2x2 maxpool -> P1PACK ---------------------------
__global__ __launch_bounds__(256) void bnpoolconv1_k(const float* __restrict__ x0,
        const float* __restrict__ cw, const float* __restrict__ sums,
        const float* __restrict__ gw, const float* __restrict__ bw,
        unsigned short* __restrict__ p1p)
{
    __shared__ float xl[10*64];
    __shared__ float wsm[576];
    __shared__ float aAs[64], aBs[64];
    const int img = blockIdx.x, band = blockIdx.y, t = threadIdx.x;
    const int oy0 = band*4;
    const float* xp = x0 + (size_t)img*4096;
    for (int idx=t; idx<640; idx+=256){
        const int iy = idx>>6, ix = idx&63;
        const int gy = 2*oy0 - 1 + iy;
        xl[idx] = (gy>=0 && gy<64) ? xp[gy*64+ix] : 0.f;
    }
    const int g = bn_group(img);
    if (t < 64){
        const float n = (float)(((g==0)?64:5) * 4096);
        float a, b;
        bn_ab(sums, g, t, n, gw[t], bw[t], a, b);
        aAs[t]=a; aBs[t]=b;
    }
    for (int idx=t; idx<576; idx+=256) wsm[idx] = cw[idx];
    __syncthreads();
    const int p = t>>1, half = t&1;
    const int ly = p>>5, ox = p&31;
    float r[4][4];
#pragma unroll
    for (int dy=0;dy<4;dy++){
        const float* Lr = xl + (2*ly+dy)*64;
#pragma unroll
        for (int dx=0;dx<4;dx++){
            const int xx = 2*ox-1+dx;
            r[dy][dx] = (xx>=0 && xx<64) ? Lr[xx] : 0.f;
        }
    }
    short8 hv[4], lv[4];
#pragma unroll
    for (int o=0;o<32;o++){
        const int och = half*32 + o;
        float w[9];
#pragma unroll
        for (int k=0;k<9;k++) w[k] = wsm[och*9+k];    // LDS broadcast (2 addrs/wave)
        const float a = aAs[och], b = aBs[och];
        float best = -1e30f;
#pragma unroll
        for (int sy=0;sy<2;sy++)
#pragma unroll
          for (int sx=0;sx<2;sx++){
            float s=0.f;
#pragma unroll
            for (int ky=0;ky<3;ky++)
#pragma unroll
              for (int kx=0;kx<3;kx++) s += r[sy+ky][sx+kx]*w[ky*3+kx];
            best = fmaxf(best, lrelu(a*s+b));
          }
        __hip_bfloat16 hb = __float2bfloat16(best);
        const float hf = __bfloat162float(hb);
        __hip_bfloat16 lb = __float2bfloat16(best - hf);
        hv[o>>3][o&7] = (short)*(unsigned short*)&hb;
        lv[o>>3][o&7] = (short)*(unsigned short*)&lb;
    }
    const size_t base = ((((size_t)img*34 + (oy0+ly) + 1)*34) + ox + 1)*128 + half*32;
#pragma unroll
    for (int j=0;j<4;j++){
        *(short8*)(p1p + base + j*8)      = hv[j];
        *(short8*)(p1p + base + 64 + j*8) = lv[j];
    }
}

// ---------------- conv2 via MFMA — 2 rows/block, &15 swizzle, pool + per-block stats ------------
__global__ __launch_bounds__(256) void conv2mfma_k(const unsigned short* __restrict__ p1p,
        const unsigned short* __restrict__ whi, const unsigned short* __restrict__ wlo,
        float* __restrict__ pmm, float* __restrict__ pbs)
{
    __shared__ __align__(16) unsigned short Bx[136*128];   // 34,816 B -> 4 blocks/CU
    const int img = blockIdx.x, rowblk = blockIdx.y;       // rowblk 0..15 -> 2 rows = 1 pooled row
    const int t = threadIdx.x;
    {
        const unsigned short* src = p1p + (((size_t)img*34 + rowblk*2)*34)*128;
        for (int idx=t; idx<2176; idx+=256){               // 136 pos * 16 chunks of 16B
            const int pos = idx>>4, sub = idx&15;
            const short8 v = *(const short8*)(src + pos*128 + sub*8);
            *(short8*)(Bx + pos*128 + ((sub ^ (pos&15))<<3)) = v;
        }
    }
    __syncthreads();
    const int lane = t & 63, wv = t >> 6;
    const int mt = wv & 1, ntp = wv >> 1;                  // 2 och-halves x 2 px-rows
    const int m = lane & 31, kg = lane >> 5;
    f32x16 accA, accB, accC;                               // 3 independent chains
#pragma unroll
    for (int r=0;r<16;r++){ accA[r]=0.f; accB[r]=0.f; accC[r]=0.f; }

#pragma unroll
    for (int ky=0; ky<3; ky++){
#pragma unroll
      for (int kx=0; kx<3; kx++){
        const int s = ky*3 + kx;
        const unsigned short* wh = whi + ((s*64 + mt*32 + m)<<6) + kg*8;
        const unsigned short* wl = wlo + ((s*64 + mt*32 + m)<<6) + kg*8;
        const int pos = (ntp+ky)*34 + m + kx;
        const int pb  = pos << 7;
        const int sw  = (pos & 15) << 3;
#pragma unroll
        for (int ch=0; ch<4; ch++){
            const int o = ch*16 + (kg<<3);
            const short8 ah = *(const short8*)(wh + ch*16);
            const short8 al = *(const short8*)(wl + ch*16);
            const short8 bh = *(const short8*)(Bx + pb + (o ^ sw));
            const short8 bl = *(const short8*)(Bx + pb + ((64 + o) ^ sw));
            accA = __builtin_amdgcn_mfma_f32_32x32x16_bf16(ah, bh, accA, 0,0,0);
            accB = __builtin_amdgcn_mfma_f32_32x32x16_bf16(al, bh, accB, 0,0,0);
            accC = __builtin_amdgcn_mfma_f32_32x32x16_bf16(ah, bl, accC, 0,0,0);
        }
      }
    }
    float fa[16];
#pragma unroll
    for (int r=0;r<16;r++) fa[r] = accA[r] + accB[r] + accC[r];

    // stash both rows in LDS (stride 33 -> bank-spread), then pool + stats per 4-lane quad
    __syncthreads();                       // all MFMA reads of Bx complete
    float* Bxf = (float*)Bx;               // [2 rows][64 och][33] = 16.9 KB
#pragma unroll
    for (int r=0; r<16; r++){
        const int och = mt*32 + (r&3) + 8*(r>>2) + 4*kg;
        Bxf[(ntp*64 + och)*33 + m] = fa[r];
    }
    __syncthreads();
    {
        const int och = t>>2, q4 = t&3;    // 64 och x 4 quads
        const int c0 = q4*8;               // 8 raw cols per quad-thread
        const float* r0 = Bxf + och*33 + c0;
        const float* r1 = Bxf + (64+och)*33 + c0;
        float4 mxv, mnv;
        float* mxp = (float*)&mxv; float* mnp = (float*)&mnv;
        float s = 0.f, q = 0.f;
#pragma unroll
        for (int k=0;k<4;k++){
            const float a0 = r0[2*k], a1 = r0[2*k+1], b0 = r1[2*k], b1 = r1[2*k+1];
            mxp[k] = fmaxf(fmaxf(a0,a1), fmaxf(b0,b1));
            mnp[k] = fminf(fminf(a0,a1), fminf(b0,b1));
            s += a0+a1+b0+b1;
            q += a0*a0+a1*a1+b0*b0+b1*b1;
        }
        float* base = pmm + (((size_t)img*64 + och)*16 + rowblk)*32;
        *(float4*)(base + q4*4)      = mxv;
        *(float4*)(base + 16 + q4*4) = mnv;
        s += __shfl_xor(s, 1); q += __shfl_xor(q, 1);
        s += __shfl_xor(s, 2); q += __shfl_xor(q, 2);
        if (q4 == 0){
            float* pb = pbs + (size_t)(img*16 + rowblk)*128 + och*2;
            pb[0] = s; pb[1] = q;
        }
    }
}

// ---------------- reduce conv2 per-block stats -> BN2 group sums ------------------------------
__global__ __launch_bounds__(128) void bnred_k(const float* __restrict__ pbs, float* __restrict__ sums)
{
    const int img = blockIdx.x, t = threadIdx.x;   // t<128: och=t>>1, metric=t&1
    const int och = t>>1, metric = t&1;
    const float* p = pbs + (size_t)img*16*128 + och*2 + metric;
    float s = 0.f;
#pragma unroll
    for (int rb=0; rb<16; rb++) s += p[rb*128];
    const int g = bn_group(img);
    atomicAdd(&sums[(g*64+och)*2 + metric], s);
}

// ---------------- stage-2 BN + lrelu + pooled-select -> P2PACK (hi/lo bf16, channel-last) -------
__global__ __launch_bounds__(256) void bnpool_pack_k(const float* __restrict__ pmm,
        const float* __restrict__ sums, const float* __restrict__ gw, const float* __restrict__ bw,
        unsigned short* __restrict__ p2p)
{
    __shared__ float aA[64], aB[64];
    const int img = blockIdx.x, cb = blockIdx.y, t = threadIdx.x;
    const int g = bn_group(img);
    if (t < 64){
        const float n = (float)(((g==0)?64:5) * 1024);
        float a, b;
        bn_ab(sums, g, t, n, gw[t], bw[t], a, b);
        aA[t]=a; aB[t]=b;
    }
    __syncthreads();
    const int oy = t>>4, ox = t&15;
    short8 hv[4], lv[4];
#pragma unroll
    for (int j8=0;j8<4;j8++){
#pragma unroll
      for (int e=0;e<8;e++){
        const int j = j8*8 + e;
        const int c = cb*32 + j;
        const float a = aA[c], b = aB[c];
        const size_t o = (((size_t)img*64 + c)*16 + oy)*32 + ox + (a >= 0.f ? 0 : 16);
        const float best = lrelu(a*pmm[o] + b);
        __hip_bfloat16 hb = __float2bfloat16(best);
        const float hf = __bfloat162float(hb);
        __hip_bfloat16 lb = __float2bfloat16(best - hf);
        hv[j8][e] = (short)*(unsigned short*)&hb;
        lv[j8][e] = (short)*(unsigned short*)&lb;
      }
    }
    unsigned short* dst = p2p + (((size_t)img*18 + oy+1)*18 + ox+1)*128 + cb*32;
#pragma unroll
    for (int j=0;j<4;j++){
        *(short8*)(dst + j*8)      = hv[j];
        *(short8*)(dst + 64 + j*8) = lv[j];
    }
}

// ---------------- 16x16 64->64 3x3 conv via MFMA (conv3 & conv4), 3 independent chains ----------
__global__ __launch_bounds__(256) void conv16mfma_k(const unsigned short* __restrict__ pack,
        const unsigned short* __restrict__ whi, const unsigned short* __restrict__ wlo,
        float* __restrict__ out, float* __restrict__ bnsum)
{
    __shared__ __align__(16) unsigned short Bx[108*128];   // 27,648 B (6 padded rows x 18 cols)
    const int img = blockIdx.x, rowblk = blockIdx.y;       // rowblk 0..3 -> 4 output rows
    const int t = threadIdx.x;
    {
        const unsigned short* src = pack + (((size_t)img*18 + rowblk*4)*18)*128;
        for (int idx=t; idx<1728; idx+=256){
            const int pos = idx>>4, sub = idx&15;
            const short8 v = *(const short8*)(src + pos*128 + sub*8);
            *(short8*)(Bx + pos*128 + ((sub ^ (pos&15))<<3)) = v;
        }
    }
    __syncthreads();
    const int lane = t & 63, wv = t >> 6;
    const int mt = wv & 1, np = wv >> 1;
    const int m = lane & 31, kg = lane >> 5;
    f32x16 accA, accB, accC;
#pragma unroll
    for (int r=0;r<16;r++){ accA[r]=0.f; accB[r]=0.f; accC[r]=0.f; }

#pragma unroll
    for (int ky=0; ky<3; ky++){
#pragma unroll
      for (int kx=0; kx<3; kx++){
        const int s = ky*3 + kx;
        const unsigned short* wh = whi + ((s*64 + mt*32 + m)<<6) + kg*8;
        const unsigned short* wl = wlo + ((s*64 + mt*32 + m)<<6) + kg*8;
        const int pos = (np*2 + (m>>4) + ky)*18 + (m&15) + kx;
        const int pb  = pos << 7;
        const int sw  = (pos & 15) << 3;
#pragma unroll
        for (int ch=0; ch<4; ch++){
            const int o = ch*16 + (kg<<3);
            const short8 ah = *(const short8*)(wh + ch*16);
            const short8 al = *(const short8*)(wl + ch*16);
            const short8 bh = *(const short8*)(Bx + pb + (o ^ sw));
            const short8 bl = *(const short8*)(Bx + pb + ((64 + o) ^ sw));
            accA = __builtin_amdgcn_mfma_f32_32x32x16_bf16(ah, bh, accA, 0,0,0);
            accB = __builtin_amdgcn_mfma_f32_32x32x16_bf16(al, bh, accB, 0,0,0);
            accC = __builtin_amdgcn_mfma_f32_32x32x16_bf16(ah, bl, accC, 0,0,0);
        }
      }
    }
    float* co = out + (size_t)img*16384 + rowblk*64 + np*32 + m;
    float fa[16];
#pragma unroll
    for (int r=0; r<16; r++){
        fa[r] = accA[r] + accB[r] + accC[r];
        const int och = mt*32 + (r&3) + 8*(r>>2) + 4*kg;
        co[(size_t)och*256] = fa[r];
    }
    const int g = bn_group(img);
    float* bs = bnsum + (rowblk*2 + np)*768;
#pragma unroll
    for (int r=0; r<16; r++){
        float sv = fa[r], qv = fa[r]*fa[r];
#pragma unroll
        for (int off=16; off>0; off>>=1){ sv += __shfl_xor(sv, off); qv += __shfl_xor(qv, off); }
        if (m == r){
            const int och = mt*32 + (r&3) + 8*(r>>2) + 4*kg;
            atomicAdd(&bs[(g*64+och)*2],   sv);
            atomicAdd(&bs[(g*64+och)*2+1], qv);
        }
    }
}

// ---------------- C3 raw + BN3 -> lrelu -> C3PACK (hi/lo bf16, channel-last) -------------------
__global__ __launch_bounds__(256) void c3pack_k(const float* __restrict__ c3,
        const float* __restrict__ s3, const float* __restrict__ gw, const float* __restrict__ bw,
        unsigned short* __restrict__ c3p)
{
    __shared__ float aA[64], aB[64];
    const int img = blockIdx.x, cb = blockIdx.y, t = threadIdx.x;
    const int g = bn_group(img);
    if (t < 64){
        const float n = (float)(((g==0)?64:5) * 256);
        float a, b;
        bn_ab_s8(s3, g, t, n, gw[t], bw[t], a, b);
        aA[t]=a; aB[t]=b;
    }
    __syncthreads();
    const float* pim = c3 + (size_t)img*16384 + (size_t)cb*8192 + t;
    short8 hv[4], lv[4];
#pragma unroll
    for (int j8=0;j8<4;j8++){
#pragma unroll
      for (int e=0;e<8;e++){
        const int j = j8*8 + e;
        const int c = cb*32 + j;
        const float v = lrelu(aA[c]*pim[(size_t)j*256] + aB[c]);
        __hip_bfloat16 hb = __float2bfloat16(v);
        const float hf = __bfloat162float(hb);
        __hip_bfloat16 lb = __float2bfloat16(v - hf);
        hv[j8][e] = (short)*(unsigned short*)&hb;
        lv[j8][e] = (short)*(unsigned short*)&lb;
      }
    }
    const int oy = t>>4, ox = t&15;
    unsigned short* dst = c3p + (((size_t)img*18 + oy+1)*18 + ox+1)*128 + cb*32;
#pragma unroll
    for (int j=0;j<4;j++){
        *(short8*)(dst + j*8)      = hv[j];
        *(short8*)(dst + 64 + j*8) = lv[j];
    }
}

// ---------------- MHSA projection: raw C4 in (BN4 8-slot inline) -> ckv ------------------------
__global__ __launch_bounds__(256) void proj_k(const float* __restrict__ c4, const float* __restrict__ wT,
               const float* __restrict__ bq, const float* __restrict__ bk, const float* __restrict__ bv,
               const float* __restrict__ sums4, const float* __restrict__ gw4, const float* __restrict__ bw4,
               float* __restrict__ ckv)
{
    __shared__ float xl[64*256];   // 64 KB exactly
    const int img = blockIdx.x, s = blockIdx.y, t = threadIdx.x;
    const int gi = bn_group(img);
    const float nin = (float)(((gi==0)?64:5) * 256);
    {
        const float4* in4 = (const float4*)(c4 + (size_t)img*16384);
        float4* xl4 = (float4*)xl;
        for (int i=t; i<4096; i+=256){
            float4 v = in4[i];
            const int c = i>>6;     // wave-uniform
            float a, b;
            bn_ab_s8(sums4, gi, c, nin, gw4[c], bw4[c], a, b);
            v.x=lrelu(a*v.x+b); v.y=lrelu(a*v.y+b); v.z=lrelu(a*v.z+b); v.w=lrelu(a*v.w+b);
            xl4[i] = v;
        }
    }
    const float* bias = (s==0)?bq:((s==1)?bk:bv);
    const int sofs = (s==0)?16:((s==1)?0:32);
    const float* wp = wT + s*4096;
    const int o0 = (t>>4)*4, i0 = (t&15)*16;
    const int h = o0>>4, d0 = o0&15;
    __syncthreads();
    float acc[4][16];
    float b0[4];
#pragma unroll
    for (int o=0;o<4;o++) b0[o]=bias[o0+o];
#pragma unroll
    for (int o=0;o<4;o++)
#pragma unroll
      for (int i=0;i<16;i++) acc[o][i]=b0[o];
    for (int c=0;c<64;c++){
        const float4 w4 = *(const float4*)(wp + c*64 + o0);
        const float* xr = xl + c*256 + i0;
#pragma unroll
        for (int k=0;k<4;k++){
            const float4 x4 = *(const float4*)(xr + 4*k);
            acc[0][4*k+0]+=w4.x*x4.x; acc[0][4*k+1]+=w4.x*x4.y; acc[0][4*k+2]+=w4.x*x4.z; acc[0][4*k+3]+=w4.x*x4.w;
            acc[1][4*k+0]+=w4.y*x4.x; acc[1][4*k+1]+=w4.y*x4.y; acc[1][4*k+2]+=w4.y*x4.z; acc[1][4*k+3]+=w4.y*x4.w;
            acc[2][4*k+0]+=w4.z*x4.x; acc[2][4*k+1]+=w4.z*x4.y; acc[2][4*k+2]+=w4.z*x4.z; acc[2][4*k+3]+=w4.z*x4.w;
            acc[3][4*k+0]+=w4.w*x4.x; acc[3][4*k+1]+=w4.w*x4.y; acc[3][4*k+2]+=w4.w*x4.z; acc[3][4*k+3]+=w4.w*x4.w;
        }
    }
#pragma unroll
    for (int ii=0;ii<16;ii++){
        const float4 v = make_float4(acc[0][ii],acc[1][ii],acc[2][ii],acc[3][ii]);
        *(float4*)(ckv + (((size_t)img*4 + h)*256 + i0+ii)*48 + sofs + d0) = v;
    }
}

// ---------------- attention: full flash pass per (img,h) -> final mhraw -------------------------
// Single pass over all 256 j (no chunk split): partial buffers + merge eliminated.
__global__ __launch_bounds__(256) void attnp_k(const float* __restrict__ ckv, const float* __restrict__ pos,
                               float* __restrict__ mhraw)
{
    const int img = blockIdx.x, h = blockIdx.y, i = threadIdx.x;
    const size_t jb = (((size_t)img*4 + h)*256)*48;
    float areg[32];
    {
        const float* myrow = ckv + jb + (size_t)i*48;
#pragma unroll
        for (int k=0;k<4;k++) *(float4*)&areg[4*k]    = *(const float4*)(myrow + 16 + 4*k);  // q_i
#pragma unroll
        for (int k=0;k<4;k++) *(float4*)&areg[16+4*k] = *(const float4*)(pos + h*4096 + i*16 + 4*k); // pos_i
    }
    float mrun = -1e30f, l = 0.f;
    float accv[16];
#pragma unroll
    for (int d=0;d<16;d++) accv[d]=0.f;

    for (int j0=0; j0<256; j0+=2){
        const float* r0 = ckv + jb + (size_t)j0*48;      // wave-uniform -> s_load
        const float* r1 = r0 + 48;
        float s0a=0.f, s0b=0.f, s1a=0.f, s1b=0.f;
#pragma unroll
        for (int dd=0; dd<16; ++dd){
            s0a += areg[2*dd]  *r0[2*dd];
            s0b += areg[2*dd+1]*r0[2*dd+1];
            s1a += areg[2*dd]  *r1[2*dd];
            s1b += areg[2*dd+1]*r1[2*dd+1];
        }
        const float s0 = s0a+s0b, s1 = s1a+s1b;
        const float mnew = fmaxf(mrun, fmaxf(s0,s1));
        const float al = __expf(mrun - mnew);
        const float e0 = __expf(s0 - mnew), e1 = __expf(s1 - mnew);
        mrun = mnew;
        l = l*al + e0 + e1;
        const float* v0 = r0 + 32;
        const float* v1 = r1 + 32;
#pragma unroll
        for (int d=0;d<16;d++) accv[d] = accv[d]*al + e0*v0[d] + e1*v1[d];
    }
    const float rl = 1.f/l;
    float* mb = mhraw + ((size_t)img*64 + h*16)*256 + i;
#pragma unroll
    for (int d=0;d<16;d++) mb[d*256] = accv[d]*rl;
}

// ---------------- fused post-attention: mhsa-norm + CBAM + residual + Q-norm --------------------
// For img<64: res is consumed ONLY by the Q-normalize -> compute qn in-kernel and skip res write.
__global__ __launch_bounds__(256) void post_k(const float* __restrict__ mhraw,
        const float* __restrict__ lng, const float* __restrict__ lnb,
        const float* __restrict__ c4,
        const float* __restrict__ sums4, const float* __restrict__ gw4, const float* __restrict__ bw4,
        const float* __restrict__ w1, const float* __restrict__ b1,
        const float* __restrict__ w2, const float* __restrict__ b2,
        const float* __restrict__ sw, const float* __restrict__ sb,
        float* __restrict__ res, float* __restrict__ qn)
{
    __shared__ float r1[256], r2[256];
    __shared__ float favg[64], fmx[64], z1s[8], ca[64];
    __shared__ float sf[512];
    __shared__ float wl[98];
    __shared__ float mh_s[2];
    __shared__ float aA[64], aB[64];
    __shared__ float sa_l[256];
    const int img = blockIdx.x, t = threadIdx.x;
    const float* mb  = mhraw + (size_t)img*16384;
    const float* fbr = c4    + (size_t)img*16384;

    if (t<64){
        const int gi = bn_group(img);
        const float nin = (float)(((gi==0)?64:5) * 256);
        float a, b;
        bn_ab_s8(sums4, gi, t, nin, gw4[t], bw4[t], a, b);
        aA[t]=a; aB[t]=b;
    }
    if (t<98) wl[t] = sw[t];

    {
        const float4* mb4 = (const float4*)mb;
        float s=0.f, ss=0.f;
        for (int i=t; i<4096; i+=256){
            const float4 v = mb4[i];
            s  += v.x+v.y+v.z+v.w;
            ss += v.x*v.x+v.y*v.y+v.z*v.z+v.w*v.w;
        }
        r1[t]=s; r2[t]=ss; __syncthreads();
        for (int st=128;st>0;st>>=1){ if(t<st){r1[t]+=r1[t+st]; r2[t]+=r2[t+st];} __syncthreads(); }
        if (t==0){
            const float m = r1[0]/16384.f;
            const float var = fmaxf(r2[0]/16384.f - m*m, 0.f);
            mh_s[0]=m; mh_s[1]=1.f/sqrtf(var+1e-5f);
        }
    }
    {
        const int c = t>>2, part4 = t&3;
        const float a = aA[c], b = aB[c];
        const float4* p4 = (const float4*)(fbr + c*256 + part4*64);
        float s=0.f, mx=-1e30f;
        for (int k=0;k<16;k++){
            const float4 v = p4[k];
            const float f0=lrelu(a*v.x+b), f1=lrelu(a*v.y+b), f2=lrelu(a*v.z+b), f3=lrelu(a*v.w+b);
            s += f0+f1+f2+f3;
            mx = fmaxf(mx, fmaxf(fmaxf(f0,f1),fmaxf(f2,f3)));
        }
        __syncthreads();
        r1[t]=s; r2[t]=mx;
        __syncthreads();
        if (t<64){
            favg[t] = (r1[t*4]+r1[t*4+1]+r1[t*4+2]+r1[t*4+3])/256.f;
            fmx[t]  = fmaxf(fmaxf(r2[t*4],r2[t*4+1]),fmaxf(r2[t*4+2],r2[t*4+3]));
        }
    }
    __syncthreads();
    if (t<8){
        const int which = t>>2, o = t&3;
        const float* f = which? fmx : favg;
        float z = b1[o];
        for (int c=0;c<64;c++) z += w1[o*64+c]*f[c];
        z1s[t] = fmaxf(z, 0.f);
    }
    __syncthreads();
    if (t<64){
        float z = 2.f*b2[t];
#pragma unroll
        for (int k=0;k<4;k++) z += w2[t*4+k]*(z1s[k]+z1s[4+k]);
        ca[t] = sigm(z);
    }
    __syncthreads();
    {
        float s=0.f, mx=-1e30f;
        for (int c=0;c<64;c++){
            const float fv = lrelu(aA[c]*fbr[c*256+t] + aB[c]);
            const float v = ca[c]*fv;
            s += v; mx = fmaxf(mx, v);
        }
        sf[t]     = s/64.f;
        sf[256+t] = mx;
    }
    __syncthreads();
    {
        float sacc = sb[0];
        const int y = t>>4, x = t&15;
        for (int ch=0; ch<2; ++ch)
          for (int ky=0; ky<7; ++ky){
            const int yy = y+ky-3;
            if (yy<0||yy>=16) continue;
            for (int kx=0; kx<7; ++kx){
                const int xx = x+kx-3;
                if (xx<0||xx>=16) continue;
                sacc += sf[ch*256 + yy*16 + xx]*wl[ch*49 + ky*7 + kx];
            }
          }
        sa_l[t] = sigm(sacc);
    }
    __syncthreads();
    {
        const int q = t & 63;
        const int cb = t >> 6;
        const float m = mh_s[0], istd = mh_s[1];
        const float4* mb4 = (const float4*)mb;
        const float4* fb4 = (const float4*)fbr;
        const float4* lg4 = (const float4*)lng;
        const float4* lb4 = (const float4*)lnb;
        float4* res4 = (float4*)(res + (size_t)img*16384);
        float*  qnb  = qn + (size_t)img*16384;
        const bool isq = (img < 64);       // block-uniform branch
        const float sa0=sa_l[4*q], sa1=sa_l[4*q+1], sa2=sa_l[4*q+2], sa3=sa_l[4*q+3];
#pragma unroll 4
        for (int cc=0; cc<16; ++cc){
            const int c = cb*16 + cc;
            const int i4 = c*64 + q;
            const float4 mv = mb4[i4];
            const float4 fv = fb4[i4], gv = lg4[i4], bv = lb4[i4];
            const float a = aA[c], b = aB[c], cf = ca[c];
            float4 r;
            r.x = (mv.x-m)*istd*gv.x + bv.x + lrelu(a*fv.x+b)*(2.f + sa0*cf);
            r.y = (mv.y-m)*istd*gv.y + bv.y + lrelu(a*fv.y+b)*(2.f + sa1*cf);
            r.z = (mv.z-m)*istd*gv.z + bv.z + lrelu(a*fv.z+b)*(2.f + sa2*cf);
            r.w = (mv.w-m)*istd*gv.w + bv.w + lrelu(a*fv.w+b)*(2.f + sa3*cf);
            if (isq){
                // fused Q-normalize: wave cb holds all 256 px of channel c (lane q -> px 4q..4q+3)
                float ssq = r.x*r.x + r.y*r.y + r.z*r.z + r.w*r.w;
#pragma unroll
                for (int off=32; off>0; off>>=1) ssq += __shfl_xor(ssq, off);
                const float inv = 1.f/sqrtf(ssq);
                float4 o;
                o.x=r.x*inv; o.y=r.y*inv; o.z=r.z*inv; o.w=r.w*inv;
                *(float4*)(qnb + c*256 + q*4) = o;
            } else {
                res4[i4] = r;
            }
        }
    }
}

// ---------------- covariance ----------------
__global__ __launch_bounds__(256) void covmu_k(const float* __restrict__ res, float* __restrict__ mu)
{
    __shared__ float r1[256];
    const int n = blockIdx.x, c = blockIdx.y, t = threadIdx.x;
    float s=0.f;
    for (int sh=0; sh<5; ++sh)
        s += res[((size_t)(64 + n*5 + sh)*64 + c)*256 + t];
    r1[t]=s; __syncthreads();
    for (int st=128;st>0;st>>=1){ if(t<st) r1[t]+=r1[t+st]; __syncthreads(); }
    if (t==0) mu[n*64+c] = r1[0]/1280.f;
}

__global__ __launch_bounds__(256) void cov_k(const float* __restrict__ res, const float* __restrict__ mu,
                                             float* __restrict__ cov)
{
    __shared__ float Xl[64*129];   // 33 KB
    const int n = blockIdx.x, by = blockIdx.y, sh = blockIdx.z, t = threadIdx.x;
    const int c = by*16 + (t>>4);
    const int d0 = (t&15)*4;
    float acc[4] = {0.f,0.f,0.f,0.f};
    for (int half=0; half<2; ++half){
        __syncthreads();
        for (int idx=t; idx<8192; idx+=256){
            const int ch = idx>>7, p = idx&127;
            Xl[ch*129+p] = res[((size_t)(64+n*5+sh)*64 + ch)*256 + half*128 + p] - mu[n*64+ch];
        }
        __syncthreads();
        for (int p=0;p<128;p++){
            const float xc = Xl[c*129+p];
#pragma unroll
            for (int k=0;k<4;k++) acc[k] += xc*Xl[(d0+k)*129+p];
        }
    }
#pragma unroll
    for (int k=0;k<4;k++) atomicAdd(&cov[((size_t)n*64 + c)*64 + d0+k], acc[k]*(1.f/1279.f));
}

// ---------------- sim[b,j,i] = Qn(:,i)^T cov_j Qn(:,i) ----------------
__global__ __launch_bounds__(256) void sim_k(const float* __restrict__ qn, const float* __restrict__ cov,
                                             float* __restrict__ sim)
{
    __shared__ float covj[64*65];
    __shared__ float Vl[64*68];
    __shared__ float simred[320];
    const int b = blockIdx.x, iq = blockIdx.y, t = threadIdx.x;
    const int i0g = iq*64;
    for (int idx=t; idx<4096; idx+=256){
        const int c = idx>>6, il = idx&63;
        Vl[c*68+il] = qn[((size_t)b*64+c)*256 + i0g + il];
    }
    for (int idx=t; idx<320; idx+=256) simred[idx]=0.f;
    const int c0 = (t>>4)*4, i0 = (t&15)*4;
    for (int j=0;j<5;j++){
        __syncthreads();
        for (int idx=t; idx<4096; idx+=256)
            covj[(idx>>6)*65 + (idx&63)] = cov[(size_t)j*4096 + idx];
        __syncthreads();
        float pt[4][4];
#pragma unroll
        for (int a=0;a<4;a++)
#pragma unroll
          for (int bb=0;bb<4;bb++) pt[a][bb]=0.f;
        for (int d=0; d<64; ++d){
            const float4 vv = *(const float4*)&Vl[d*68 + i0];
            float cw[4];
#pragma unroll
            for (int cc=0;cc<4;cc++) cw[cc] = covj[(c0+cc)*65 + d];
#pragma unroll
            for (int cc=0;cc<4;cc++){
                pt[cc][0] += cw[cc]*vv.x;
                pt[cc][1] += cw[cc]*vv.y;
                pt[cc][2] += cw[cc]*vv.z;
                pt[cc][3] += cw[cc]*vv.w;
            }
        }
#pragma unroll
        for (int ii=0;ii<4;ii++){
            float s = 0.f;
#pragma unroll
            for (int cc=0;cc<4;cc++) s += pt[cc][ii]*Vl[(c0+cc)*68 + i0+ii];
            atomicAdd(&simred[j*64 + i0 + ii], s);
        }
    }
    __syncthreads();
    for (int idx=t; idx<320; idx+=256){
        const int j = idx>>6, il = idx&63;
        sim[((size_t)b*5 + j)*256 + i0g + il] = simred[idx];
    }
}

// ---------------- classifier ----------------
__global__ __launch_bounds__(256) void cls_k(const float* __restrict__ sim, const float* __restrict__ cw,
                                             float* __restrict__ out)
{
    __shared__ float red[256];
    const int b = blockIdx.x, t = threadIdx.x;
    const float w = cw[t];
    for (int j=0;j<5;j++){
        const float v = sim[((size_t)b*5 + j)*256 + t];
        red[t] = lrelu(v)*w;
        __syncthreads();
        for (int st=128;st>0;st>>=1){ if(t<st) red[t]+=red[t+st]; __syncthreads(); }
        if (t==0) out[b*5+j] = red[0];
        __syncthreads();
    }
}

// ---------------- launch ----------------
extern "C" void kernel_launch(void* const* d_in, const int* in_sizes, int n_in,
                              void* d_out, int out_size, void* d_ws, size_t ws_size,
                              hipStream_t stream)
{
    const float* IN[31];
    for (int i=0;i<31;i++) IN[i] = (const float*)d_in[i];
    float* W = (float*)d_ws;
    float* OUT = (float*)d_out;
    const unsigned short* WHp  = (const unsigned short*)(W + OFF_WH);
    const unsigned short* WLp  = (const unsigned short*)(W + OFF_WL);
    const unsigned short* WH3p = (const unsigned short*)(W + OFF_WH3);
    const unsigned short* WL3p = (const unsigned short*)(W + OFF_WL3);
    const unsigned short* WH4p = (const unsigned short*)(W + OFF_WH4);
    const unsigned short* WL4p = (const unsigned short*)(W + OFF_WL4);
    unsigned short* P1P = (unsigned short*)(W + OFF_P1);
    unsigned short* P2P = (unsigned short*)(W + OFF_P2);
    unsigned short* C3P = (unsigned short*)(W + OFF_C3P);

    prep_k<<<8074,256,0,stream>>>(IN[0],IN[1],IN[20],IN[21],IN[14],IN[16],IN[18],
                                  IN[5],IN[8],IN[11],W);

    // stage 1: conv1 stats-only -> fused recompute+BN+pool -> packed hi/lo bf16, channel-last
    conv3x3_k<64,64,1,1,4,4,false,false><<<dim3(89,16),256,0,stream>>>(W+OFF_X0, IN[2], nullptr, W+OFF_STATS, nullptr,nullptr,nullptr,0);
    bnpoolconv1_k<<<dim3(89,8),256,0,stream>>>(W+OFF_X0, IN[2], W+OFF_STATS, IN[3], IN[4], P1P);

    // stage 2: MFMA conv2 (pooled max/min + per-block stats, no atomics) -> per-image reduce -> pack
    conv2mfma_k<<<dim3(89,16),256,0,stream>>>(P1P, WHp, WLp, W+OFF_PMM, W+OFF_PBS);
    bnred_k<<<89,128,0,stream>>>(W+OFF_PBS, W+OFF_S2);
    bnpool_pack_k<<<dim3(89,2),256,0,stream>>>(W+OFF_PMM, W+OFF_S2, IN[6], IN[7], P2P);

    // stage 3: MFMA conv3 (+8-slot BN3 stats) -> raw C3; then BN3+lrelu pack -> C3PACK
    conv16mfma_k<<<dim3(89,4),256,0,stream>>>(P2P, WH3p, WL3p, W+OFF_C3, W+OFF_S3);
    c3pack_k<<<dim3(89,2),256,0,stream>>>(W+OFF_C3, W+OFF_S3, IN[9], IN[10], C3P);

    // stage 4: MFMA conv4 (+8-slot BN4 stats) -> raw C4 (BN4 applied inline by proj/post)
    conv16mfma_k<<<dim3(89,4),256,0,stream>>>(C3P, WH4p, WL4p, W+OFF_C4, W+OFF_S4);

    // MHSA (BN4 8-slot inline in proj); single-pass flash attention -> final mhraw
    proj_k<<<dim3(89,3),256,0,stream>>>(W+OFF_C4, W+OFF_WQT, IN[15], IN[17], IN[19],
                                        W+OFF_S4, IN[12], IN[13], W+OFF_CKV);
    attnp_k<<<dim3(89,4),256,0,stream>>>(W+OFF_CKV, W+OFF_POS, W+OFF_MHRAW);

    // fused mhsa-norm + CBAM + residual + Q-normalize
    post_k<<<89,256,0,stream>>>(W+OFF_MHRAW, IN[22], IN[23], W+OFF_C4,
                                W+OFF_S4, IN[12], IN[13],
                                IN[24], IN[25], IN[26], IN[27], IN[28], IN[29],
                                W+OFF_RES, W+OFF_QN);

    // covariance metric + classifier
    covmu_k<<<dim3(5,64),256,0,stream>>>(W+OFF_RES, W+OFF_MU);
    cov_k<<<dim3(5,4,5),256,0,stream>>>(W+OFF_RES, W+OFF_MU, W+OFF_COV);
    sim_k<<<dim3(64,4),256,0,stream>>>(W+OFF_QN, W+OFF_COV, W+OFF_SIM);
    cls_k<<<64,256,0,stream>>>(W+OFF_SIM, IN[30], OUT);
}

// Round 12
// 461.016 us; speedup vs baseline: 1.1067x; 1.1067x over previous
//
#include <hip/hip_runtime.h>
#include <hip/hip_bf16.h>

__device__ __forceinline__ float lrelu(float x){ return x >= 0.f ? x : 0.2f*x; }
__device__ __forceinline__ float sigm(float x){ return 1.f/(1.f+__expf(-x)); }

typedef short short8 __attribute__((ext_vector_type(8)));
typedef float f32x16 __attribute__((ext_vector_type(16)));

// ---------------- workspace layout (float offsets) ----------------
static constexpr size_t OFF_X0    = 0;          // 89*4096 = 364544
static constexpr size_t OFF_POS   = 475712;     // 16384  [h][i][d]
static constexpr size_t OFF_WQT   = 492096;     // 12288  [s][c][o]
static constexpr size_t OFF_STATS = 504384;     // stage1 single-slot sums (768)
static constexpr size_t OFF_P1    = 507456;     // P1PACK: 89*34*34*128 ushorts (ends 7,092,032)
static constexpr size_t OFF_P2    = 7092224;    // P2PACK: 89*18*18*128 ushorts (ends 8,937,728)
static constexpr size_t OFF_S3    = 8937728;    // BN3 sums: 8 slots * 768
static constexpr size_t OFF_S4    = 8943872;    // BN4 sums: 8 slots * 768
static constexpr size_t OFF_WH3   = 8950016;    // conv3 w hi  [9][och][cin]  (36864 ushorts)
static constexpr size_t OFF_WL3   = 8968448;
static constexpr size_t OFF_WH4   = 8986880;
static constexpr size_t OFF_WL4   = 9005312;    // ends 9,023,744
static constexpr size_t OFF_PBS   = 9023744;    // conv2 per-block stats [1424 slots][64 och][2] = 182,272
static constexpr size_t OFF_S2    = 9206016;    // BN2 group sums: 768 (atomic-accum, zeroed in prep)
static constexpr size_t OFF_RES   = 10714688;   // 89*64*256 (only imgs 64+ written/read)
static constexpr size_t OFF_MU    = 12172864;   // 320
static constexpr size_t OFF_COV   = 12173184;   // 5*64*64 (atomic-accumulated, zeroed in prep)
static constexpr size_t OFF_SIM   = 12193664;   // 64*5*256
static constexpr size_t OFF_R1    = 12275584;   // big overlaid region
static constexpr size_t OFF_PMM   = OFF_R1;                 // 89*64*16*32 pooled {16max|16min}
static constexpr size_t OFF_ATP   = OFF_R1;                 // attn partials (PMM dead by then)
static constexpr size_t OFF_C3    = OFF_R1 + 5832704;       // 89*64*256 (raw conv3)
static constexpr size_t OFF_C4    = OFF_R1 + 8749056;       // 89*64*256 (raw conv4)
static constexpr size_t OFF_CKV   = OFF_R1 + 10207232;      // 89*4*256*48 (packed {k,q,v})
static constexpr size_t OFF_C3P   = OFF_R1 + 10207232;      // C3PACK overlays CKV (dead until proj)
static constexpr size_t OFF_QN    = OFF_R1 + 17543680;      // 64*64*256 (written by post_k)
static constexpr size_t OFF_WH    = OFF_R1 + 21737984;      // conv2 w hi [9][och][cin]
static constexpr size_t OFF_WL    = OFF_WH + 18432;         // conv2 w lo

__device__ __forceinline__ int bn_group(int img){ return (img < 64) ? 0 : (1 + (img-64)/5); }

__device__ __forceinline__ void bn_ab(const float* __restrict__ sums, int g, int c, float n,
                                      float gw, float bw, float& a, float& b)
{
    const float sum = sums[(g*64+c)*2], ss = sums[(g*64+c)*2+1];
    const float m = sum/n;
    const float var = fmaxf(ss/n - m*m, 0.f);
    const float istd = 1.f/sqrtf(var + 1e-5f);
    a = gw*istd;
    b = bw - m*a;
}

// 8-slot variant (slots stride 768): BN3/BN4 accumulated by conv16mfma_k
__device__ __forceinline__ void bn_ab_s8(const float* __restrict__ sums, int g, int c, float n,
                                         float gw, float bw, float& a, float& b)
{
    float sum = 0.f, ss = 0.f;
#pragma unroll
    for (int s=0;s<8;s++){
        sum += sums[s*768 + (g*64+c)*2];
        ss  += sums[s*768 + (g*64+c)*2 + 1];
    }
    const float m = sum/n;
    const float var = fmaxf(ss/n - m*m, 0.f);
    const float istd = 1.f/sqrtf(var + 1e-5f);
    a = gw*istd;
    b = bw - m*a;
}

// ---------------- prep ----------------
__global__ __launch_bounds__(256) void prep_k(const float* __restrict__ in1, const float* __restrict__ in2,
        const float* __restrict__ relh, const float* __restrict__ relw,
        const float* __restrict__ wq, const float* __restrict__ wk, const float* __restrict__ wv,
        const float* __restrict__ cw2, const float* __restrict__ cw3, const float* __restrict__ cw4,
        float* __restrict__ ws)
{
    int idx = blockIdx.x*256 + threadIdx.x;
    if (idx < 364544) { ws[OFF_X0+idx] = (idx < 262144 ? in1[idx] : in2[idx-262144]); return; }
    idx -= 364544;
    if (idx < 16384) {
        const int h = idx>>12, r = idx&4095, i = r>>4, d = r&15;
        ws[OFF_POS+idx] = relh[h*256 + d*16 + (i&15)] + relw[h*256 + d*16 + (i>>4)];
        return;
    }
    idx -= 16384;
    if (idx < 12288) {
        const int s = idx/4096, r = idx%4096, c = r>>6, o = r&63;
        const float* wp = (s==0)?wq:((s==1)?wk:wv);
        ws[OFF_WQT+idx] = wp[o*64 + c];   // [s][c][o] = W[o][c]
        return;
    }
    idx -= 12288;
    if (idx < 3072) { ws[OFF_STATS+idx] = 0.f; return; }   // stage1 sums
    idx -= 3072;
    if (idx < 20480) { ws[OFF_COV+idx] = 0.f; return; }    // zero cov
    idx -= 20480;
    if (idx < 12288) { ws[OFF_S3+idx] = 0.f; return; }     // BN3 + BN4 8-slot sums (contiguous)
    idx -= 12288;
    if (idx < 768) { ws[OFF_S2+idx] = 0.f; return; }       // BN2 sums (atomic-accumulated by bnred_k)
    idx -= 768;
    if (idx < 110592) {                                    // conv2/3/4 weights -> bf16 hi/lo [k9][och][cin]
        const int which = idx / 36864, r0 = idx - which*36864;
        const int och = r0/576, rr = r0%576, cin = rr/9, k9 = rr%9;
        const float* cwp = (which==0)?cw2:((which==1)?cw3:cw4);
        const float v = cwp[r0];
        __hip_bfloat16 hb = __float2bfloat16(v);
        const float hv = __bfloat162float(hb);
        __hip_bfloat16 lb = __float2bfloat16(v - hv);
        const size_t oh = (which==0)?OFF_WH:((which==1)?OFF_WH3:OFF_WH4);
        const size_t ol = (which==0)?OFF_WL:((which==1)?OFF_WL3:OFF_WL4);
        unsigned short* WH = (unsigned short*)(ws + oh);
        unsigned short* WL = (unsigned short*)(ws + ol);
        const int d = k9*4096 + och*64 + cin;
        WH[d] = *(unsigned short*)&hb;
        WL[d] = *(unsigned short*)&lb;
        return;
    }
    idx -= 110592;
    if (idx < 751872) {                                    // zero P1PACK halo: 89 imgs * 132 pos * 64 floats
        const int img = idx/8448, r = idx%8448;
        const int pos = r>>6, d = r&63;
        int ypad, xpad;
        if (pos < 68){ ypad = (pos<34)?0:33; xpad = (pos<34)?pos:(pos-34); }
        else { const int q = pos-68; ypad = 1 + (q>>1); xpad = (q&1)*33; }
        ws[OFF_P1 + (((size_t)img*34 + ypad)*34 + xpad)*64 + d] = 0.f;
        return;
    }
    idx -= 751872;
    if (idx < 387328) {                                    // zero P2PACK halo: 89 imgs * 68 pos * 64 floats
        const int img = idx/4352, r = idx%4352;
        const int pos = r>>6, d = r&63;
        int ypad, xpad;
        if (pos < 36){ ypad = (pos<18)?0:17; xpad = (pos<18)?pos:(pos-18); }
        else { const int q = pos-36; ypad = 1 + (q>>1); xpad = (q&1)*17; }
        ws[OFF_P2 + (((size_t)img*18 + ypad)*18 + xpad)*64 + d] = 0.f;
        return;
    }
    idx -= 387328;
    if (idx < 387328) {                                    // zero C3PACK halo
        const int img = idx/4352, r = idx%4352;
        const int pos = r>>6, d = r&63;
        int ypad, xpad;
        if (pos < 36){ ypad = (pos<18)?0:17; xpad = (pos<18)?pos:(pos-18); }
        else { const int q = pos-36; ypad = 1 + (q>>1); xpad = (q&1)*17; }
        ws[OFF_C3P + (((size_t)img*18 + ypad)*18 + xpad)*64 + d] = 0.f;
    }
}

// ---------------- direct 3x3 conv (fp32) — now only conv1 stats -------------------
template<int H, int W, int CIN, int CH, int OCB, int PT, bool STORE, bool INBN>
__global__ __launch_bounds__(256) void conv3x3_k(const float* __restrict__ in,
                                                 const float* __restrict__ wt,
                                                 float* __restrict__ out,
                                                 float* __restrict__ bnsum,
                                                 const float* __restrict__ isums,
                                                 const float* __restrict__ igw,
                                                 const float* __restrict__ ibw,
                                                 int ihw)
{
    constexpr int P = W + 1;
    constexpr int PLANE = H * P;
    constexpr int HW = H * W;
    constexpr int PASSES = HW / (256 * PT);
    constexpr int NLD = CH * HW / 256;
    __shared__ float lds[CH * PLANE];
    __shared__ float redS[OCB*4], redQ[OCB*4];
    __shared__ float abA[64], abB[64];
    const int img = blockIdx.x;
    const int och0 = blockIdx.y * OCB;
    const int t = threadIdx.x;

    if constexpr (INBN) {
        if (t < CIN) {
            const int gi = bn_group(img);
            const float nin = (float)(((gi==0)?64:5) * ihw);
            float a, b;
            bn_ab(isums, gi, t, nin, igw[t], ibw[t], a, b);
            abA[t]=a; abB[t]=b;
        }
        __syncthreads();
    }

    float acc[PASSES][OCB][PT];
#pragma unroll
    for (int a=0;a<PASSES;a++)
#pragma unroll
      for (int o=0;o<OCB;o++)
#pragma unroll
        for (int p=0;p<PT;p++) acc[a][o][p]=0.f;

    for (int idx = t; idx < CH*HW; idx += 256) {
        const int c = idx / HW, p = idx % HW;
        float v = in[((size_t)img*CIN + c)*HW + p];
        if constexpr (INBN) v = lrelu(abA[c]*v + abB[c]);
        lds[c*PLANE + (p/W)*P + (p%W)] = v;
    }
    __syncthreads();

    for (int cc0 = 0; cc0 < CIN; cc0 += CH) {
        float pre[(CIN > CH) ? NLD : 1];
        if constexpr (CIN > CH) {
            if (cc0 + CH < CIN) {
#pragma unroll
                for (int j=0;j<NLD;j++){
                    const int idx = j*256 + t;
                    const int c = idx / HW, p = idx % HW;
                    pre[j] = in[((size_t)img*CIN + cc0 + CH + c)*HW + p];
                }
            }
        }
        for (int c = 0; c < CH; ++c) {
            float wr[OCB][9];
#pragma unroll
            for (int o=0;o<OCB;o++)
#pragma unroll
              for (int k=0;k<9;k++)
                wr[o][k] = wt[((size_t)(och0+o)*CIN + (cc0+c))*9 + k];
            const float* Lc = lds + c*PLANE;
#pragma unroll
            for (int ps=0; ps<PASSES; ++ps) {
                const int px0 = (ps*256 + t)*PT;
                const int y = px0 / W, x0 = px0 % W;
#pragma unroll
                for (int ky=0; ky<3; ++ky) {
                    const int yy = y + ky - 1;
                    if (yy >= 0 && yy < H) {
                        const float* Lr = Lc + yy*P;
                        float r[PT+2];
                        r[0] = (x0 > 0) ? Lr[x0-1] : 0.f;
#pragma unroll
                        for (int k2=0;k2<PT;k2++) r[k2+1] = Lr[x0+k2];
                        r[PT+1] = (x0+PT < W) ? Lr[x0+PT] : 0.f;
#pragma unroll
                        for (int p=0;p<PT;p++)
#pragma unroll
                          for (int kx=0;kx<3;kx++) {
                              const float v = r[p+kx];
#pragma unroll
                              for (int o=0;o<OCB;o++)
                                  acc[ps][o][p] += v * wr[o][ky*3+kx];
                          }
                    }
                }
            }
        }
        if constexpr (CIN > CH) {
            if (cc0 + CH < CIN) {
                __syncthreads();
#pragma unroll
                for (int j=0;j<NLD;j++){
                    const int idx = j*256 + t;
                    const int c = idx / HW, p = idx % HW;
                    float v = pre[j];
                    if constexpr (INBN) v = lrelu(abA[cc0+CH+c]*v + abB[cc0+CH+c]);
                    lds[c*PLANE + (p/W)*P + (p%W)] = v;
                }
                __syncthreads();
            }
        }
    }
    if constexpr (STORE) {
#pragma unroll
        for (int ps=0; ps<PASSES; ++ps) {
            const int px0 = (ps*256 + t)*PT;
#pragma unroll
            for (int o=0;o<OCB;o++)
#pragma unroll
              for (int p=0;p<PT;p++)
                out[((size_t)img*64 + och0+o)*HW + px0 + p] = acc[ps][o][p];
        }
    }
    const int g = bn_group(img);
    const int wv = t >> 6;
#pragma unroll
    for (int o=0;o<OCB;o++){
        float s=0.f, ss=0.f;
#pragma unroll
        for (int ps=0;ps<PASSES;ps++)
#pragma unroll
          for (int p=0;p<PT;p++){ const float v=acc[ps][o][p]; s+=v; ss+=v*v; }
#pragma unroll
        for (int off=32; off>0; off>>=1){ s += __shfl_xor(s, off); ss += __shfl_xor(ss, off); }
        if ((t&63)==0){ redS[o*4+wv]=s; redQ[o*4+wv]=ss; }
    }
    __syncthreads();
    if (t < OCB*2){
        const int o = t>>1, metric = t&1;
        const float v = metric ? (redQ[o*4]+redQ[o*4+1]+redQ[o*4+2]+redQ[o*4+3])
                               : (redS[o*4]+redS[o*4+1]+redS[o*4+2]+redS[o*4+3]);
        atomicAdd(&bnsum[(g*64 + och0+o)*2 + metric], v);
    }
}

// ---------------- stage 1 fused: conv1+BN+lrelu+2x2 maxpool -> P1PACK ---------------------------
__global__ __launch_bounds__(256) void bnpoolconv1_k(const float* __restrict__ x0,
        const float* __restrict__ cw, const float* __restrict__ sums,
        const float* __restrict__ gw, const float* __restrict__ bw,
        unsigned short* __restrict__ p1p)
{
    __shared__ float xl[10*64];
    __shared__ float wsm[576];
    __shared__ float aAs[64], aBs[64];
    const int img = blockIdx.x, band = blockIdx.y, t = threadIdx.x;
    const int oy0 = band*4;
    const float* xp = x0 + (size_t)img*4096;
    for (int idx=t; idx<640; idx+=256){
        const int iy = idx>>6, ix = idx&63;
        const int gy = 2*oy0 - 1 + iy;
        xl[idx] = (gy>=0 && gy<64) ? xp[gy*64+ix] : 0.f;
    }
    const int g = bn_group(img);
    if (t < 64){
        const float n = (float)(((g==0)?64:5) * 4096);
        float a, b;
        bn_ab(sums, g, t, n, gw[t], bw[t], a, b);
        aAs[t]=a; aBs[t]=b;
    }
    for (int idx=t; idx<576; idx+=256) wsm[idx] = cw[idx];
    __syncthreads();
    const int p = t>>1, half = t&1;
    const int ly = p>>5, ox = p&31;
    float r[4][4];
#pragma unroll
    for (int dy=0;dy<4;dy++){
        const float* Lr = xl + (2*ly+dy)*64;
#pragma unroll
        for (int dx=0;dx<4;dx++){
            const int xx = 2*ox-1+dx;
            r[dy][dx] = (xx>=0 && xx<64) ? Lr[xx] : 0.f;
        }
    }
    short8 hv[4], lv[4];
#pragma unroll
    for (int o=0;o<32;o++){
        const int och = half*32 + o;
        float w[9];
#pragma unroll
        for (int k=0;k<9;k++) w[k] = wsm[och*9+k];    // LDS broadcast (2 addrs/wave)
        const float a = aAs[och], b = aBs[och];
        float best = -1e30f;
#pragma unroll
        for (int sy=0;sy<2;sy++)
#pragma unroll
          for (int sx=0;sx<2;sx++){
            float s=0.f;
#pragma unroll
            for (int ky=0;ky<3;ky++)
#pragma unroll
              for (int kx=0;kx<3;kx++) s += r[sy+ky][sx+kx]*w[ky*3+kx];
            best = fmaxf(best, lrelu(a*s+b));
          }
        __hip_bfloat16 hb = __float2bfloat16(best);
        const float hf = __bfloat162float(hb);
        __hip_bfloat16 lb = __float2bfloat16(best - hf);
        hv[o>>3][o&7] = (short)*(unsigned short*)&hb;
        lv[o>>3][o&7] = (short)*(unsigned short*)&lb;
    }
    const size_t base = ((((size_t)img*34 + (oy0+ly) + 1)*34) + ox + 1)*128 + half*32;
#pragma unroll
    for (int j=0;j<4;j++){
        *(short8*)(p1p + base + j*8)      = hv[j];
        *(short8*)(p1p + base + 64 + j*8) = lv[j];
    }
}

// ---------------- conv2 via MFMA — 2 rows/block, &15 swizzle, pool + per-block stats ------------
__global__ __launch_bounds__(256) void conv2mfma_k(const unsigned short* __restrict__ p1p,
        const unsigned short* __restrict__ whi, const unsigned short* __restrict__ wlo,
        float* __restrict__ pmm, float* __restrict__ pbs)
{
    __shared__ __align__(16) unsigned short Bx[136*128];   // 34,816 B -> 4 blocks/CU
    const int img = blockIdx.x, rowblk = blockIdx.y;       // rowblk 0..15 -> 2 rows = 1 pooled row
    const int t = threadIdx.x;
    {
        const unsigned short* src = p1p + (((size_t)img*34 + rowblk*2)*34)*128;
        for (int idx=t; idx<2176; idx+=256){               // 136 pos * 16 chunks of 16B
            const int pos = idx>>4, sub = idx&15;
            const short8 v = *(const short8*)(src + pos*128 + sub*8);
            *(short8*)(Bx + pos*128 + ((sub ^ (pos&15))<<3)) = v;
        }
    }
    __syncthreads();
    const int lane = t & 63, wv = t >> 6;
    const int mt = wv & 1, ntp = wv >> 1;                  // 2 och-halves x 2 px-rows
    const int m = lane & 31, kg = lane >> 5;
    f32x16 accA, accB, accC;                               // 3 independent chains
#pragma unroll
    for (int r=0;r<16;r++){ accA[r]=0.f; accB[r]=0.f; accC[r]=0.f; }

#pragma unroll
    for (int ky=0; ky<3; ky++){
#pragma unroll
      for (int kx=0; kx<3; kx++){
        const int s = ky*3 + kx;
        const unsigned short* wh = whi + ((s*64 + mt*32 + m)<<6) + kg*8;
        const unsigned short* wl = wlo + ((s*64 + mt*32 + m)<<6) + kg*8;
        const int pos = (ntp+ky)*34 + m + kx;
        const int pb  = pos << 7;
        const int sw  = (pos & 15) << 3;
#pragma unroll
        for (int ch=0; ch<4; ch++){
            const int o = ch*16 + (kg<<3);
            const short8 ah = *(const short8*)(wh + ch*16);
            const short8 al = *(const short8*)(wl + ch*16);
            const short8 bh = *(const short8*)(Bx + pb + (o ^ sw));
            const short8 bl = *(const short8*)(Bx + pb + ((64 + o) ^ sw));
            accA = __builtin_amdgcn_mfma_f32_32x32x16_bf16(ah, bh, accA, 0,0,0);
            accB = __builtin_amdgcn_mfma_f32_32x32x16_bf16(al, bh, accB, 0,0,0);
            accC = __builtin_amdgcn_mfma_f32_32x32x16_bf16(ah, bl, accC, 0,0,0);
        }
      }
    }
    float fa[16];
#pragma unroll
    for (int r=0;r<16;r++) fa[r] = accA[r] + accB[r] + accC[r];

    // stash both rows in LDS (stride 33 -> bank-spread), then pool + stats per 4-lane quad
    __syncthreads();                       // all MFMA reads of Bx complete
    float* Bxf = (float*)Bx;               // [2 rows][64 och][33] = 16.9 KB
#pragma unroll
    for (int r=0; r<16; r++){
        const int och = mt*32 + (r&3) + 8*(r>>2) + 4*kg;
        Bxf[(ntp*64 + och)*33 + m] = fa[r];
    }
    __syncthreads();
    {
        const int och = t>>2, q4 = t&3;    // 64 och x 4 quads
        const int c0 = q4*8;               // 8 raw cols per quad-thread
        const float* r0 = Bxf + och*33 + c0;
        const float* r1 = Bxf + (64+och)*33 + c0;
        float4 mxv, mnv;
        float* mxp = (float*)&mxv; float* mnp = (float*)&mnv;
        float s = 0.f, q = 0.f;
#pragma unroll
        for (int k=0;k<4;k++){
            const float a0 = r0[2*k], a1 = r0[2*k+1], b0 = r1[2*k], b1 = r1[2*k+1];
            mxp[k] = fmaxf(fmaxf(a0,a1), fmaxf(b0,b1));
            mnp[k] = fminf(fminf(a0,a1), fminf(b0,b1));
            s += a0+a1+b0+b1;
            q += a0*a0+a1*a1+b0*b0+b1*b1;
        }
        float* base = pmm + (((size_t)img*64 + och)*16 + rowblk)*32;
        *(float4*)(base + q4*4)      = mxv;
        *(float4*)(base + 16 + q4*4) = mnv;
        s += __shfl_xor(s, 1); q += __shfl_xor(q, 1);
        s += __shfl_xor(s, 2); q += __shfl_xor(q, 2);
        if (q4 == 0){
            float* pb = pbs + (size_t)(img*16 + rowblk)*128 + och*2;
            pb[0] = s; pb[1] = q;
        }
    }
}

// ---------------- reduce conv2 per-block stats -> BN2 group sums ------------------------------
__global__ __launch_bounds__(128) void bnred_k(const float* __restrict__ pbs, float* __restrict__ sums)
{
    const int img = blockIdx.x, t = threadIdx.x;   // t<128: och=t>>1, metric=t&1
    const int och = t>>1, metric = t&1;
    const float* p = pbs + (size_t)img*16*128 + och*2 + metric;
    float s = 0.f;
#pragma unroll
    for (int rb=0; rb<16; rb++) s += p[rb*128];
    const int g = bn_group(img);
    atomicAdd(&sums[(g*64+och)*2 + metric], s);
}

// ---------------- stage-2 BN + lrelu + pooled-select -> P2PACK (hi/lo bf16, channel-last) -------
__global__ __launch_bounds__(256) void bnpool_pack_k(const float* __restrict__ pmm,
        const float* __restrict__ sums, const float* __restrict__ gw, const float* __restrict__ bw,
        unsigned short* __restrict__ p2p)
{
    __shared__ float aA[64], aB[64];
    const int img = blockIdx.x, cb = blockIdx.y, t = threadIdx.x;
    const int g = bn_group(img);
    if (t < 64){
        const float n = (float)(((g==0)?64:5) * 1024);
        float a, b;
        bn_ab(sums, g, t, n, gw[t], bw[t], a, b);
        aA[t]=a; aB[t]=b;
    }
    __syncthreads();
    const int oy = t>>4, ox = t&15;
    short8 hv[4], lv[4];
#pragma unroll
    for (int j8=0;j8<4;j8++){
#pragma unroll
      for (int e=0;e<8;e++){
        const int j = j8*8 + e;
        const int c = cb*32 + j;
        const float a = aA[c], b = aB[c];
        const size_t o = (((size_t)img*64 + c)*16 + oy)*32 + ox + (a >= 0.f ? 0 : 16);
        const float best = lrelu(a*pmm[o] + b);
        __hip_bfloat16 hb = __float2bfloat16(best);
        const float hf = __bfloat162float(hb);
        __hip_bfloat16 lb = __float2bfloat16(best - hf);
        hv[j8][e] = (short)*(unsigned short*)&hb;
        lv[j8][e] = (short)*(unsigned short*)&lb;
      }
    }
    unsigned short* dst = p2p + (((size_t)img*18 + oy+1)*18 + ox+1)*128 + cb*32;
#pragma unroll
    for (int j=0;j<4;j++){
        *(short8*)(dst + j*8)      = hv[j];
        *(short8*)(dst + 64 + j*8) = lv[j];
    }
}

// ---------------- 16x16 64->64 3x3 conv via MFMA (conv3 & conv4), 3 independent chains ----------
__global__ __launch_bounds__(256) void conv16mfma_k(const unsigned short* __restrict__ pack,
        const unsigned short* __restrict__ whi, const unsigned short* __restrict__ wlo,
        float* __restrict__ out, float* __restrict__ bnsum)
{
    __shared__ __align__(16) unsigned short Bx[108*128];   // 27,648 B (6 padded rows x 18 cols)
    const int img = blockIdx.x, rowblk = blockIdx.y;       // rowblk 0..3 -> 4 output rows
    const int t = threadIdx.x;
    {
        const unsigned short* src = pack + (((size_t)img*18 + rowblk*4)*18)*128;
        for (int idx=t; idx<1728; idx+=256){
            const int pos = idx>>4, sub = idx&15;
            const short8 v = *(const short8*)(src + pos*128 + sub*8);
            *(short8*)(Bx + pos*128 + ((sub ^ (pos&15))<<3)) = v;
        }
    }
    __syncthreads();
    const int lane = t & 63, wv = t >> 6;
    const int mt = wv & 1, np = wv >> 1;
    const int m = lane & 31, kg = lane >> 5;
    f32x16 accA, accB, accC;
#pragma unroll
    for (int r=0;r<16;r++){ accA[r]=0.f; accB[r]=0.f; accC[r]=0.f; }

#pragma unroll
    for (int ky=0; ky<3; ky++){
#pragma unroll
      for (int kx=0; kx<3; kx++){
        const int s = ky*3 + kx;
        const unsigned short* wh = whi + ((s*64 + mt*32 + m)<<6) + kg*8;
        const unsigned short* wl = wlo + ((s*64 + mt*32 + m)<<6) + kg*8;
        const int pos = (np*2 + (m>>4) + ky)*18 + (m&15) + kx;
        const int pb  = pos << 7;
        const int sw  = (pos & 15) << 3;
#pragma unroll
        for (int ch=0; ch<4; ch++){
            const int o = ch*16 + (kg<<3);
            const short8 ah = *(const short8*)(wh + ch*16);
            const short8 al = *(const short8*)(wl + ch*16);
            const short8 bh = *(const short8*)(Bx + pb + (o ^ sw));
            const short8 bl = *(const short8*)(Bx + pb + ((64 + o) ^ sw));
            accA = __builtin_amdgcn_mfma_f32_32x32x16_bf16(ah, bh, accA, 0,0,0);
            accB = __builtin_amdgcn_mfma_f32_32x32x16_bf16(al, bh, accB, 0,0,0);
            accC = __builtin_amdgcn_mfma_f32_32x32x16_bf16(ah, bl, accC, 0,0,0);
        }
      }
    }
    float* co = out + (size_t)img*16384 + rowblk*64 + np*32 + m;
    float fa[16];
#pragma unroll
    for (int r=0; r<16; r++){
        fa[r] = accA[r] + accB[r] + accC[r];
        const int och = mt*32 + (r&3) + 8*(r>>2) + 4*kg;
        co[(size_t)och*256] = fa[r];
    }
    const int g = bn_group(img);
    float* bs = bnsum + (rowblk*2 + np)*768;
#pragma unroll
    for (int r=0; r<16; r++){
        float sv = fa[r], qv = fa[r]*fa[r];
#pragma unroll
        for (int off=16; off>0; off>>=1){ sv += __shfl_xor(sv, off); qv += __shfl_xor(qv, off); }
        if (m == r){
            const int och = mt*32 + (r&3) + 8*(r>>2) + 4*kg;
            atomicAdd(&bs[(g*64+och)*2],   sv);
            atomicAdd(&bs[(g*64+och)*2+1], qv);
        }
    }
}

// ---------------- C3 raw + BN3 -> lrelu -> C3PACK (hi/lo bf16, channel-last) -------------------
__global__ __launch_bounds__(256) void c3pack_k(const float* __restrict__ c3,
        const float* __restrict__ s3, const float* __restrict__ gw, const float* __restrict__ bw,
        unsigned short* __restrict__ c3p)
{
    __shared__ float aA[64], aB[64];
    const int img = blockIdx.x, cb = blockIdx.y, t = threadIdx.x;
    const int g = bn_group(img);
    if (t < 64){
        const float n = (float)(((g==0)?64:5) * 256);
        float a, b;
        bn_ab_s8(s3, g, t, n, gw[t], bw[t], a, b);
        aA[t]=a; aB[t]=b;
    }
    __syncthreads();
    const float* pim = c3 + (size_t)img*16384 + (size_t)cb*8192 + t;
    short8 hv[4], lv[4];
#pragma unroll
    for (int j8=0;j8<4;j8++){
#pragma unroll
      for (int e=0;e<8;e++){
        const int j = j8*8 + e;
        const int c = cb*32 + j;
        const float v = lrelu(aA[c]*pim[(size_t)j*256] + aB[c]);
        __hip_bfloat16 hb = __float2bfloat16(v);
        const float hf = __bfloat162float(hb);
        __hip_bfloat16 lb = __float2bfloat16(v - hf);
        hv[j8][e] = (short)*(unsigned short*)&hb;
        lv[j8][e] = (short)*(unsigned short*)&lb;
      }
    }
    const int oy = t>>4, ox = t&15;
    unsigned short* dst = c3p + (((size_t)img*18 + oy+1)*18 + ox+1)*128 + cb*32;
#pragma unroll
    for (int j=0;j<4;j++){
        *(short8*)(dst + j*8)      = hv[j];
        *(short8*)(dst + 64 + j*8) = lv[j];
    }
}

// ---------------- MHSA projection: raw C4 in (BN4 8-slot inline) -> ckv ------------------------
__global__ __launch_bounds__(256) void proj_k(const float* __restrict__ c4, const float* __restrict__ wT,
               const float* __restrict__ bq, const float* __restrict__ bk, const float* __restrict__ bv,
               const float* __restrict__ sums4, const float* __restrict__ gw4, const float* __restrict__ bw4,
               float* __restrict__ ckv)
{
    __shared__ float xl[64*256];   // 64 KB exactly
    const int img = blockIdx.x, s = blockIdx.y, t = threadIdx.x;
    const int gi = bn_group(img);
    const float nin = (float)(((gi==0)?64:5) * 256);
    {
        const float4* in4 = (const float4*)(c4 + (size_t)img*16384);
        float4* xl4 = (float4*)xl;
        for (int i=t; i<4096; i+=256){
            float4 v = in4[i];
            const int c = i>>6;     // wave-uniform
            float a, b;
            bn_ab_s8(sums4, gi, c, nin, gw4[c], bw4[c], a, b);
            v.x=lrelu(a*v.x+b); v.y=lrelu(a*v.y+b); v.z=lrelu(a*v.z+b); v.w=lrelu(a*v.w+b);
            xl4[i] = v;
        }
    }
    const float* bias = (s==0)?bq:((s==1)?bk:bv);
    const int sofs = (s==0)?16:((s==1)?0:32);
    const float* wp = wT + s*4096;
    const int o0 = (t>>4)*4, i0 = (t&15)*16;
    const int h = o0>>4, d0 = o0&15;
    __syncthreads();
    float acc[4][16];
    float b0[4];
#pragma unroll
    for (int o=0;o<4;o++) b0[o]=bias[o0+o];
#pragma unroll
    for (int o=0;o<4;o++)
#pragma unroll
      for (int i=0;i<16;i++) acc[o][i]=b0[o];
    for (int c=0;c<64;c++){
        const float4 w4 = *(const float4*)(wp + c*64 + o0);
        const float* xr = xl + c*256 + i0;
#pragma unroll
        for (int k=0;k<4;k++){
            const float4 x4 = *(const float4*)(xr + 4*k);
            acc[0][4*k+0]+=w4.x*x4.x; acc[0][4*k+1]+=w4.x*x4.y; acc[0][4*k+2]+=w4.x*x4.z; acc[0][4*k+3]+=w4.x*x4.w;
            acc[1][4*k+0]+=w4.y*x4.x; acc[1][4*k+1]+=w4.y*x4.y; acc[1][4*k+2]+=w4.y*x4.z; acc[1][4*k+3]+=w4.y*x4.w;
            acc[2][4*k+0]+=w4.z*x4.x; acc[2][4*k+1]+=w4.z*x4.y; acc[2][4*k+2]+=w4.z*x4.z; acc[2][4*k+3]+=w4.z*x4.w;
            acc[3][4*k+0]+=w4.w*x4.x; acc[3][4*k+1]+=w4.w*x4.y; acc[3][4*k+2]+=w4.w*x4.z; acc[3][4*k+3]+=w4.w*x4.w;
        }
    }
#pragma unroll
    for (int ii=0;ii<16;ii++){
        const float4 v = make_float4(acc[0][ii],acc[1][ii],acc[2][ii],acc[3][ii]);
        *(float4*)(ckv + (((size_t)img*4 + h)*256 + i0+ii)*48 + sofs + d0) = v;
    }
}

// ---------------- attention partial: j-chunk flash pass (4 chunks of 64 j) ----------------------
__global__ __launch_bounds__(256) void attnp_k(const float* __restrict__ ckv, const float* __restrict__ pos,
                               float* __restrict__ part)
{
    const int img = blockIdx.x, h = blockIdx.y, jc = blockIdx.z, i = threadIdx.x;
    const size_t jb = (((size_t)img*4 + h)*256)*48;
    float areg[32];
    {
        const float* myrow = ckv + jb + (size_t)i*48;
#pragma unroll
        for (int k=0;k<4;k++) *(float4*)&areg[4*k]    = *(const float4*)(myrow + 16 + 4*k);
#pragma unroll
        for (int k=0;k<4;k++) *(float4*)&areg[16+4*k] = *(const float4*)(pos + h*4096 + i*16 + 4*k);
    }
    float mrun = -1e30f, l = 0.f;
    float accv[16];
#pragma unroll
    for (int d=0;d<16;d++) accv[d]=0.f;

    const int jend = jc*64 + 64;
    for (int j0=jc*64; j0<jend; j0+=2){
        const float* r0 = ckv + jb + (size_t)j0*48;
        const float* r1 = r0 + 48;
        float s0a=0.f, s0b=0.f, s1a=0.f, s1b=0.f;
#pragma unroll
        for (int dd=0; dd<16; ++dd){
            s0a += areg[2*dd]  *r0[2*dd];
            s0b += areg[2*dd+1]*r0[2*dd+1];
            s1a += areg[2*dd]  *r1[2*dd];
            s1b += areg[2*dd+1]*r1[2*dd+1];
        }
        const float s0 = s0a+s0b, s1 = s1a+s1b;
        const float mnew = fmaxf(mrun, fmaxf(s0,s1));
        const float al = __expf(mrun - mnew);
        const float e0 = __expf(s0 - mnew), e1 = __expf(s1 - mnew);
        mrun = mnew;
        l = l*al + e0 + e1;
        const float* v0 = r0 + 32;
        const float* v1 = r1 + 32;
#pragma unroll
        for (int d=0;d<16;d++) accv[d] = accv[d]*al + e0*v0[d] + e1*v1[d];
    }
    float* pp = part + ((((size_t)img*4 + h)*4 + jc)*18)*256;
    pp[i]       = mrun;
    pp[256 + i] = l;
#pragma unroll
    for (int d=0;d<16;d++) pp[(2+d)*256 + i] = accv[d];
}

// ---------------- fused post-attention: partial-merge + mhsa-norm + CBAM + residual + Q-norm ----
__global__ __launch_bounds__(256) void post_k(const float* __restrict__ part,
        const float* __restrict__ lng, const float* __restrict__ lnb,
        const float* __restrict__ c4,
        const float* __restrict__ sums4, const float* __restrict__ gw4, const float* __restrict__ bw4,
        const float* __restrict__ w1, const float* __restrict__ b1,
        const float* __restrict__ w2, const float* __restrict__ b2,
        const float* __restrict__ sw, const float* __restrict__ sb,
        float* __restrict__ res, float* __restrict__ qn)
{
    __shared__ float mh_l[16384];          // 64 KB merged attention [c][i]
    __shared__ float r1[256], r2[256];
    __shared__ float favg[64], fmx[64], z1s[8], ca[64];
    __shared__ float sf[512];
    __shared__ float wl[98];
    __shared__ float mh_s[2];
    __shared__ float aA[64], aB[64];
    __shared__ float sa_l[256];
    const int img = blockIdx.x, t = threadIdx.x;
    const float* fbr = c4 + (size_t)img*16384;
    const float* pb_img = part + (size_t)img*73728;   // 4h * 4jc * 18 * 256

    if (t<64){
        const int gi = bn_group(img);
        const float nin = (float)(((gi==0)?64:5) * 256);
        float a, b;
        bn_ab_s8(sums4, gi, t, nin, gw4[t], bw4[t], a, b);
        aA[t]=a; aB[t]=b;
    }
    if (t<98) wl[t] = sw[t];

    // merge 4 j-chunk partials (i = t) + accumulate mean/var of merged output
    {
        float wgt[4][4], rl4[4];
#pragma unroll
        for (int h=0;h<4;h++){
            const float* pbh = pb_img + h*18432;
            float mc[4], lc[4];
#pragma unroll
            for (int c=0;c<4;c++){ mc[c] = pbh[c*4608 + t]; lc[c] = pbh[c*4608 + 256 + t]; }
            const float ms = fmaxf(fmaxf(mc[0],mc[1]), fmaxf(mc[2],mc[3]));
            float ls = 0.f;
#pragma unroll
            for (int c=0;c<4;c++){ wgt[h][c] = __expf(mc[c]-ms); ls += wgt[h][c]*lc[c]; }
            rl4[h] = 1.f/ls;
        }
        float s=0.f, ss=0.f;
#pragma unroll 4
        for (int c=0;c<64;c++){
            const int h = c>>4, d = c&15;
            const float* pa = pb_img + h*18432 + (2+d)*256 + t;
            const float v = (wgt[h][0]*pa[0] + wgt[h][1]*pa[4608]
                           + wgt[h][2]*pa[9216] + wgt[h][3]*pa[13824]) * rl4[h];
            mh_l[c*256 + t] = v;
            s += v; ss += v*v;
        }
        r1[t]=s; r2[t]=ss; __syncthreads();
        for (int st=128;st>0;st>>=1){ if(t<st){r1[t]+=r1[t+st]; r2[t]+=r2[t+st];} __syncthreads(); }
        if (t==0){
            const float m = r1[0]/16384.f;
            const float var = fmaxf(r2[0]/16384.f - m*m, 0.f);
            mh_s[0]=m; mh_s[1]=1.f/sqrtf(var+1e-5f);
        }
    }
    {
        const int c = t>>2, part4 = t&3;
        const float a = aA[c], b = aB[c];
        const float4* p4 = (const float4*)(fbr + c*256 + part4*64);
        float s=0.f, mx=-1e30f;
        for (int k=0;k<16;k++){
            const float4 v = p4[k];
            const float f0=lrelu(a*v.x+b), f1=lrelu(a*v.y+b), f2=lrelu(a*v.z+b), f3=lrelu(a*v.w+b);
            s += f0+f1+f2+f3;
            mx = fmaxf(mx, fmaxf(fmaxf(f0,f1),fmaxf(f2,f3)));
        }
        __syncthreads();
        r1[t]=s; r2[t]=mx;
        __syncthreads();
        if (t<64){
            favg[t] = (r1[t*4]+r1[t*4+1]+r1[t*4+2]+r1[t*4+3])/256.f;
            fmx[t]  = fmaxf(fmaxf(r2[t*4],r2[t*4+1]),fmaxf(r2[t*4+2],r2[t*4+3]));
        }
    }
    __syncthreads();
    if (t<8){
        const int which = t>>2, o = t&3;
        const float* f = which? fmx : favg;
        float z = b1[o];
        for (int c=0;c<64;c++) z += w1[o*64+c]*f[c];
        z1s[t] = fmaxf(z, 0.f);
    }
    __syncthreads();
    if (t<64){
        float z = 2.f*b2[t];
#pragma unroll
        for (int k=0;k<4;k++) z += w2[t*4+k]*(z1s[k]+z1s[4+k]);
        ca[t] = sigm(z);
    }
    __syncthreads();
    {
        float s=0.f, mx=-1e30f;
        for (int c=0;c<64;c++){
            const float fv = lrelu(aA[c]*fbr[c*256+t] + aB[c]);
            const float v = ca[c]*fv;
            s += v; mx = fmaxf(mx, v);
        }
        sf[t]     = s/64.f;
        sf[256+t] = mx;
    }
    __syncthreads();
    {
        float sacc = sb[0];
        const int y = t>>4, x = t&15;
        for (int ch=0; ch<2; ++ch)
          for (int ky=0; ky<7; ++ky){
            const int yy = y+ky-3;
            if (yy<0||yy>=16) continue;
            for (int kx=0; kx<7; ++kx){
                const int xx = x+kx-3;
                if (xx<0||xx>=16) continue;
                sacc += sf[ch*256 + yy*16 + xx]*wl[ch*49 + ky*7 + kx];
            }
          }
        sa_l[t] = sigm(sacc);
    }
    __syncthreads();
    {
        const int q = t & 63;
        const int cb = t >> 6;
        const float m = mh_s[0], istd = mh_s[1];
        const float4* fb4 = (const float4*)fbr;
        const float4* lg4 = (const float4*)lng;
        const float4* lb4 = (const float4*)lnb;
        float4* res4 = (float4*)(res + (size_t)img*16384);
        float*  qnb  = qn + (size_t)img*16384;
        const bool isq = (img < 64);       // block-uniform branch
        const float sa0=sa_l[4*q], sa1=sa_l[4*q+1], sa2=sa_l[4*q+2], sa3=sa_l[4*q+3];
#pragma unroll 4
        for (int cc=0; cc<16; ++cc){
            const int c = cb*16 + cc;
            const int i4 = c*64 + q;
            const float4 mv = *(const float4*)&mh_l[c*256 + q*4];
            const float4 fv = fb4[i4], gv = lg4[i4], bv = lb4[i4];
            const float a = aA[c], b = aB[c], cf = ca[c];
            float4 r;
            r.x = (mv.x-m)*istd*gv.x + bv.x + lrelu(a*fv.x+b)*(2.f + sa0*cf);
            r.y = (mv.y-m)*istd*gv.y + bv.y + lrelu(a*fv.y+b)*(2.f + sa1*cf);
            r.z = (mv.z-m)*istd*gv.z + bv.z + lrelu(a*fv.z+b)*(2.f + sa2*cf);
            r.w = (mv.w-m)*istd*gv.w + bv.w + lrelu(a*fv.w+b)*(2.f + sa3*cf);
            if (isq){
                // fused Q-normalize: wave cb holds all 256 px of channel c (lane q -> px 4q..4q+3)
                float ssq = r.x*r.x + r.y*r.y + r.z*r.z + r.w*r.w;
#pragma unroll
                for (int off=32; off>0; off>>=1) ssq += __shfl_xor(ssq, off);
                const float inv = 1.f/sqrtf(ssq);
                float4 o;
                o.x=r.x*inv; o.y=r.y*inv; o.z=r.z*inv; o.w=r.w*inv;
                *(float4*)(qnb + c*256 + q*4) = o;
            } else {
                res4[i4] = r;
            }
        }
    }
}

// ---------------- covariance ----------------
__global__ __launch_bounds__(256) void covmu_k(const float* __restrict__ res, float* __restrict__ mu)
{
    __shared__ float r1[256];
    const int n = blockIdx.x, c = blockIdx.y, t = threadIdx.x;
    float s=0.f;
    for (int sh=0; sh<5; ++sh)
        s += res[((size_t)(64 + n*5 + sh)*64 + c)*256 + t];
    r1[t]=s; __syncthreads();
    for (int st=128;st>0;st>>=1){ if(t<st) r1[t]+=r1[t+st]; __syncthreads(); }
    if (t==0) mu[n*64+c] = r1[0]/1280.f;
}

__global__ __launch_bounds__(256) void cov_k(const float* __restrict__ res, const float* __restrict__ mu,
                                             float* __restrict__ cov)
{
    __shared__ float Xl[64*129];   // 33 KB
    const int n = blockIdx.x, by = blockIdx.y, sh = blockIdx.z, t = threadIdx.x;
    const int c = by*16 + (t>>4);
    const int d0 = (t&15)*4;
    float acc[4] = {0.f,0.f,0.f,0.f};
    for (int half=0; half<2; ++half){
        __syncthreads();
        for (int idx=t; idx<8192; idx+=256){
            const int ch = idx>>7, p = idx&127;
            Xl[ch*129+p] = res[((size_t)(64+n*5+sh)*64 + ch)*256 + half*128 + p] - mu[n*64+ch];
        }
        __syncthreads();
        for (int p=0;p<128;p++){
            const float xc = Xl[c*129+p];
#pragma unroll
            for (int k=0;k<4;k++) acc[k] += xc*Xl[(d0+k)*129+p];
        }
    }
#pragma unroll
    for (int k=0;k<4;k++) atomicAdd(&cov[((size_t)n*64 + c)*64 + d0+k], acc[k]*(1.f/1279.f));
}

// ---------------- sim[b,j,i] = Qn(:,i)^T cov_j Qn(:,i) ----------------
__global__ __launch_bounds__(256) void sim_k(const float* __restrict__ qn, const float* __restrict__ cov,
                                             float* __restrict__ sim)
{
    __shared__ float covj[64*65];
    __shared__ float Vl[64*68];
    __shared__ float simred[320];
    const int b = blockIdx.x, iq = blockIdx.y, t = threadIdx.x;
    const int i0g = iq*64;
    for (int idx=t; idx<4096; idx+=256){
        const int c = idx>>6, il = idx&63;
        Vl[c*68+il] = qn[((size_t)b*64+c)*256 + i0g + il];
    }
    for (int idx=t; idx<320; idx+=256) simred[idx]=0.f;
    const int c0 = (t>>4)*4, i0 = (t&15)*4;
    for (int j=0;j<5;j++){
        __syncthreads();
        for (int idx=t; idx<4096; idx+=256)
            covj[(idx>>6)*65 + (idx&63)] = cov[(size_t)j*4096 + idx];
        __syncthreads();
        float pt[4][4];
#pragma unroll
        for (int a=0;a<4;a++)
#pragma unroll
          for (int bb=0;bb<4;bb++) pt[a][bb]=0.f;
        for (int d=0; d<64; ++d){
            const float4 vv = *(const float4*)&Vl[d*68 + i0];
            float cw[4];
#pragma unroll
            for (int cc=0;cc<4;cc++) cw[cc] = covj[(c0+cc)*65 + d];
#pragma unroll
            for (int cc=0;cc<4;cc++){
                pt[cc][0] += cw[cc]*vv.x;
                pt[cc][1] += cw[cc]*vv.y;
                pt[cc][2] += cw[cc]*vv.z;
                pt[cc][3] += cw[cc]*vv.w;
            }
        }
#pragma unroll
        for (int ii=0;ii<4;ii++){
            float s = 0.f;
#pragma unroll
            for (int cc=0;cc<4;cc++) s += pt[cc][ii]*Vl[(c0+cc)*68 + i0+ii];
            atomicAdd(&simred[j*64 + i0 + ii], s);
        }
    }
    __syncthreads();
    for (int idx=t; idx<320; idx+=256){
        const int j = idx>>6, il = idx&63;
        sim[((size_t)b*5 + j)*256 + i0g + il] = simred[idx];
    }
}

// ---------------- classifier ----------------
__global__ __launch_bounds__(256) void cls_k(const float* __restrict__ sim, const float* __restrict__ cw,
                                             float* __restrict__ out)
{
    __shared__ float red[256];
    const int b = blockIdx.x, t = threadIdx.x;
    const float w = cw[t];
    for (int j=0;j<5;j++){
        const float v = sim[((size_t)b*5 + j)*256 + t];
        red[t] = lrelu(v)*w;
        __syncthreads();
        for (int st=128;st>0;st>>=1){ if(t<st) red[t]+=red[t+st]; __syncthreads(); }
        if (t==0) out[b*5+j] = red[0];
        __syncthreads();
    }
}

// ---------------- launch ----------------
extern "C" void kernel_launch(void* const* d_in, const int* in_sizes, int n_in,
                              void* d_out, int out_size, void* d_ws, size_t ws_size,
                              hipStream_t stream)
{
    const float* IN[31];
    for (int i=0;i<31;i++) IN[i] = (const float*)d_in[i];
    float* W = (float*)d_ws;
    float* OUT = (float*)d_out;
    const unsigned short* WHp  = (const unsigned short*)(W + OFF_WH);
    const unsigned short* WLp  = (const unsigned short*)(W + OFF_WL);
    const unsigned short* WH3p = (const unsigned short*)(W + OFF_WH3);
    const unsigned short* WL3p = (const unsigned short*)(W + OFF_WL3);
    const unsigned short* WH4p = (const unsigned short*)(W + OFF_WH4);
    const unsigned short* WL4p = (const unsigned short*)(W + OFF_WL4);
    unsigned short* P1P = (unsigned short*)(W + OFF_P1);
    unsigned short* P2P = (unsigned short*)(W + OFF_P2);
    unsigned short* C3P = (unsigned short*)(W + OFF_C3P);

    prep_k<<<8074,256,0,stream>>>(IN[0],IN[1],IN[20],IN[21],IN[14],IN[16],IN[18],
                                  IN[5],IN[8],IN[11],W);

    // stage 1: conv1 stats-only -> fused recompute+BN+pool -> packed hi/lo bf16, channel-last
    conv3x3_k<64,64,1,1,4,4,false,false><<<dim3(89,16),256,0,stream>>>(W+OFF_X0, IN[2], nullptr, W+OFF_STATS, nullptr,nullptr,nullptr,0);
    bnpoolconv1_k<<<dim3(89,8),256,0,stream>>>(W+OFF_X0, IN[2], W+OFF_STATS, IN[3], IN[4], P1P);

    // stage 2: MFMA conv2 (pooled max/min + per-block stats, no atomics) -> per-image reduce -> pack
    conv2mfma_k<<<dim3(89,16),256,0,stream>>>(P1P, WHp, WLp, W+OFF_PMM, W+OFF_PBS);
    bnred_k<<<89,128,0,stream>>>(W+OFF_PBS, W+OFF_S2);
    bnpool_pack_k<<<dim3(89,2),256,0,stream>>>(W+OFF_PMM, W+OFF_S2, IN[6], IN[7], P2P);

    // stage 3: MFMA conv3 (+8-slot BN3 stats) -> raw C3; then BN3+lrelu pack -> C3PACK
    conv16mfma_k<<<dim3(89,4),256,0,stream>>>(P2P, WH3p, WL3p, W+OFF_C3, W+OFF_S3);
    c3pack_k<<<dim3(89,2),256,0,stream>>>(W+OFF_C3, W+OFF_S3, IN[9], IN[10], C3P);

    // stage 4: MFMA conv4 (+8-slot BN4 stats) -> raw C4 (BN4 applied inline by proj/post)
    conv16mfma_k<<<dim3(89,4),256,0,stream>>>(C3P, WH4p, WL4p, W+OFF_C4, W+OFF_S4);

    // MHSA (BN4 8-slot inline in proj); attention partials (4 j-chunks); merge fused into post_k
    proj_k<<<dim3(89,3),256,0,stream>>>(W+OFF_C4, W+OFF_WQT, IN[15], IN[17], IN[19],
                                        W+OFF_S4, IN[12], IN[13], W+OFF_CKV);
    attnp_k<<<dim3(89,4,4),256,0,stream>>>(W+OFF_CKV, W+OFF_POS, W+OFF_ATP);

    // fused partial-merge + mhsa-norm + CBAM + residual + Q-normalize
    post_k<<<89,256,0,stream>>>(W+OFF_ATP, IN[22], IN[23], W+OFF_C4,
                                W+OFF_S4, IN[12], IN[13],
                                IN[24], IN[25], IN[26], IN[27], IN[28], IN[29],
                                W+OFF_RES, W+OFF_QN);

    // covariance metric + classifier
    covmu_k<<<dim3(5,64),256,0,stream>>>(W+OFF_RES, W+OFF_MU);
    cov_k<<<dim3(5,4,5),256,0,stream>>>(W+OFF_RES, W+OFF_MU, W+OFF_COV);
    sim_k<<<dim3(64,4),256,0,stream>>>(W+OFF_QN, W+OFF_COV, W+OFF_SIM);
    cls_k<<<64,256,0,stream>>>(W+OFF_SIM, IN[30], OUT);
}

// Round 13
// 445.959 us; speedup vs baseline: 1.1441x; 1.0338x over previous
//
#include <hip/hip_runtime.h>
#include <hip/hip_bf16.h>

__device__ __forceinline__ float lrelu(float x){ return x >= 0.f ? x : 0.2f*x; }
__device__ __forceinline__ float sigm(float x){ return 1.f/(1.f+__expf(-x)); }

typedef short short8 __attribute__((ext_vector_type(8)));
typedef float f32x16 __attribute__((ext_vector_type(16)));

// ---------------- workspace layout (float offsets) ----------------
static constexpr size_t OFF_X0    = 0;          // 89*4096 = 364544
static constexpr size_t OFF_POS   = 475712;     // 16384  [h][i][d]
static constexpr size_t OFF_WQT   = 492096;     // 12288  [s][c][o]
static constexpr size_t OFF_STATS = 504384;     // stage1 single-slot sums (768)
static constexpr size_t OFF_P1    = 507456;     // P1PACK: 89*34*34*128 ushorts (ends 7,092,032)
static constexpr size_t OFF_P2    = 7092224;    // P2PACK: 89*18*18*128 ushorts (ends 8,937,728)
static constexpr size_t OFF_S3    = 8937728;    // BN3 sums: 8 slots * 768
static constexpr size_t OFF_S4    = 8943872;    // BN4 sums: 8 slots * 768
static constexpr size_t OFF_WH3   = 8950016;    // conv3 w hi  [9][och][cin]  (36864 ushorts)
static constexpr size_t OFF_WL3   = 8968448;
static constexpr size_t OFF_WH4   = 8986880;
static constexpr size_t OFF_WL4   = 9005312;    // ends 9,023,744
static constexpr size_t OFF_PBS   = 9023744;    // conv2 per-block stats [1424 slots][64 och][2] = 182,272
static constexpr size_t OFF_S2    = 9206016;    // BN2 group sums: 768 (atomic-accum, zeroed in prep)
static constexpr size_t OFF_RES   = 10714688;   // 89*64*256 (only imgs 64+ written/read)
static constexpr size_t OFF_MU    = 12172864;   // 320
static constexpr size_t OFF_COV   = 12173184;   // 5*64*64 (atomic-accumulated, zeroed in prep)
static constexpr size_t OFF_SIM   = 12193664;   // 64*5*256
static constexpr size_t OFF_R1    = 12275584;   // big overlaid region
static constexpr size_t OFF_PMM   = OFF_R1;                 // 89*64*16*32 pooled {16max|16min}
static constexpr size_t OFF_ATP   = OFF_R1;                 // attn partials (PMM dead by then)
static constexpr size_t OFF_C3    = OFF_R1 + 5832704;       // 89*64*256 (raw conv3)
static constexpr size_t OFF_C4    = OFF_R1 + 8749056;       // 89*64*256 (raw conv4)
static constexpr size_t OFF_CKV   = OFF_R1 + 10207232;      // 89*4*256*48 (packed {k,q,v})
static constexpr size_t OFF_C3P   = OFF_R1 + 10207232;      // C3PACK overlays CKV (dead until proj)
static constexpr size_t OFF_QN    = OFF_R1 + 17543680;      // 64*64*256 (written by post_k)
static constexpr size_t OFF_WH    = OFF_R1 + 21737984;      // conv2 w hi [9][och][cin]
static constexpr size_t OFF_WL    = OFF_WH + 18432;         // conv2 w lo

__device__ __forceinline__ int bn_group(int img){ return (img < 64) ? 0 : (1 + (img-64)/5); }

__device__ __forceinline__ void bn_ab(const float* __restrict__ sums, int g, int c, float n,
                                      float gw, float bw, float& a, float& b)
{
    const float sum = sums[(g*64+c)*2], ss = sums[(g*64+c)*2+1];
    const float m = sum/n;
    const float var = fmaxf(ss/n - m*m, 0.f);
    const float istd = 1.f/sqrtf(var + 1e-5f);
    a = gw*istd;
    b = bw - m*a;
}

// 8-slot variant (slots stride 768): BN3/BN4 accumulated by conv16mfma_k
__device__ __forceinline__ void bn_ab_s8(const float* __restrict__ sums, int g, int c, float n,
                                         float gw, float bw, float& a, float& b)
{
    float sum = 0.f, ss = 0.f;
#pragma unroll
    for (int s=0;s<8;s++){
        sum += sums[s*768 + (g*64+c)*2];
        ss  += sums[s*768 + (g*64+c)*2 + 1];
    }
    const float m = sum/n;
    const float var = fmaxf(ss/n - m*m, 0.f);
    const float istd = 1.f/sqrtf(var + 1e-5f);
    a = gw*istd;
    b = bw - m*a;
}

// ---------------- prep ----------------
__global__ __launch_bounds__(256) void prep_k(const float* __restrict__ in1, const float* __restrict__ in2,
        const float* __restrict__ relh, const float* __restrict__ relw,
        const float* __restrict__ wq, const float* __restrict__ wk, const float* __restrict__ wv,
        const float* __restrict__ cw2, const float* __restrict__ cw3, const float* __restrict__ cw4,
        float* __restrict__ ws)
{
    int idx = blockIdx.x*256 + threadIdx.x;
    if (idx < 364544) { ws[OFF_X0+idx] = (idx < 262144 ? in1[idx] : in2[idx-262144]); return; }
    idx -= 364544;
    if (idx < 16384) {
        const int h = idx>>12, r = idx&4095, i = r>>4, d = r&15;
        ws[OFF_POS+idx] = relh[h*256 + d*16 + (i&15)] + relw[h*256 + d*16 + (i>>4)];
        return;
    }
    idx -= 16384;
    if (idx < 12288) {
        const int s = idx/4096, r = idx%4096, c = r>>6, o = r&63;
        const float* wp = (s==0)?wq:((s==1)?wk:wv);
        ws[OFF_WQT+idx] = wp[o*64 + c];   // [s][c][o] = W[o][c]
        return;
    }
    idx -= 12288;
    if (idx < 3072) { ws[OFF_STATS+idx] = 0.f; return; }   // stage1 sums
    idx -= 3072;
    if (idx < 20480) { ws[OFF_COV+idx] = 0.f; return; }    // zero cov
    idx -= 20480;
    if (idx < 12288) { ws[OFF_S3+idx] = 0.f; return; }     // BN3 + BN4 8-slot sums (contiguous)
    idx -= 12288;
    if (idx < 768) { ws[OFF_S2+idx] = 0.f; return; }       // BN2 sums (atomic-accumulated by bnred_k)
    idx -= 768;
    if (idx < 110592) {                                    // conv2/3/4 weights -> bf16 hi/lo [k9][och][cin]
        const int which = idx / 36864, r0 = idx - which*36864;
        const int och = r0/576, rr = r0%576, cin = rr/9, k9 = rr%9;
        const float* cwp = (which==0)?cw2:((which==1)?cw3:cw4);
        const float v = cwp[r0];
        __hip_bfloat16 hb = __float2bfloat16(v);
        const float hv = __bfloat162float(hb);
        __hip_bfloat16 lb = __float2bfloat16(v - hv);
        const size_t oh = (which==0)?OFF_WH:((which==1)?OFF_WH3:OFF_WH4);
        const size_t ol = (which==0)?OFF_WL:((which==1)?OFF_WL3:OFF_WL4);
        unsigned short* WH = (unsigned short*)(ws + oh);
        unsigned short* WL = (unsigned short*)(ws + ol);
        const int d = k9*4096 + och*64 + cin;
        WH[d] = *(unsigned short*)&hb;
        WL[d] = *(unsigned short*)&lb;
        return;
    }
    idx -= 110592;
    if (idx < 751872) {                                    // zero P1PACK halo: 89 imgs * 132 pos * 64 floats
        const int img = idx/8448, r = idx%8448;
        const int pos = r>>6, d = r&63;
        int ypad, xpad;
        if (pos < 68){ ypad = (pos<34)?0:33; xpad = (pos<34)?pos:(pos-34); }
        else { const int q = pos-68; ypad = 1 + (q>>1); xpad = (q&1)*33; }
        ws[OFF_P1 + (((size_t)img*34 + ypad)*34 + xpad)*64 + d] = 0.f;
        return;
    }
    idx -= 751872;
    if (idx < 387328) {                                    // zero P2PACK halo: 89 imgs * 68 pos * 64 floats
        const int img = idx/4352, r = idx%4352;
        const int pos = r>>6, d = r&63;
        int ypad, xpad;
        if (pos < 36){ ypad = (pos<18)?0:17; xpad = (pos<18)?pos:(pos-18); }
        else { const int q = pos-36; ypad = 1 + (q>>1); xpad = (q&1)*17; }
        ws[OFF_P2 + (((size_t)img*18 + ypad)*18 + xpad)*64 + d] = 0.f;
        return;
    }
    idx -= 387328;
    if (idx < 387328) {                                    // zero C3PACK halo
        const int img = idx/4352, r = idx%4352;
        const int pos = r>>6, d = r&63;
        int ypad, xpad;
        if (pos < 36){ ypad = (pos<18)?0:17; xpad = (pos<18)?pos:(pos-18); }
        else { const int q = pos-36; ypad = 1 + (q>>1); xpad = (q&1)*17; }
        ws[OFF_C3P + (((size_t)img*18 + ypad)*18 + xpad)*64 + d] = 0.f;
    }
}

// ---------------- direct 3x3 conv (fp32) — now only conv1 stats -------------------
template<int H, int W, int CIN, int CH, int OCB, int PT, bool STORE, bool INBN>
__global__ __launch_bounds__(256) void conv3x3_k(const float* __restrict__ in,
                                                 const float* __restrict__ wt,
                                                 float* __restrict__ out,
                                                 float* __restrict__ bnsum,
                                                 const float* __restrict__ isums,
                                                 const float* __restrict__ igw,
                                                 const float* __restrict__ ibw,
                                                 int ihw)
{
    constexpr int P = W + 1;
    constexpr int PLANE = H * P;
    constexpr int HW = H * W;
    constexpr int PASSES = HW / (256 * PT);
    constexpr int NLD = CH * HW / 256;
    __shared__ float lds[CH * PLANE];
    __shared__ float redS[OCB*4], redQ[OCB*4];
    __shared__ float abA[64], abB[64];
    const int img = blockIdx.x;
    const int och0 = blockIdx.y * OCB;
    const int t = threadIdx.x;

    if constexpr (INBN) {
        if (t < CIN) {
            const int gi = bn_group(img);
            const float nin = (float)(((gi==0)?64:5) * ihw);
            float a, b;
            bn_ab(isums, gi, t, nin, igw[t], ibw[t], a, b);
            abA[t]=a; abB[t]=b;
        }
        __syncthreads();
    }

    float acc[PASSES][OCB][PT];
#pragma unroll
    for (int a=0;a<PASSES;a++)
#pragma unroll
      for (int o=0;o<OCB;o++)
#pragma unroll
        for (int p=0;p<PT;p++) acc[a][o][p]=0.f;

    for (int idx = t; idx < CH*HW; idx += 256) {
        const int c = idx / HW, p = idx % HW;
        float v = in[((size_t)img*CIN + c)*HW + p];
        if constexpr (INBN) v = lrelu(abA[c]*v + abB[c]);
        lds[c*PLANE + (p/W)*P + (p%W)] = v;
    }
    __syncthreads();

    for (int cc0 = 0; cc0 < CIN; cc0 += CH) {
        float pre[(CIN > CH) ? NLD : 1];
        if constexpr (CIN > CH) {
            if (cc0 + CH < CIN) {
#pragma unroll
                for (int j=0;j<NLD;j++){
                    const int idx = j*256 + t;
                    const int c = idx / HW, p = idx % HW;
                    pre[j] = in[((size_t)img*CIN + cc0 + CH + c)*HW + p];
                }
            }
        }
        for (int c = 0; c < CH; ++c) {
            float wr[OCB][9];
#pragma unroll
            for (int o=0;o<OCB;o++)
#pragma unroll
              for (int k=0;k<9;k++)
                wr[o][k] = wt[((size_t)(och0+o)*CIN + (cc0+c))*9 + k];
            const float* Lc = lds + c*PLANE;
#pragma unroll
            for (int ps=0; ps<PASSES; ++ps) {
                const int px0 = (ps*256 + t)*PT;
                const int y = px0 / W, x0 = px0 % W;
#pragma unroll
                for (int ky=0; ky<3; ++ky) {
                    const int yy = y + ky - 1;
                    if (yy >= 0 && yy < H) {
                        const float* Lr = Lc + yy*P;
                        float r[PT+2];
                        r[0] = (x0 > 0) ? Lr[x0-1] : 0.f;
#pragma unroll
                        for (int k2=0;k2<PT;k2++) r[k2+1] = Lr[x0+k2];
                        r[PT+1] = (x0+PT < W) ? Lr[x0+PT] : 0.f;
#pragma unroll
                        for (int p=0;p<PT;p++)
#pragma unroll
                          for (int kx=0;kx<3;kx++) {
                              const float v = r[p+kx];
#pragma unroll
                              for (int o=0;o<OCB;o++)
                                  acc[ps][o][p] += v * wr[o][ky*3+kx];
                          }
                    }
                }
            }
        }
        if constexpr (CIN > CH) {
            if (cc0 + CH < CIN) {
                __syncthreads();
#pragma unroll
                for (int j=0;j<NLD;j++){
                    const int idx = j*256 + t;
                    const int c = idx / HW, p = idx % HW;
                    float v = pre[j];
                    if constexpr (INBN) v = lrelu(abA[cc0+CH+c]*v + abB[cc0+CH+c]);
                    lds[c*PLANE + (p/W)*P + (p%W)] = v;
                }
                __syncthreads();
            }
        }
    }
    if constexpr (STORE) {
#pragma unroll
        for (int ps=0; ps<PASSES; ++ps) {
            const int px0 = (ps*256 + t)*PT;
#pragma unroll
            for (int o=0;o<OCB;o++)
#pragma unroll
              for (int p=0;p<PT;p++)
                out[((size_t)img*64 + och0+o)*HW + px0 + p] = acc[ps][o][p];
        }
    }
    const int g = bn_group(img);
    const int wv = t >> 6;
#pragma unroll
    for (int o=0;o<OCB;o++){
        float s=0.f, ss=0.f;
#pragma unroll
        for (int ps=0;ps<PASSES;ps++)
#pragma unroll
          for (int p=0;p<PT;p++){ const float v=acc[ps][o][p]; s+=v; ss+=v*v; }
#pragma unroll
        for (int off=32; off>0; off>>=1){ s += __shfl_xor(s, off); ss += __shfl_xor(ss, off); }
        if ((t&63)==0){ redS[o*4+wv]=s; redQ[o*4+wv]=ss; }
    }
    __syncthreads();
    if (t < OCB*2){
        const int o = t>>1, metric = t&1;
        const float v = metric ? (redQ[o*4]+redQ[o*4+1]+redQ[o*4+2]+redQ[o*4+3])
                               : (redS[o*4]+redS[o*4+1]+redS[o*4+2]+redS[o*4+3]);
        atomicAdd(&bnsum[(g*64 + och0+o)*2 + metric], v);
    }
}

// ---------------- stage 1 fused: conv1+BN+lrelu+2x2 maxpool -> P1PACK ---------------------------
__global__ __launch_bounds__(256) void bnpoolconv1_k(const float* __restrict__ x0,
        const float* __restrict__ cw, const float* __restrict__ sums,
        const float* __restrict__ gw, const float* __restrict__ bw,
        unsigned short* __restrict__ p1p)
{
    __shared__ float xl[10*64];
    __shared__ float wsm[576];
    __shared__ float aAs[64], aBs[64];
    const int img = blockIdx.x, band = blockIdx.y, t = threadIdx.x;
    const int oy0 = band*4;
    const float* xp = x0 + (size_t)img*4096;
    for (int idx=t; idx<640; idx+=256){
        const int iy = idx>>6, ix = idx&63;
        const int gy = 2*oy0 - 1 + iy;
        xl[idx] = (gy>=0 && gy<64) ? xp[gy*64+ix] : 0.f;
    }
    const int g = bn_group(img);
    if (t < 64){
        const float n = (float)(((g==0)?64:5) * 4096);
        float a, b;
        bn_ab(sums, g, t, n, gw[t], bw[t], a, b);
        aAs[t]=a; aBs[t]=b;
    }
    for (int idx=t; idx<576; idx+=256) wsm[idx] = cw[idx];
    __syncthreads();
    const int p = t>>1, half = t&1;
    const int ly = p>>5, ox = p&31;
    float r[4][4];
#pragma unroll
    for (int dy=0;dy<4;dy++){
        const float* Lr = xl + (2*ly+dy)*64;
#pragma unroll
        for (int dx=0;dx<4;dx++){
            const int xx = 2*ox-1+dx;
            r[dy][dx] = (xx>=0 && xx<64) ? Lr[xx] : 0.f;
        }
    }
    short8 hv[4], lv[4];
#pragma unroll
    for (int o=0;o<32;o++){
        const int och = half*32 + o;
        float w[9];
#pragma unroll
        for (int k=0;k<9;k++) w[k] = wsm[och*9+k];    // LDS broadcast (2 addrs/wave)
        const float a = aAs[och], b = aBs[och];
        float best = -1e30f;
#pragma unroll
        for (int sy=0;sy<2;sy++)
#pragma unroll
          for (int sx=0;sx<2;sx++){
            float s=0.f;
#pragma unroll
            for (int ky=0;ky<3;ky++)
#pragma unroll
              for (int kx=0;kx<3;kx++) s += r[sy+ky][sx+kx]*w[ky*3+kx];
            best = fmaxf(best, lrelu(a*s+b));
          }
        __hip_bfloat16 hb = __float2bfloat16(best);
        const float hf = __bfloat162float(hb);
        __hip_bfloat16 lb = __float2bfloat16(best - hf);
        hv[o>>3][o&7] = (short)*(unsigned short*)&hb;
        lv[o>>3][o&7] = (short)*(unsigned short*)&lb;
    }
    const size_t base = ((((size_t)img*34 + (oy0+ly) + 1)*34) + ox + 1)*128 + half*32;
#pragma unroll
    for (int j=0;j<4;j++){
        *(short8*)(p1p + base + j*8)      = hv[j];
        *(short8*)(p1p + base + 64 + j*8) = lv[j];
    }
}

// ---------------- conv2 via MFMA — 1D grid + XCD-chunked swizzle for halo L2 reuse --------------
// Work w = img*16 + rowblk; b -> w = (b&7)*178 + (b>>3) puts contiguous work (halo-sharing
// neighbor rowblks, same img) on one XCD's L2 under round-robin dispatch. 1424 = 8*178.
__global__ __launch_bounds__(256) void conv2mfma_k(const unsigned short* __restrict__ p1p,
        const unsigned short* __restrict__ whi, const unsigned short* __restrict__ wlo,
        float* __restrict__ pmm, float* __restrict__ pbs)
{
    __shared__ __align__(16) unsigned short Bx[136*128];   // 34,816 B -> 4 blocks/CU
    const int b = blockIdx.x;
    const int w = (b & 7)*178 + (b >> 3);
    const int img = w >> 4, rowblk = w & 15;               // rowblk 0..15 -> 2 rows = 1 pooled row
    const int t = threadIdx.x;
    {
        const unsigned short* src = p1p + (((size_t)img*34 + rowblk*2)*34)*128;
        for (int idx=t; idx<2176; idx+=256){               // 136 pos * 16 chunks of 16B
            const int pos = idx>>4, sub = idx&15;
            const short8 v = *(const short8*)(src + pos*128 + sub*8);
            *(short8*)(Bx + pos*128 + ((sub ^ (pos&15))<<3)) = v;
        }
    }
    __syncthreads();
    const int lane = t & 63, wv = t >> 6;
    const int mt = wv & 1, ntp = wv >> 1;                  // 2 och-halves x 2 px-rows
    const int m = lane & 31, kg = lane >> 5;
    f32x16 accA, accB, accC;                               // 3 independent chains
#pragma unroll
    for (int r=0;r<16;r++){ accA[r]=0.f; accB[r]=0.f; accC[r]=0.f; }

#pragma unroll
    for (int ky=0; ky<3; ky++){
#pragma unroll
      for (int kx=0; kx<3; kx++){
        const int s = ky*3 + kx;
        const unsigned short* wh = whi + ((s*64 + mt*32 + m)<<6) + kg*8;
        const unsigned short* wl = wlo + ((s*64 + mt*32 + m)<<6) + kg*8;
        const int pos = (ntp+ky)*34 + m + kx;
        const int pb  = pos << 7;
        const int sw  = (pos & 15) << 3;
#pragma unroll
        for (int ch=0; ch<4; ch++){
            const int o = ch*16 + (kg<<3);
            const short8 ah = *(const short8*)(wh + ch*16);
            const short8 al = *(const short8*)(wl + ch*16);
            const short8 bh = *(const short8*)(Bx + pb + (o ^ sw));
            const short8 bl = *(const short8*)(Bx + pb + ((64 + o) ^ sw));
            accA = __builtin_amdgcn_mfma_f32_32x32x16_bf16(ah, bh, accA, 0,0,0);
            accB = __builtin_amdgcn_mfma_f32_32x32x16_bf16(al, bh, accB, 0,0,0);
            accC = __builtin_amdgcn_mfma_f32_32x32x16_bf16(ah, bl, accC, 0,0,0);
        }
      }
    }
    float fa[16];
#pragma unroll
    for (int r=0;r<16;r++) fa[r] = accA[r] + accB[r] + accC[r];

    // stash both rows in LDS (stride 33 -> bank-spread), then pool + stats per 4-lane quad
    __syncthreads();                       // all MFMA reads of Bx complete
    float* Bxf = (float*)Bx;               // [2 rows][64 och][33] = 16.9 KB
#pragma unroll
    for (int r=0; r<16; r++){
        const int och = mt*32 + (r&3) + 8*(r>>2) + 4*kg;
        Bxf[(ntp*64 + och)*33 + m] = fa[r];
    }
    __syncthreads();
    {
        const int och = t>>2, q4 = t&3;    // 64 och x 4 quads
        const int c0 = q4*8;               // 8 raw cols per quad-thread
        const float* r0 = Bxf + och*33 + c0;
        const float* r1 = Bxf + (64+och)*33 + c0;
        float4 mxv, mnv;
        float* mxp = (float*)&mxv; float* mnp = (float*)&mnv;
        float s = 0.f, q = 0.f;
#pragma unroll
        for (int k=0;k<4;k++){
            const float a0 = r0[2*k], a1 = r0[2*k+1], b0 = r1[2*k], b1 = r1[2*k+1];
            mxp[k] = fmaxf(fmaxf(a0,a1), fmaxf(b0,b1));
            mnp[k] = fminf(fminf(a0,a1), fminf(b0,b1));
            s += a0+a1+b0+b1;
            q += a0*a0+a1*a1+b0*b0+b1*b1;
        }
        float* base = pmm + (((size_t)img*64 + och)*16 + rowblk)*32;
        *(float4*)(base + q4*4)      = mxv;
        *(float4*)(base + 16 + q4*4) = mnv;
        s += __shfl_xor(s, 1); q += __shfl_xor(q, 1);
        s += __shfl_xor(s, 2); q += __shfl_xor(q, 2);
        if (q4 == 0){
            float* pb = pbs + (size_t)(img*16 + rowblk)*128 + och*2;
            pb[0] = s; pb[1] = q;
        }
    }
}

// ---------------- reduce conv2 per-block stats -> BN2 group sums ------------------------------
__global__ __launch_bounds__(128) void bnred_k(const float* __restrict__ pbs, float* __restrict__ sums)
{
    const int img = blockIdx.x, t = threadIdx.x;   // t<128: och=t>>1, metric=t&1
    const int och = t>>1, metric = t&1;
    const float* p = pbs + (size_t)img*16*128 + och*2 + metric;
    float s = 0.f;
#pragma unroll
    for (int rb=0; rb<16; rb++) s += p[rb*128];
    const int g = bn_group(img);
    atomicAdd(&sums[(g*64+och)*2 + metric], s);
}

// ---------------- stage-2 BN + lrelu + pooled-select -> P2PACK (hi/lo bf16, channel-last) -------
__global__ __launch_bounds__(256) void bnpool_pack_k(const float* __restrict__ pmm,
        const float* __restrict__ sums, const float* __restrict__ gw, const float* __restrict__ bw,
        unsigned short* __restrict__ p2p)
{
    __shared__ float aA[64], aB[64];
    const int img = blockIdx.x, cb = blockIdx.y, t = threadIdx.x;
    const int g = bn_group(img);
    if (t < 64){
        const float n = (float)(((g==0)?64:5) * 1024);
        float a, b;
        bn_ab(sums, g, t, n, gw[t], bw[t], a, b);
        aA[t]=a; aB[t]=b;
    }
    __syncthreads();
    const int oy = t>>4, ox = t&15;
    short8 hv[4], lv[4];
#pragma unroll
    for (int j8=0;j8<4;j8++){
#pragma unroll
      for (int e=0;e<8;e++){
        const int j = j8*8 + e;
        const int c = cb*32 + j;
        const float a = aA[c], b = aB[c];
        const size_t o = (((size_t)img*64 + c)*16 + oy)*32 + ox + (a >= 0.f ? 0 : 16);
        const float best = lrelu(a*pmm[o] + b);
        __hip_bfloat16 hb = __float2bfloat16(best);
        const float hf = __bfloat162float(hb);
        __hip_bfloat16 lb = __float2bfloat16(best - hf);
        hv[j8][e] = (short)*(unsigned short*)&hb;
        lv[j8][e] = (short)*(unsigned short*)&lb;
      }
    }
    unsigned short* dst = p2p + (((size_t)img*18 + oy+1)*18 + ox+1)*128 + cb*32;
#pragma unroll
    for (int j=0;j<4;j++){
        *(short8*)(dst + j*8)      = hv[j];
        *(short8*)(dst + 64 + j*8) = lv[j];
    }
}

// ---------------- 16x16 64->64 3x3 conv via MFMA (conv3 & conv4), XCD-chunked swizzle -----------
// 356 blocks = 8*44 + 4; bijective chunked map (m204 form), work w = img*4 + rowblk.
__global__ __launch_bounds__(256) void conv16mfma_k(const unsigned short* __restrict__ pack,
        const unsigned short* __restrict__ whi, const unsigned short* __restrict__ wlo,
        float* __restrict__ out, float* __restrict__ bnsum)
{
    __shared__ __align__(16) unsigned short Bx[108*128];   // 27,648 B (6 padded rows x 18 cols)
    const int b = blockIdx.x;
    const int xcd = b & 7, posb = b >> 3;                  // q=44, r=4
    const int w = ((xcd < 4) ? xcd*45 : 180 + (xcd-4)*44) + posb;
    const int img = w >> 2, rowblk = w & 3;                // rowblk 0..3 -> 4 output rows
    const int t = threadIdx.x;
    {
        const unsigned short* src = pack + (((size_t)img*18 + rowblk*4)*18)*128;
        for (int idx=t; idx<1728; idx+=256){
            const int pos = idx>>4, sub = idx&15;
            const short8 v = *(const short8*)(src + pos*128 + sub*8);
            *(short8*)(Bx + pos*128 + ((sub ^ (pos&15))<<3)) = v;
        }
    }
    __syncthreads();
    const int lane = t & 63, wv = t >> 6;
    const int mt = wv & 1, np = wv >> 1;
    const int m = lane & 31, kg = lane >> 5;
    f32x16 accA, accB, accC;
#pragma unroll
    for (int r=0;r<16;r++){ accA[r]=0.f; accB[r]=0.f; accC[r]=0.f; }

#pragma unroll
    for (int ky=0; ky<3; ky++){
#pragma unroll
      for (int kx=0; kx<3; kx++){
        const int s = ky*3 + kx;
        const unsigned short* wh = whi + ((s*64 + mt*32 + m)<<6) + kg*8;
        const unsigned short* wl = wlo + ((s*64 + mt*32 + m)<<6) + kg*8;
        const int pos = (np*2 + (m>>4) + ky)*18 + (m&15) + kx;
        const int pb  = pos << 7;
        const int sw  = (pos & 15) << 3;
#pragma unroll
        for (int ch=0; ch<4; ch++){
            const int o = ch*16 + (kg<<3);
            const short8 ah = *(const short8*)(wh + ch*16);
            const short8 al = *(const short8*)(wl + ch*16);
            const short8 bh = *(const short8*)(Bx + pb + (o ^ sw));
            const short8 bl = *(const short8*)(Bx + pb + ((64 + o) ^ sw));
            accA = __builtin_amdgcn_mfma_f32_32x32x16_bf16(ah, bh, accA, 0,0,0);
            accB = __builtin_amdgcn_mfma_f32_32x32x16_bf16(al, bh, accB, 0,0,0);
            accC = __builtin_amdgcn_mfma_f32_32x32x16_bf16(ah, bl, accC, 0,0,0);
        }
      }
    }
    float* co = out + (size_t)img*16384 + rowblk*64 + np*32 + m;
    float fa[16];
#pragma unroll
    for (int r=0; r<16; r++){
        fa[r] = accA[r] + accB[r] + accC[r];
        const int och = mt*32 + (r&3) + 8*(r>>2) + 4*kg;
        co[(size_t)och*256] = fa[r];
    }
    const int g = bn_group(img);
    float* bs = bnsum + (rowblk*2 + np)*768;
#pragma unroll
    for (int r=0; r<16; r++){
        float sv = fa[r], qv = fa[r]*fa[r];
#pragma unroll
        for (int off=16; off>0; off>>=1){ sv += __shfl_xor(sv, off); qv += __shfl_xor(qv, off); }
        if (m == r){
            const int och = mt*32 + (r&3) + 8*(r>>2) + 4*kg;
            atomicAdd(&bs[(g*64+och)*2],   sv);
            atomicAdd(&bs[(g*64+och)*2+1], qv);
        }
    }
}

// ---------------- C3 raw + BN3 -> lrelu -> C3PACK (hi/lo bf16, channel-last) -------------------
__global__ __launch_bounds__(256) void c3pack_k(const float* __restrict__ c3,
        const float* __restrict__ s3, const float* __restrict__ gw, const float* __restrict__ bw,
        unsigned short* __restrict__ c3p)
{
    __shared__ float aA[64], aB[64];
    const int img = blockIdx.x, cb = blockIdx.y, t = threadIdx.x;
    const int g = bn_group(img);
    if (t < 64){
        const float n = (float)(((g==0)?64:5) * 256);
        float a, b;
        bn_ab_s8(s3, g, t, n, gw[t], bw[t], a, b);
        aA[t]=a; aB[t]=b;
    }
    __syncthreads();
    const float* pim = c3 + (size_t)img*16384 + (size_t)cb*8192 + t;
    short8 hv[4], lv[4];
#pragma unroll
    for (int j8=0;j8<4;j8++){
#pragma unroll
      for (int e=0;e<8;e++){
        const int j = j8*8 + e;
        const int c = cb*32 + j;
        const float v = lrelu(aA[c]*pim[(size_t)j*256] + aB[c]);
        __hip_bfloat16 hb = __float2bfloat16(v);
        const float hf = __bfloat162float(hb);
        __hip_bfloat16 lb = __float2bfloat16(v - hf);
        hv[j8][e] = (short)*(unsigned short*)&hb;
        lv[j8][e] = (short)*(unsigned short*)&lb;
      }
    }
    const int oy = t>>4, ox = t&15;
    unsigned short* dst = c3p + (((size_t)img*18 + oy+1)*18 + ox+1)*128 + cb*32;
#pragma unroll
    for (int j=0;j<4;j++){
        *(short8*)(dst + j*8)      = hv[j];
        *(short8*)(dst + 64 + j*8) = lv[j];
    }
}

// ---------------- MHSA projection: raw C4 in (BN4 8-slot inline) -> ckv ------------------------
__global__ __launch_bounds__(256) void proj_k(const float* __restrict__ c4, const float* __restrict__ wT,
               const float* __restrict__ bq, const float* __restrict__ bk, const float* __restrict__ bv,
               const float* __restrict__ sums4, const float* __restrict__ gw4, const float* __restrict__ bw4,
               float* __restrict__ ckv)
{
    __shared__ float xl[64*256];   // 64 KB exactly
    const int img = blockIdx.x, s = blockIdx.y, t = threadIdx.x;
    const int gi = bn_group(img);
    const float nin = (float)(((gi==0)?64:5) * 256);
    {
        const float4* in4 = (const float4*)(c4 + (size_t)img*16384);
        float4* xl4 = (float4*)xl;
        for (int i=t; i<4096; i+=256){
            float4 v = in4[i];
            const int c = i>>6;     // wave-uniform
            float a, b;
            bn_ab_s8(sums4, gi, c, nin, gw4[c], bw4[c], a, b);
            v.x=lrelu(a*v.x+b); v.y=lrelu(a*v.y+b); v.z=lrelu(a*v.z+b); v.w=lrelu(a*v.w+b);
            xl4[i] = v;
        }
    }
    const float* bias = (s==0)?bq:((s==1)?bk:bv);
    const int sofs = (s==0)?16:((s==1)?0:32);
    const float* wp = wT + s*4096;
    const int o0 = (t>>4)*4, i0 = (t&15)*16;
    const int h = o0>>4, d0 = o0&15;
    __syncthreads();
    float acc[4][16];
    float b0[4];
#pragma unroll
    for (int o=0;o<4;o++) b0[o]=bias[o0+o];
#pragma unroll
    for (int o=0;o<4;o++)
#pragma unroll
      for (int i=0;i<16;i++) acc[o][i]=b0[o];
    for (int c=0;c<64;c++){
        const float4 w4 = *(const float4*)(wp + c*64 + o0);
        const float* xr = xl + c*256 + i0;
#pragma unroll
        for (int k=0;k<4;k++){
            const float4 x4 = *(const float4*)(xr + 4*k);
            acc[0][4*k+0]+=w4.x*x4.x; acc[0][4*k+1]+=w4.x*x4.y; acc[0][4*k+2]+=w4.x*x4.z; acc[0][4*k+3]+=w4.x*x4.w;
            acc[1][4*k+0]+=w4.y*x4.x; acc[1][4*k+1]+=w4.y*x4.y; acc[1][4*k+2]+=w4.y*x4.z; acc[1][4*k+3]+=w4.y*x4.w;
            acc[2][4*k+0]+=w4.z*x4.x; acc[2][4*k+1]+=w4.z*x4.y; acc[2][4*k+2]+=w4.z*x4.z; acc[2][4*k+3]+=w4.z*x4.w;
            acc[3][4*k+0]+=w4.w*x4.x; acc[3][4*k+1]+=w4.w*x4.y; acc[3][4*k+2]+=w4.w*x4.z; acc[3][4*k+3]+=w4.w*x4.w;
        }
    }
#pragma unroll
    for (int ii=0;ii<16;ii++){
        const float4 v = make_float4(acc[0][ii],acc[1][ii],acc[2][ii],acc[3][ii]);
        *(float4*)(ckv + (((size_t)img*4 + h)*256 + i0+ii)*48 + sofs + d0) = v;
    }
}

// ---------------- attention partial: j-chunk flash pass (4 chunks of 64 j) ----------------------
__global__ __launch_bounds__(256) void attnp_k(const float* __restrict__ ckv, const float* __restrict__ pos,
                               float* __restrict__ part)
{
    const int img = blockIdx.x, h = blockIdx.y, jc = blockIdx.z, i = threadIdx.x;
    const size_t jb = (((size_t)img*4 + h)*256)*48;
    float areg[32];
    {
        const float* myrow = ckv + jb + (size_t)i*48;
#pragma unroll
        for (int k=0;k<4;k++) *(float4*)&areg[4*k]    = *(const float4*)(myrow + 16 + 4*k);
#pragma unroll
        for (int k=0;k<4;k++) *(float4*)&areg[16+4*k] = *(const float4*)(pos + h*4096 + i*16 + 4*k);
    }
    float mrun = -1e30f, l = 0.f;
    float accv[16];
#pragma unroll
    for (int d=0;d<16;d++) accv[d]=0.f;

    const int jend = jc*64 + 64;
    for (int j0=jc*64; j0<jend; j0+=2){
        const float* r0 = ckv + jb + (size_t)j0*48;
        const float* r1 = r0 + 48;
        float s0a=0.f, s0b=0.f, s1a=0.f, s1b=0.f;
#pragma unroll
        for (int dd=0; dd<16; ++dd){
            s0a += areg[2*dd]  *r0[2*dd];
            s0b += areg[2*dd+1]*r0[2*dd+1];
            s1a += areg[2*dd]  *r1[2*dd];
            s1b += areg[2*dd+1]*r1[2*dd+1];
        }
        const float s0 = s0a+s0b, s1 = s1a+s1b;
        const float mnew = fmaxf(mrun, fmaxf(s0,s1));
        const float al = __expf(mrun - mnew);
        const float e0 = __expf(s0 - mnew), e1 = __expf(s1 - mnew);
        mrun = mnew;
        l = l*al + e0 + e1;
        const float* v0 = r0 + 32;
        const float* v1 = r1 + 32;
#pragma unroll
        for (int d=0;d<16;d++) accv[d] = accv[d]*al + e0*v0[d] + e1*v1[d];
    }
    float* pp = part + ((((size_t)img*4 + h)*4 + jc)*18)*256;
    pp[i]       = mrun;
    pp[256 + i] = l;
#pragma unroll
    for (int d=0;d<16;d++) pp[(2+d)*256 + i] = accv[d];
}

// ---------------- fused post-attention: partial-merge + mhsa-norm + CBAM + residual + Q-norm ----
__global__ __launch_bounds__(256) void post_k(const float* __restrict__ part,
        const float* __restrict__ lng, const float* __restrict__ lnb,
        const float* __restrict__ c4,
        const float* __restrict__ sums4, const float* __restrict__ gw4, const float* __restrict__ bw4,
        const float* __restrict__ w1, const float* __restrict__ b1,
        const float* __restrict__ w2, const float* __restrict__ b2,
        const float* __restrict__ sw, const float* __restrict__ sb,
        float* __restrict__ res, float* __restrict__ qn)
{
    __shared__ float mh_l[16384];          // 64 KB merged attention [c][i]
    __shared__ float r1[256], r2[256];
    __shared__ float favg[64], fmx[64], z1s[8], ca[64];
    __shared__ float sf[512];
    __shared__ float wl[98];
    __shared__ float mh_s[2];
    __shared__ float aA[64], aB[64];
    __shared__ float sa_l[256];
    const int img = blockIdx.x, t = threadIdx.x;
    const float* fbr = c4 + (size_t)img*16384;
    const float* pb_img = part + (size_t)img*73728;   // 4h * 4jc * 18 * 256

    if (t<64){
        const int gi = bn_group(img);
        const float nin = (float)(((gi==0)?64:5) * 256);
        float a, b;
        bn_ab_s8(sums4, gi, t, nin, gw4[t], bw4[t], a, b);
        aA[t]=a; aB[t]=b;
    }
    if (t<98) wl[t] = sw[t];

    // merge 4 j-chunk partials (i = t) + accumulate mean/var of merged output
    {
        float wgt[4][4], rl4[4];
#pragma unroll
        for (int h=0;h<4;h++){
            const float* pbh = pb_img + h*18432;
            float mc[4], lc[4];
#pragma unroll
            for (int c=0;c<4;c++){ mc[c] = pbh[c*4608 + t]; lc[c] = pbh[c*4608 + 256 + t]; }
            const float ms = fmaxf(fmaxf(mc[0],mc[1]), fmaxf(mc[2],mc[3]));
            float ls = 0.f;
#pragma unroll
            for (int c=0;c<4;c++){ wgt[h][c] = __expf(mc[c]-ms); ls += wgt[h][c]*lc[c]; }
            rl4[h] = 1.f/ls;
        }
        float s=0.f, ss=0.f;
#pragma unroll 4
        for (int c=0;c<64;c++){
            const int h = c>>4, d = c&15;
            const float* pa = pb_img + h*18432 + (2+d)*256 + t;
            const float v = (wgt[h][0]*pa[0] + wgt[h][1]*pa[4608]
                           + wgt[h][2]*pa[9216] + wgt[h][3]*pa[13824]) * rl4[h];
            mh_l[c*256 + t] = v;
            s += v; ss += v*v;
        }
        r1[t]=s; r2[t]=ss; __syncthreads();
        for (int st=128;st>0;st>>=1){ if(t<st){r1[t]+=r1[t+st]; r2[t]+=r2[t+st];} __syncthreads(); }
        if (t==0){
            const float m = r1[0]/16384.f;
            const float var = fmaxf(r2[0]/16384.f - m*m, 0.f);
            mh_s[0]=m; mh_s[1]=1.f/sqrtf(var+1e-5f);
        }
    }
    {
        const int c = t>>2, part4 = t&3;
        const float a = aA[c], b = aB[c];
        const float4* p4 = (const float4*)(fbr + c*256 + part4*64);
        float s=0.f, mx=-1e30f;
        for (int k=0;k<16;k++){
            const float4 v = p4[k];
            const float f0=lrelu(a*v.x+b), f1=lrelu(a*v.y+b), f2=lrelu(a*v.z+b), f3=lrelu(a*v.w+b);
            s += f0+f1+f2+f3;
            mx = fmaxf(mx, fmaxf(fmaxf(f0,f1),fmaxf(f2,f3)));
        }
        __syncthreads();
        r1[t]=s; r2[t]=mx;
        __syncthreads();
        if (t<64){
            favg[t] = (r1[t*4]+r1[t*4+1]+r1[t*4+2]+r1[t*4+3])/256.f;
            fmx[t]  = fmaxf(fmaxf(r2[t*4],r2[t*4+1]),fmaxf(r2[t*4+2],r2[t*4+3]));
        }
    }
    __syncthreads();
    if (t<8){
        const int which = t>>2, o = t&3;
        const float* f = which? fmx : favg;
        float z = b1[o];
        for (int c=0;c<64;c++) z += w1[o*64+c]*f[c];
        z1s[t] = fmaxf(z, 0.f);
    }
    __syncthreads();
    if (t<64){
        float z = 2.f*b2[t];
#pragma unroll
        for (int k=0;k<4;k++) z += w2[t*4+k]*(z1s[k]+z1s[4+k]);
        ca[t] = sigm(z);
    }
    __syncthreads();
    {
        float s=0.f, mx=-1e30f;
        for (int c=0;c<64;c++){
            const float fv = lrelu(aA[c]*fbr[c*256+t] + aB[c]);
            const float v = ca[c]*fv;
            s += v; mx = fmaxf(mx, v);
        }
        sf[t]     = s/64.f;
        sf[256+t] = mx;
    }
    __syncthreads();
    {
        float sacc = sb[0];
        const int y = t>>4, x = t&15;
        for (int ch=0; ch<2; ++ch)
          for (int ky=0; ky<7; ++ky){
            const int yy = y+ky-3;
            if (yy<0||yy>=16) continue;
            for (int kx=0; kx<7; ++kx){
                const int xx = x+kx-3;
                if (xx<0||xx>=16) continue;
                sacc += sf[ch*256 + yy*16 + xx]*wl[ch*49 + ky*7 + kx];
            }
          }
        sa_l[t] = sigm(sacc);
    }
    __syncthreads();
    {
        const int q = t & 63;
        const int cb = t >> 6;
        const float m = mh_s[0], istd = mh_s[1];
        const float4* fb4 = (const float4*)fbr;
        const float4* lg4 = (const float4*)lng;
        const float4* lb4 = (const float4*)lnb;
        float4* res4 = (float4*)(res + (size_t)img*16384);
        float*  qnb  = qn + (size_t)img*16384;
        const bool isq = (img < 64);       // block-uniform branch
        const float sa0=sa_l[4*q], sa1=sa_l[4*q+1], sa2=sa_l[4*q+2], sa3=sa_l[4*q+3];
#pragma unroll 4
        for (int cc=0; cc<16; ++cc){
            const int c = cb*16 + cc;
            const int i4 = c*64 + q;
            const float4 mv = *(const float4*)&mh_l[c*256 + q*4];
            const float4 fv = fb4[i4], gv = lg4[i4], bv = lb4[i4];
            const float a = aA[c], b = aB[c], cf = ca[c];
            float4 r;
            r.x = (mv.x-m)*istd*gv.x + bv.x + lrelu(a*fv.x+b)*(2.f + sa0*cf);
            r.y = (mv.y-m)*istd*gv.y + bv.y + lrelu(a*fv.y+b)*(2.f + sa1*cf);
            r.z = (mv.z-m)*istd*gv.z + bv.z + lrelu(a*fv.z+b)*(2.f + sa2*cf);
            r.w = (mv.w-m)*istd*gv.w + bv.w + lrelu(a*fv.w+b)*(2.f + sa3*cf);
            if (isq){
                // fused Q-normalize: wave cb holds all 256 px of channel c (lane q -> px 4q..4q+3)
                float ssq = r.x*r.x + r.y*r.y + r.z*r.z + r.w*r.w;
#pragma unroll
                for (int off=32; off>0; off>>=1) ssq += __shfl_xor(ssq, off);
                const float inv = 1.f/sqrtf(ssq);
                float4 o;
                o.x=r.x*inv; o.y=r.y*inv; o.z=r.z*inv; o.w=r.w*inv;
                *(float4*)(qnb + c*256 + q*4) = o;
            } else {
                res4[i4] = r;
            }
        }
    }
}

// ---------------- covariance ----------------
__global__ __launch_bounds__(256) void covmu_k(const float* __restrict__ res, float* __restrict__ mu)
{
    __shared__ float r1[256];
    const int n = blockIdx.x, c = blockIdx.y, t = threadIdx.x;
    float s=0.f;
    for (int sh=0; sh<5; ++sh)
        s += res[((size_t)(64 + n*5 + sh)*64 + c)*256 + t];
    r1[t]=s; __syncthreads();
    for (int st=128;st>0;st>>=1){ if(t<st) r1[t]+=r1[t+st]; __syncthreads(); }
    if (t==0) mu[n*64+c] = r1[0]/1280.f;
}

__global__ __launch_bounds__(256) void cov_k(const float* __restrict__ res, const float* __restrict__ mu,
                                             float* __restrict__ cov)
{
    __shared__ float Xl[64*129];   // 33 KB
    const int n = blockIdx.x, by = blockIdx.y, sh = blockIdx.z, t = threadIdx.x;
    const int c = by*16 + (t>>4);
    const int d0 = (t&15)*4;
    float acc[4] = {0.f,0.f,0.f,0.f};
    for (int half=0; half<2; ++half){
        __syncthreads();
        for (int idx=t; idx<8192; idx+=256){
            const int ch = idx>>7, p = idx&127;
            Xl[ch*129+p] = res[((size_t)(64+n*5+sh)*64 + ch)*256 + half*128 + p] - mu[n*64+ch];
        }
        __syncthreads();
        for (int p=0;p<128;p++){
            const float xc = Xl[c*129+p];
#pragma unroll
            for (int k=0;k<4;k++) acc[k] += xc*Xl[(d0+k)*129+p];
        }
    }
#pragma unroll
    for (int k=0;k<4;k++) atomicAdd(&cov[((size_t)n*64 + c)*64 + d0+k], acc[k]*(1.f/1279.f));
}

// ---------------- sim[b,j,i] = Qn(:,i)^T cov_j Qn(:,i) ----------------
__global__ __launch_bounds__(256) void sim_k(const float* __restrict__ qn, const float* __restrict__ cov,
                                             float* __restrict__ sim)
{
    __shared__ float covj[64*65];
    __shared__ float Vl[64*68];
    __shared__ float simred[320];
    const int b = blockIdx.x, iq = blockIdx.y, t = threadIdx.x;
    const int i0g = iq*64;
    for (int idx=t; idx<4096; idx+=256){
        const int c = idx>>6, il = idx&63;
        Vl[c*68+il] = qn[((size_t)b*64+c)*256 + i0g + il];
    }
    for (int idx=t; idx<320; idx+=256) simred[idx]=0.f;
    const int c0 = (t>>4)*4, i0 = (t&15)*4;
    for (int j=0;j<5;j++){
        __syncthreads();
        for (int idx=t; idx<4096; idx+=256)
            covj[(idx>>6)*65 + (idx&63)] = cov[(size_t)j*4096 + idx];
        __syncthreads();
        float pt[4][4];
#pragma unroll
        for (int a=0;a<4;a++)
#pragma unroll
          for (int bb=0;bb<4;bb++) pt[a][bb]=0.f;
        for (int d=0; d<64; ++d){
            const float4 vv = *(const float4*)&Vl[d*68 + i0];
            float cw[4];
#pragma unroll
            for (int cc=0;cc<4;cc++) cw[cc] = covj[(c0+cc)*65 + d];
#pragma unroll
            for (int cc=0;cc<4;cc++){
                pt[cc][0] += cw[cc]*vv.x;
                pt[cc][1] += cw[cc]*vv.y;
                pt[cc][2] += cw[cc]*vv.z;
                pt[cc][3] += cw[cc]*vv.w;
            }
        }
#pragma unroll
        for (int ii=0;ii<4;ii++){
            float s = 0.f;
#pragma unroll
            for (int cc=0;cc<4;cc++) s += pt[cc][ii]*Vl[(c0+cc)*68 + i0+ii];
            atomicAdd(&simred[j*64 + i0 + ii], s);
        }
    }
    __syncthreads();
    for (int idx=t; idx<320; idx+=256){
        const int j = idx>>6, il = idx&63;
        sim[((size_t)b*5 + j)*256 + i0g + il] = simred[idx];
    }
}

// ---------------- classifier ----------------
__global__ __launch_bounds__(256) void cls_k(const float* __restrict__ sim, const float* __restrict__ cw,
                                             float* __restrict__ out)
{
    __shared__ float red[256];
    const int b = blockIdx.x, t = threadIdx.x;
    const float w = cw[t];
    for (int j=0;j<5;j++){
        const float v = sim[((size_t)b*5 + j)*256 + t];
        red[t] = lrelu(v)*w;
        __syncthreads();
        for (int st=128;st>0;st>>=1){ if(t<st) red[t]+=red[t+st]; __syncthreads(); }
        if (t==0) out[b*5+j] = red[0];
        __syncthreads();
    }
}

// ---------------- launch ----------------
extern "C" void kernel_launch(void* const* d_in, const int* in_sizes, int n_in,
                              void* d_out, int out_size, void* d_ws, size_t ws_size,
                              hipStream_t stream)
{
    const float* IN[31];
    for (int i=0;i<31;i++) IN[i] = (const float*)d_in[i];
    float* W = (float*)d_ws;
    float* OUT = (float*)d_out;
    const unsigned short* WHp  = (const unsigned short*)(W + OFF_WH);
    const unsigned short* WLp  = (const unsigned short*)(W + OFF_WL);
    const unsigned short* WH3p = (const unsigned short*)(W + OFF_WH3);
    const unsigned short* WL3p = (const unsigned short*)(W + OFF_WL3);
    const unsigned short* WH4p = (const unsigned short*)(W + OFF_WH4);
    const unsigned short* WL4p = (const unsigned short*)(W + OFF_WL4);
    unsigned short* P1P = (unsigned short*)(W + OFF_P1);
    unsigned short* P2P = (unsigned short*)(W + OFF_P2);
    unsigned short* C3P = (unsigned short*)(W + OFF_C3P);

    prep_k<<<8074,256,0,stream>>>(IN[0],IN[1],IN[20],IN[21],IN[14],IN[16],IN[18],
                                  IN[5],IN[8],IN[11],W);

    // stage 1: conv1 stats-only -> fused recompute+BN+pool -> packed hi/lo bf16, channel-last
    conv3x3_k<64,64,1,1,4,4,false,false><<<dim3(89,16),256,0,stream>>>(W+OFF_X0, IN[2], nullptr, W+OFF_STATS, nullptr,nullptr,nullptr,0);
    bnpoolconv1_k<<<dim3(89,8),256,0,stream>>>(W+OFF_X0, IN[2], W+OFF_STATS, IN[3], IN[4], P1P);

    // stage 2: MFMA conv2 (XCD-chunked swizzle for halo L2 reuse) -> per-image reduce -> pack
    conv2mfma_k<<<1424,256,0,stream>>>(P1P, WHp, WLp, W+OFF_PMM, W+OFF_PBS);
    bnred_k<<<89,128,0,stream>>>(W+OFF_PBS, W+OFF_S2);
    bnpool_pack_k<<<dim3(89,2),256,0,stream>>>(W+OFF_PMM, W+OFF_S2, IN[6], IN[7], P2P);

    // stage 3: MFMA conv3 (+8-slot BN3 stats, XCD swizzle) -> raw C3; then BN3+lrelu pack
    conv16mfma_k<<<356,256,0,stream>>>(P2P, WH3p, WL3p, W+OFF_C3, W+OFF_S3);
    c3pack_k<<<dim3(89,2),256,0,stream>>>(W+OFF_C3, W+OFF_S3, IN[9], IN[10], C3P);

    // stage 4: MFMA conv4 (+8-slot BN4 stats, XCD swizzle) -> raw C4
    conv16mfma_k<<<356,256,0,stream>>>(C3P, WH4p, WL4p, W+OFF_C4, W+OFF_S4);

    // MHSA (BN4 8-slot inline in proj); attention partials (4 j-chunks); merge fused into post_k
    proj_k<<<dim3(89,3),256,0,stream>>>(W+OFF_C4, W+OFF_WQT, IN[15], IN[17], IN[19],
                                        W+OFF_S4, IN[12], IN[13], W+OFF_CKV);
    attnp_k<<<dim3(89,4,4),256,0,stream>>>(W+OFF_CKV, W+OFF_POS, W+OFF_ATP);

    // fused partial-merge + mhsa-norm + CBAM + residual + Q-normalize
    post_k<<<89,256,0,stream>>>(W+OFF_ATP, IN[22], IN[23], W+OFF_C4,
                                W+OFF_S4, IN[12], IN[13],
                                IN[24], IN[25], IN[26], IN[27], IN[28], IN[29],
                                W+OFF_RES, W+OFF_QN);

    // covariance metric + classifier
    covmu_k<<<dim3(5,64),256,0,stream>>>(W+OFF_RES, W+OFF_MU);
    cov_k<<<dim3(5,4,5),256,0,stream>>>(W+OFF_RES, W+OFF_MU, W+OFF_COV);
    sim_k<<<dim3(64,4),256,0,stream>>>(W+OFF_QN, W+OFF_COV, W+OFF_SIM);
    cls_k<<<64,256,0,stream>>>(W+OFF_SIM, IN[30], OUT);
}

// Round 14
// 443.593 us; speedup vs baseline: 1.1502x; 1.0053x over previous
//
#include <hip/hip_runtime.h>
#include <hip/hip_bf16.h>

__device__ __forceinline__ float lrelu(float x){ return x >= 0.f ? x : 0.2f*x; }
__device__ __forceinline__ float sigm(float x){ return 1.f/(1.f+__expf(-x)); }

typedef short short8 __attribute__((ext_vector_type(8)));
typedef float f32x16 __attribute__((ext_vector_type(16)));

// ---------------- workspace layout (float offsets) ----------------
static constexpr size_t OFF_X0    = 0;          // 89*4096 = 364544
static constexpr size_t OFF_POS   = 475712;     // 16384  [h][i][d]
static constexpr size_t OFF_WQT   = 492096;     // 12288  [s][c][o]
static constexpr size_t OFF_STATS = 504384;     // stage1 single-slot sums (768)
static constexpr size_t OFF_P1    = 507456;     // P1PACK: 89*34*34*128 ushorts (ends 7,092,032)
static constexpr size_t OFF_P2    = 7092224;    // P2PACK: 89*18*18*128 ushorts (ends 8,937,728)
static constexpr size_t OFF_S3    = 8937728;    // BN3 sums: 8 slots * 768
static constexpr size_t OFF_S4    = 8943872;    // BN4 sums: 8 slots * 768
static constexpr size_t OFF_WH3   = 8950016;    // conv3 w hi  [9][och][cin]  (36864 ushorts)
static constexpr size_t OFF_WL3   = 8968448;
static constexpr size_t OFF_WH4   = 8986880;
static constexpr size_t OFF_WL4   = 9005312;    // ends 9,023,744
static constexpr size_t OFF_PBS   = 9023744;    // conv2 per-block stats [1424 slots][64 och][2] = 182,272
static constexpr size_t OFF_S2    = 9206016;    // BN2 group sums: 768 (atomic-accum, zeroed in prep)
static constexpr size_t OFF_RES   = 10714688;   // 89*64*256 (only imgs 64+ written/read)
static constexpr size_t OFF_MU    = 12172864;   // 320
static constexpr size_t OFF_COV   = 12173184;   // 5*64*64 (atomic-accumulated, zeroed in prep)
static constexpr size_t OFF_SIM   = 12193664;   // 64*5*256
static constexpr size_t OFF_R1    = 12275584;   // big overlaid region
static constexpr size_t OFF_PMM   = OFF_R1;                 // 89*64*16*32 pooled {16max|16min}
static constexpr size_t OFF_ATP   = OFF_R1;                 // attn partials (PMM dead by then)
static constexpr size_t OFF_C3    = OFF_R1 + 5832704;       // 89*64*256 (raw conv3)
static constexpr size_t OFF_C4    = OFF_R1 + 8749056;       // 89*64*256 (raw conv4)
static constexpr size_t OFF_CKV   = OFF_R1 + 10207232;      // 89*4*256*48 (packed {k,q,v})
static constexpr size_t OFF_C3P   = OFF_R1 + 10207232;      // C3PACK overlays CKV (dead until proj)
static constexpr size_t OFF_QN    = OFF_R1 + 17543680;      // 64*64*256 (written by post_k)
static constexpr size_t OFF_WH    = OFF_R1 + 21737984;      // conv2 w hi [9][och][cin]
static constexpr size_t OFF_WL    = OFF_WH + 18432;         // conv2 w lo

__device__ __forceinline__ int bn_group(int img){ return (img < 64) ? 0 : (1 + (img-64)/5); }

__device__ __forceinline__ void bn_ab(const float* __restrict__ sums, int g, int c, float n,
                                      float gw, float bw, float& a, float& b)
{
    const float sum = sums[(g*64+c)*2], ss = sums[(g*64+c)*2+1];
    const float m = sum/n;
    const float var = fmaxf(ss/n - m*m, 0.f);
    const float istd = 1.f/sqrtf(var + 1e-5f);
    a = gw*istd;
    b = bw - m*a;
}

// 8-slot variant (slots stride 768): BN3/BN4 accumulated by conv16mfma_k
__device__ __forceinline__ void bn_ab_s8(const float* __restrict__ sums, int g, int c, float n,
                                         float gw, float bw, float& a, float& b)
{
    float sum = 0.f, ss = 0.f;
#pragma unroll
    for (int s=0;s<8;s++){
        sum += sums[s*768 + (g*64+c)*2];
        ss  += sums[s*768 + (g*64+c)*2 + 1];
    }
    const float m = sum/n;
    const float var = fmaxf(ss/n - m*m, 0.f);
    const float istd = 1.f/sqrtf(var + 1e-5f);
    a = gw*istd;
    b = bw - m*a;
}

// chunked bijective b -> w maps (round-robin XCD = b%8); N = 8*q + r
__device__ __forceinline__ int xcd_map(int b, int q, int r)
{
    const int x = b & 7, pos = b >> 3;
    return (x < r ? x*(q+1) : r*(q+1) + (x-r)*q) + pos;
}

// ---------------- prep ----------------
__global__ __launch_bounds__(256) void prep_k(const float* __restrict__ in1, const float* __restrict__ in2,
        const float* __restrict__ relh, const float* __restrict__ relw,
        const float* __restrict__ wq, const float* __restrict__ wk, const float* __restrict__ wv,
        const float* __restrict__ cw2, const float* __restrict__ cw3, const float* __restrict__ cw4,
        float* __restrict__ ws)
{
    int idx = blockIdx.x*256 + threadIdx.x;
    if (idx < 364544) { ws[OFF_X0+idx] = (idx < 262144 ? in1[idx] : in2[idx-262144]); return; }
    idx -= 364544;
    if (idx < 16384) {
        const int h = idx>>12, r = idx&4095, i = r>>4, d = r&15;
        ws[OFF_POS+idx] = relh[h*256 + d*16 + (i&15)] + relw[h*256 + d*16 + (i>>4)];
        return;
    }
    idx -= 16384;
    if (idx < 12288) {
        const int s = idx/4096, r = idx%4096, c = r>>6, o = r&63;
        const float* wp = (s==0)?wq:((s==1)?wk:wv);
        ws[OFF_WQT+idx] = wp[o*64 + c];   // [s][c][o] = W[o][c]
        return;
    }
    idx -= 12288;
    if (idx < 3072) { ws[OFF_STATS+idx] = 0.f; return; }   // stage1 sums
    idx -= 3072;
    if (idx < 20480) { ws[OFF_COV+idx] = 0.f; return; }    // zero cov
    idx -= 20480;
    if (idx < 12288) { ws[OFF_S3+idx] = 0.f; return; }     // BN3 + BN4 8-slot sums (contiguous)
    idx -= 12288;
    if (idx < 768) { ws[OFF_S2+idx] = 0.f; return; }       // BN2 sums (atomic-accumulated by bnred_k)
    idx -= 768;
    if (idx < 110592) {                                    // conv2/3/4 weights -> bf16 hi/lo [k9][och][cin]
        const int which = idx / 36864, r0 = idx - which*36864;
        const int och = r0/576, rr = r0%576, cin = rr/9, k9 = rr%9;
        const float* cwp = (which==0)?cw2:((which==1)?cw3:cw4);
        const float v = cwp[r0];
        __hip_bfloat16 hb = __float2bfloat16(v);
        const float hv = __bfloat162float(hb);
        __hip_bfloat16 lb = __float2bfloat16(v - hv);
        const size_t oh = (which==0)?OFF_WH:((which==1)?OFF_WH3:OFF_WH4);
        const size_t ol = (which==0)?OFF_WL:((which==1)?OFF_WL3:OFF_WL4);
        unsigned short* WH = (unsigned short*)(ws + oh);
        unsigned short* WL = (unsigned short*)(ws + ol);
        const int d = k9*4096 + och*64 + cin;
        WH[d] = *(unsigned short*)&hb;
        WL[d] = *(unsigned short*)&lb;
        return;
    }
    idx -= 110592;
    if (idx < 751872) {                                    // zero P1PACK halo: 89 imgs * 132 pos * 64 floats
        const int img = idx/8448, r = idx%8448;
        const int pos = r>>6, d = r&63;
        int ypad, xpad;
        if (pos < 68){ ypad = (pos<34)?0:33; xpad = (pos<34)?pos:(pos-34); }
        else { const int q = pos-68; ypad = 1 + (q>>1); xpad = (q&1)*33; }
        ws[OFF_P1 + (((size_t)img*34 + ypad)*34 + xpad)*64 + d] = 0.f;
        return;
    }
    idx -= 751872;
    if (idx < 387328) {                                    // zero P2PACK halo: 89 imgs * 68 pos * 64 floats
        const int img = idx/4352, r = idx%4352;
        const int pos = r>>6, d = r&63;
        int ypad, xpad;
        if (pos < 36){ ypad = (pos<18)?0:17; xpad = (pos<18)?pos:(pos-18); }
        else { const int q = pos-36; ypad = 1 + (q>>1); xpad = (q&1)*17; }
        ws[OFF_P2 + (((size_t)img*18 + ypad)*18 + xpad)*64 + d] = 0.f;
        return;
    }
    idx -= 387328;
    if (idx < 387328) {                                    // zero C3PACK halo
        const int img = idx/4352, r = idx%4352;
        const int pos = r>>6, d = r&63;
        int ypad, xpad;
        if (pos < 36){ ypad = (pos<18)?0:17; xpad = (pos<18)?pos:(pos-18); }
        else { const int q = pos-36; ypad = 1 + (q>>1); xpad = (q&1)*17; }
        ws[OFF_C3P + (((size_t)img*18 + ypad)*18 + xpad)*64 + d] = 0.f;
    }
}

// ---------------- direct 3x3 conv (fp32) — conv1 stats only; XCD-chunked when SWZ --------------
template<int H, int W, int CIN, int CH, int OCB, int PT, bool STORE, bool INBN, bool SWZ>
__global__ __launch_bounds__(256) void conv3x3_k(const float* __restrict__ in,
                                                 const float* __restrict__ wt,
                                                 float* __restrict__ out,
                                                 float* __restrict__ bnsum,
                                                 const float* __restrict__ isums,
                                                 const float* __restrict__ igw,
                                                 const float* __restrict__ ibw,
                                                 int ihw)
{
    constexpr int P = W + 1;
    constexpr int PLANE = H * P;
    constexpr int HW = H * W;
    constexpr int PASSES = HW / (256 * PT);
    constexpr int NLD = CH * HW / 256;
    __shared__ float lds[CH * PLANE];
    __shared__ float redS[OCB*4], redQ[OCB*4];
    __shared__ float abA[64], abB[64];
    int img, och0;
    if constexpr (SWZ) {
        // grid 1424 = 8*178; w = img*16 + ochblk -> all 16 och-blocks of an img on one XCD
        const int b = blockIdx.x;
        const int w = (b & 7)*178 + (b >> 3);
        img = w >> 4; och0 = (w & 15)*OCB;
    } else {
        img = blockIdx.x; och0 = blockIdx.y*OCB;
    }
    const int t = threadIdx.x;

    if constexpr (INBN) {
        if (t < CIN) {
            const int gi = bn_group(img);
            const float nin = (float)(((gi==0)?64:5) * ihw);
            float a, b;
            bn_ab(isums, gi, t, nin, igw[t], ibw[t], a, b);
            abA[t]=a; abB[t]=b;
        }
        __syncthreads();
    }

    float acc[PASSES][OCB][PT];
#pragma unroll
    for (int a=0;a<PASSES;a++)
#pragma unroll
      for (int o=0;o<OCB;o++)
#pragma unroll
        for (int p=0;p<PT;p++) acc[a][o][p]=0.f;

    for (int idx = t; idx < CH*HW; idx += 256) {
        const int c = idx / HW, p = idx % HW;
        float v = in[((size_t)img*CIN + c)*HW + p];
        if constexpr (INBN) v = lrelu(abA[c]*v + abB[c]);
        lds[c*PLANE + (p/W)*P + (p%W)] = v;
    }
    __syncthreads();

    for (int cc0 = 0; cc0 < CIN; cc0 += CH) {
        float pre[(CIN > CH) ? NLD : 1];
        if constexpr (CIN > CH) {
            if (cc0 + CH < CIN) {
#pragma unroll
                for (int j=0;j<NLD;j++){
                    const int idx = j*256 + t;
                    const int c = idx / HW, p = idx % HW;
                    pre[j] = in[((size_t)img*CIN + cc0 + CH + c)*HW + p];
                }
            }
        }
        for (int c = 0; c < CH; ++c) {
            float wr[OCB][9];
#pragma unroll
            for (int o=0;o<OCB;o++)
#pragma unroll
              for (int k=0;k<9;k++)
                wr[o][k] = wt[((size_t)(och0+o)*CIN + (cc0+c))*9 + k];
            const float* Lc = lds + c*PLANE;
#pragma unroll
            for (int ps=0; ps<PASSES; ++ps) {
                const int px0 = (ps*256 + t)*PT;
                const int y = px0 / W, x0 = px0 % W;
#pragma unroll
                for (int ky=0; ky<3; ++ky) {
                    const int yy = y + ky - 1;
                    if (yy >= 0 && yy < H) {
                        const float* Lr = Lc + yy*P;
                        float r[PT+2];
                        r[0] = (x0 > 0) ? Lr[x0-1] : 0.f;
#pragma unroll
                        for (int k2=0;k2<PT;k2++) r[k2+1] = Lr[x0+k2];
                        r[PT+1] = (x0+PT < W) ? Lr[x0+PT] : 0.f;
#pragma unroll
                        for (int p=0;p<PT;p++)
#pragma unroll
                          for (int kx=0;kx<3;kx++) {
                              const float v = r[p+kx];
#pragma unroll
                              for (int o=0;o<OCB;o++)
                                  acc[ps][o][p] += v * wr[o][ky*3+kx];
                          }
                    }
                }
            }
        }
        if constexpr (CIN > CH) {
            if (cc0 + CH < CIN) {
                __syncthreads();
#pragma unroll
                for (int j=0;j<NLD;j++){
                    const int idx = j*256 + t;
                    const int c = idx / HW, p = idx % HW;
                    float v = pre[j];
                    if constexpr (INBN) v = lrelu(abA[cc0+CH+c]*v + abB[cc0+CH+c]);
                    lds[c*PLANE + (p/W)*P + (p%W)] = v;
                }
                __syncthreads();
            }
        }
    }
    if constexpr (STORE) {
#pragma unroll
        for (int ps=0; ps<PASSES; ++ps) {
            const int px0 = (ps*256 + t)*PT;
#pragma unroll
            for (int o=0;o<OCB;o++)
#pragma unroll
              for (int p=0;p<PT;p++)
                out[((size_t)img*64 + och0+o)*HW + px0 + p] = acc[ps][o][p];
        }
    }
    const int g = bn_group(img);
    const int wv = t >> 6;
#pragma unroll
    for (int o=0;o<OCB;o++){
        float s=0.f, ss=0.f;
#pragma unroll
        for (int ps=0;ps<PASSES;ps++)
#pragma unroll
          for (int p=0;p<PT;p++){ const float v=acc[ps][o][p]; s+=v; ss+=v*v; }
#pragma unroll
        for (int off=32; off>0; off>>=1){ s += __shfl_xor(s, off); ss += __shfl_xor(ss, off); }
        if ((t&63)==0){ redS[o*4+wv]=s; redQ[o*4+wv]=ss; }
    }
    __syncthreads();
    if (t < OCB*2){
        const int o = t>>1, metric = t&1;
        const float v = metric ? (redQ[o*4]+redQ[o*4+1]+redQ[o*4+2]+redQ[o*4+3])
                               : (redS[o*4]+redS[o*4+1]+redS[o*4+2]+redS[o*4+3]);
        atomicAdd(&bnsum[(g*64 + och0+o)*2 + metric], v);
    }
}

// ---------------- stage 1 fused: conv1+BN+lrelu+2x2 maxpool -> P1PACK (XCD-chunked) -------------
__global__ __launch_bounds__(256) void bnpoolconv1_k(const float* __restrict__ x0,
        const float* __restrict__ cw, const float* __restrict__ sums,
        const float* __restrict__ gw, const float* __restrict__ bw,
        unsigned short* __restrict__ p1p)
{
    __shared__ float xl[10*64];
    __shared__ float wsm[576];
    __shared__ float aAs[64], aBs[64];
    // grid 712 = 8*89; w = img*8 + band -> all bands of an img on one XCD (x0 warm from conv1-stats)
    const int bb = blockIdx.x;
    const int w = (bb & 7)*89 + (bb >> 3);
    const int img = w >> 3, band = w & 7;
    const int t = threadIdx.x;
    const int oy0 = band*4;
    const float* xp = x0 + (size_t)img*4096;
    for (int idx=t; idx<640; idx+=256){
        const int iy = idx>>6, ix = idx&63;
        const int gy = 2*oy0 - 1 + iy;
        xl[idx] = (gy>=0 && gy<64) ? xp[gy*64+ix] : 0.f;
    }
    const int g = bn_group(img);
    if (t < 64){
        const float n = (float)(((g==0)?64:5) * 4096);
        float a, b;
        bn_ab(sums, g, t, n, gw[t], bw[t], a, b);
        aAs[t]=a; aBs[t]=b;
    }
    for (int idx=t; idx<576; idx+=256) wsm[idx] = cw[idx];
    __syncthreads();
    const int p = t>>1, half = t&1;
    const int ly = p>>5, ox = p&31;
    float r[4][4];
#pragma unroll
    for (int dy=0;dy<4;dy++){
        const float* Lr = xl + (2*ly+dy)*64;
#pragma unroll
        for (int dx=0;dx<4;dx++){
            const int xx = 2*ox-1+dx;
            r[dy][dx] = (xx>=0 && xx<64) ? Lr[xx] : 0.f;
        }
    }
    short8 hv[4], lv[4];
#pragma unroll
    for (int o=0;o<32;o++){
        const int och = half*32 + o;
        float w9[9];
#pragma unroll
        for (int k=0;k<9;k++) w9[k] = wsm[och*9+k];   // LDS broadcast (2 addrs/wave)
        const float a = aAs[och], b = aBs[och];
        float best = -1e30f;
#pragma unroll
        for (int sy=0;sy<2;sy++)
#pragma unroll
          for (int sx=0;sx<2;sx++){
            float s=0.f;
#pragma unroll
            for (int ky=0;ky<3;ky++)
#pragma unroll
              for (int kx=0;kx<3;kx++) s += r[sy+ky][sx+kx]*w9[ky*3+kx];
            best = fmaxf(best, lrelu(a*s+b));
          }
        __hip_bfloat16 hb = __float2bfloat16(best);
        const float hf = __bfloat162float(hb);
        __hip_bfloat16 lb = __float2bfloat16(best - hf);
        hv[o>>3][o&7] = (short)*(unsigned short*)&hb;
        lv[o>>3][o&7] = (short)*(unsigned short*)&lb;
    }
    const size_t base = ((((size_t)img*34 + (oy0+ly) + 1)*34) + ox + 1)*128 + half*32;
#pragma unroll
    for (int j=0;j<4;j++){
        *(short8*)(p1p + base + j*8)      = hv[j];
        *(short8*)(p1p + base + 64 + j*8) = lv[j];
    }
}

// ---------------- conv2 via MFMA — 1D grid + XCD-chunked swizzle for halo L2 reuse --------------
__global__ __launch_bounds__(256) void conv2mfma_k(const unsigned short* __restrict__ p1p,
        const unsigned short* __restrict__ whi, const unsigned short* __restrict__ wlo,
        float* __restrict__ pmm, float* __restrict__ pbs)
{
    __shared__ __align__(16) unsigned short Bx[136*128];   // 34,816 B -> 4 blocks/CU
    const int b = blockIdx.x;
    const int w = (b & 7)*178 + (b >> 3);
    const int img = w >> 4, rowblk = w & 15;               // rowblk 0..15 -> 2 rows = 1 pooled row
    const int t = threadIdx.x;
    {
        const unsigned short* src = p1p + (((size_t)img*34 + rowblk*2)*34)*128;
        for (int idx=t; idx<2176; idx+=256){               // 136 pos * 16 chunks of 16B
            const int pos = idx>>4, sub = idx&15;
            const short8 v = *(const short8*)(src + pos*128 + sub*8);
            *(short8*)(Bx + pos*128 + ((sub ^ (pos&15))<<3)) = v;
        }
    }
    __syncthreads();
    const int lane = t & 63, wv = t >> 6;
    const int mt = wv & 1, ntp = wv >> 1;                  // 2 och-halves x 2 px-rows
    const int m = lane & 31, kg = lane >> 5;
    f32x16 accA, accB, accC;                               // 3 independent chains
#pragma unroll
    for (int r=0;r<16;r++){ accA[r]=0.f; accB[r]=0.f; accC[r]=0.f; }

#pragma unroll
    for (int ky=0; ky<3; ky++){
#pragma unroll
      for (int kx=0; kx<3; kx++){
        const int s = ky*3 + kx;
        const unsigned short* wh = whi + ((s*64 + mt*32 + m)<<6) + kg*8;
        const unsigned short* wl = wlo + ((s*64 + mt*32 + m)<<6) + kg*8;
        const int pos = (ntp+ky)*34 + m + kx;
        const int pb  = pos << 7;
        const int sw  = (pos & 15) << 3;
#pragma unroll
        for (int ch=0; ch<4; ch++){
            const int o = ch*16 + (kg<<3);
            const short8 ah = *(const short8*)(wh + ch*16);
            const short8 al = *(const short8*)(wl + ch*16);
            const short8 bh = *(const short8*)(Bx + pb + (o ^ sw));
            const short8 bl = *(const short8*)(Bx + pb + ((64 + o) ^ sw));
            accA = __builtin_amdgcn_mfma_f32_32x32x16_bf16(ah, bh, accA, 0,0,0);
            accB = __builtin_amdgcn_mfma_f32_32x32x16_bf16(al, bh, accB, 0,0,0);
            accC = __builtin_amdgcn_mfma_f32_32x32x16_bf16(ah, bl, accC, 0,0,0);
        }
      }
    }
    float fa[16];
#pragma unroll
    for (int r=0;r<16;r++) fa[r] = accA[r] + accB[r] + accC[r];

    __syncthreads();                       // all MFMA reads of Bx complete
    float* Bxf = (float*)Bx;               // [2 rows][64 och][33] = 16.9 KB
#pragma unroll
    for (int r=0; r<16; r++){
        const int och = mt*32 + (r&3) + 8*(r>>2) + 4*kg;
        Bxf[(ntp*64 + och)*33 + m] = fa[r];
    }
    __syncthreads();
    {
        const int och = t>>2, q4 = t&3;    // 64 och x 4 quads
        const int c0 = q4*8;               // 8 raw cols per quad-thread
        const float* r0 = Bxf + och*33 + c0;
        const float* r1 = Bxf + (64+och)*33 + c0;
        float4 mxv, mnv;
        float* mxp = (float*)&mxv; float* mnp = (float*)&mnv;
        float s = 0.f, q = 0.f;
#pragma unroll
        for (int k=0;k<4;k++){
            const float a0 = r0[2*k], a1 = r0[2*k+1], b0 = r1[2*k], b1 = r1[2*k+1];
            mxp[k] = fmaxf(fmaxf(a0,a1), fmaxf(b0,b1));
            mnp[k] = fminf(fminf(a0,a1), fminf(b0,b1));
            s += a0+a1+b0+b1;
            q += a0*a0+a1*a1+b0*b0+b1*b1;
        }
        float* base = pmm + (((size_t)img*64 + och)*16 + rowblk)*32;
        *(float4*)(base + q4*4)      = mxv;
        *(float4*)(base + 16 + q4*4) = mnv;
        s += __shfl_xor(s, 1); q += __shfl_xor(q, 1);
        s += __shfl_xor(s, 2); q += __shfl_xor(q, 2);
        if (q4 == 0){
            float* pb = pbs + (size_t)(img*16 + rowblk)*128 + och*2;
            pb[0] = s; pb[1] = q;
        }
    }
}

// ---------------- reduce conv2 per-block stats -> BN2 group sums (XCD-aligned with conv2) -------
__global__ __launch_bounds__(128) void bnred_k(const float* __restrict__ pbs, float* __restrict__ sums)
{
    const int img = xcd_map(blockIdx.x, 11, 1);    // 89 = 8*11+1
    const int t = threadIdx.x;                     // t<128: och=t>>1, metric=t&1
    const int och = t>>1, metric = t&1;
    const float* p = pbs + (size_t)img*16*128 + och*2 + metric;
    float s = 0.f;
#pragma unroll
    for (int rb=0; rb<16; rb++) s += p[rb*128];
    const int g = bn_group(img);
    atomicAdd(&sums[(g*64+och)*2 + metric], s);
}

// ---------------- stage-2 BN + lrelu + pooled-select -> P2PACK (XCD-aligned with conv2) ---------
__global__ __launch_bounds__(256) void bnpool_pack_k(const float* __restrict__ pmm,
        const float* __restrict__ sums, const float* __restrict__ gw, const float* __restrict__ bw,
        unsigned short* __restrict__ p2p)
{
    __shared__ float aA[64], aB[64];
    // grid 178 = 8*22+2; w = img*2 + cb
    const int w = xcd_map(blockIdx.x, 22, 2);
    const int img = w >> 1, cb = w & 1;
    const int t = threadIdx.x;
    const int g = bn_group(img);
    if (t < 64){
        const float n = (float)(((g==0)?64:5) * 1024);
        float a, b;
        bn_ab(sums, g, t, n, gw[t], bw[t], a, b);
        aA[t]=a; aB[t]=b;
    }
    __syncthreads();
    const int oy = t>>4, ox = t&15;
    short8 hv[4], lv[4];
#pragma unroll
    for (int j8=0;j8<4;j8++){
#pragma unroll
      for (int e=0;e<8;e++){
        const int j = j8*8 + e;
        const int c = cb*32 + j;
        const float a = aA[c], b = aB[c];
        const size_t o = (((size_t)img*64 + c)*16 + oy)*32 + ox + (a >= 0.f ? 0 : 16);
        const float best = lrelu(a*pmm[o] + b);
        __hip_bfloat16 hb = __float2bfloat16(best);
        const float hf = __bfloat162float(hb);
        __hip_bfloat16 lb = __float2bfloat16(best - hf);
        hv[j8][e] = (short)*(unsigned short*)&hb;
        lv[j8][e] = (short)*(unsigned short*)&lb;
      }
    }
    unsigned short* dst = p2p + (((size_t)img*18 + oy+1)*18 + ox+1)*128 + cb*32;
#pragma unroll
    for (int j=0;j<4;j++){
        *(short8*)(dst + j*8)      = hv[j];
        *(short8*)(dst + 64 + j*8) = lv[j];
    }
}

// ---------------- 16x16 64->64 3x3 conv via MFMA (conv3 & conv4), XCD-chunked swizzle -----------
__global__ __launch_bounds__(256) void conv16mfma_k(const unsigned short* __restrict__ pack,
        const unsigned short* __restrict__ whi, const unsigned short* __restrict__ wlo,
        float* __restrict__ out, float* __restrict__ bnsum)
{
    __shared__ __align__(16) unsigned short Bx[108*128];   // 27,648 B (6 padded rows x 18 cols)
    const int w = xcd_map(blockIdx.x, 44, 4);              // 356 = 8*44+4
    const int img = w >> 2, rowblk = w & 3;                // rowblk 0..3 -> 4 output rows
    const int t = threadIdx.x;
    {
        const unsigned short* src = pack + (((size_t)img*18 + rowblk*4)*18)*128;
        for (int idx=t; idx<1728; idx+=256){
            const int pos = idx>>4, sub = idx&15;
            const short8 v = *(const short8*)(src + pos*128 + sub*8);
            *(short8*)(Bx + pos*128 + ((sub ^ (pos&15))<<3)) = v;
        }
    }
    __syncthreads();
    const int lane = t & 63, wv = t >> 6;
    const int mt = wv & 1, np = wv >> 1;
    const int m = lane & 31, kg = lane >> 5;
    f32x16 accA, accB, accC;
#pragma unroll
    for (int r=0;r<16;r++){ accA[r]=0.f; accB[r]=0.f; accC[r]=0.f; }

#pragma unroll
    for (int ky=0; ky<3; ky++){
#pragma unroll
      for (int kx=0; kx<3; kx++){
        const int s = ky*3 + kx;
        const unsigned short* wh = whi + ((s*64 + mt*32 + m)<<6) + kg*8;
        const unsigned short* wl = wlo + ((s*64 + mt*32 + m)<<6) + kg*8;
        const int pos = (np*2 + (m>>4) + ky)*18 + (m&15) + kx;
        const int pb  = pos << 7;
        const int sw  = (pos & 15) << 3;
#pragma unroll
        for (int ch=0; ch<4; ch++){
            const int o = ch*16 + (kg<<3);
            const short8 ah = *(const short8*)(wh + ch*16);
            const short8 al = *(const short8*)(wl + ch*16);
            const short8 bh = *(const short8*)(Bx + pb + (o ^ sw));
            const short8 bl = *(const short8*)(Bx + pb + ((64 + o) ^ sw));
            accA = __builtin_amdgcn_mfma_f32_32x32x16_bf16(ah, bh, accA, 0,0,0);
            accB = __builtin_amdgcn_mfma_f32_32x32x16_bf16(al, bh, accB, 0,0,0);
            accC = __builtin_amdgcn_mfma_f32_32x32x16_bf16(ah, bl, accC, 0,0,0);
        }
      }
    }
    float* co = out + (size_t)img*16384 + rowblk*64 + np*32 + m;
    float fa[16];
#pragma unroll
    for (int r=0; r<16; r++){
        fa[r] = accA[r] + accB[r] + accC[r];
        const int och = mt*32 + (r&3) + 8*(r>>2) + 4*kg;
        co[(size_t)och*256] = fa[r];
    }
    const int g = bn_group(img);
    float* bs = bnsum + (rowblk*2 + np)*768;
#pragma unroll
    for (int r=0; r<16; r++){
        float sv = fa[r], qv = fa[r]*fa[r];
#pragma unroll
        for (int off=16; off>0; off>>=1){ sv += __shfl_xor(sv, off); qv += __shfl_xor(qv, off); }
        if (m == r){
            const int och = mt*32 + (r&3) + 8*(r>>2) + 4*kg;
            atomicAdd(&bs[(g*64+och)*2],   sv);
            atomicAdd(&bs[(g*64+och)*2+1], qv);
        }
    }
}

// ---------------- C3 raw + BN3 -> lrelu -> C3PACK (XCD-aligned with conv16) --------------------
__global__ __launch_bounds__(256) void c3pack_k(const float* __restrict__ c3,
        const float* __restrict__ s3, const float* __restrict__ gw, const float* __restrict__ bw,
        unsigned short* __restrict__ c3p)
{
    __shared__ float aA[64], aB[64];
    const int w = xcd_map(blockIdx.x, 22, 2);      // 178 = 8*22+2; w = img*2 + cb
    const int img = w >> 1, cb = w & 1;
    const int t = threadIdx.x;
    const int g = bn_group(img);
    if (t < 64){
        const float n = (float)(((g==0)?64:5) * 256);
        float a, b;
        bn_ab_s8(s3, g, t, n, gw[t], bw[t], a, b);
        aA[t]=a; aB[t]=b;
    }
    __syncthreads();
    const float* pim = c3 + (size_t)img*16384 + (size_t)cb*8192 + t;
    short8 hv[4], lv[4];
#pragma unroll
    for (int j8=0;j8<4;j8++){
#pragma unroll
      for (int e=0;e<8;e++){
        const int j = j8*8 + e;
        const int c = cb*32 + j;
        const float v = lrelu(aA[c]*pim[(size_t)j*256] + aB[c]);
        __hip_bfloat16 hb = __float2bfloat16(v);
        const float hf = __bfloat162float(hb);
        __hip_bfloat16 lb = __float2bfloat16(v - hf);
        hv[j8][e] = (short)*(unsigned short*)&hb;
        lv[j8][e] = (short)*(unsigned short*)&lb;
      }
    }
    const int oy = t>>4, ox = t&15;
    unsigned short* dst = c3p + (((size_t)img*18 + oy+1)*18 + ox+1)*128 + cb*32;
#pragma unroll
    for (int j=0;j<4;j++){
        *(short8*)(dst + j*8)      = hv[j];
        *(short8*)(dst + 64 + j*8) = lv[j];
    }
}

// ---------------- MHSA projection (XCD-aligned with conv16's C4) -------------------------------
__global__ __launch_bounds__(256) void proj_k(const float* __restrict__ c4, const float* __restrict__ wT,
               const float* __restrict__ bq, const float* __restrict__ bk, const float* __restrict__ bv,
               const float* __restrict__ sums4, const float* __restrict__ gw4, const float* __restrict__ bw4,
               float* __restrict__ ckv)
{
    __shared__ float xl[64*256];   // 64 KB exactly
    const int w = xcd_map(blockIdx.x, 33, 3);      // 267 = 8*33+3; w = img*3 + s
    const int img = w / 3, s = w - img*3;
    const int t = threadIdx.x;
    const int gi = bn_group(img);
    const float nin = (float)(((gi==0)?64:5) * 256);
    {
        const float4* in4 = (const float4*)(c4 + (size_t)img*16384);
        float4* xl4 = (float4*)xl;
        for (int i=t; i<4096; i+=256){
            float4 v = in4[i];
            const int c = i>>6;     // wave-uniform
            float a, b;
            bn_ab_s8(sums4, gi, c, nin, gw4[c], bw4[c], a, b);
            v.x=lrelu(a*v.x+b); v.y=lrelu(a*v.y+b); v.z=lrelu(a*v.z+b); v.w=lrelu(a*v.w+b);
            xl4[i] = v;
        }
    }
    const float* bias = (s==0)?bq:((s==1)?bk:bv);
    const int sofs = (s==0)?16:((s==1)?0:32);
    const float* wp = wT + s*4096;
    const int o0 = (t>>4)*4, i0 = (t&15)*16;
    const int h = o0>>4, d0 = o0&15;
    __syncthreads();
    float acc[4][16];
    float b0[4];
#pragma unroll
    for (int o=0;o<4;o++) b0[o]=bias[o0+o];
#pragma unroll
    for (int o=0;o<4;o++)
#pragma unroll
      for (int i=0;i<16;i++) acc[o][i]=b0[o];
    for (int c=0;c<64;c++){
        const float4 w4 = *(const float4*)(wp + c*64 + o0);
        const float* xr = xl + c*256 + i0;
#pragma unroll
        for (int k=0;k<4;k++){
            const float4 x4 = *(const float4*)(xr + 4*k);
            acc[0][4*k+0]+=w4.x*x4.x; acc[0][4*k+1]+=w4.x*x4.y; acc[0][4*k+2]+=w4.x*x4.z; acc[0][4*k+3]+=w4.x*x4.w;
            acc[1][4*k+0]+=w4.y*x4.x; acc[1][4*k+1]+=w4.y*x4.y; acc[1][4*k+2]+=w4.y*x4.z; acc[1][4*k+3]+=w4.y*x4.w;
            acc[2][4*k+0]+=w4.z*x4.x; acc[2][4*k+1]+=w4.z*x4.y; acc[2][4*k+2]+=w4.z*x4.z; acc[2][4*k+3]+=w4.z*x4.w;
            acc[3][4*k+0]+=w4.w*x4.x; acc[3][4*k+1]+=w4.w*x4.y; acc[3][4*k+2]+=w4.w*x4.z; acc[3][4*k+3]+=w4.w*x4.w;
        }
    }
#pragma unroll
    for (int ii=0;ii<16;ii++){
        const float4 v = make_float4(acc[0][ii],acc[1][ii],acc[2][ii],acc[3][ii]);
        *(float4*)(ckv + (((size_t)img*4 + h)*256 + i0+ii)*48 + sofs + d0) = v;
    }
}

// ---------------- attention partial: j-chunk flash pass (XCD-aligned with proj's ckv) -----------
__global__ __launch_bounds__(256) void attnp_k(const float* __restrict__ ckv, const float* __restrict__ pos,
                               float* __restrict__ part)
{
    const int b = blockIdx.x;                      // grid 1424 = 8*178
    const int w = (b & 7)*178 + (b >> 3);
    const int img = w >> 4, h = (w >> 2) & 3, jc = w & 3;
    const int i = threadIdx.x;
    const size_t jb = (((size_t)img*4 + h)*256)*48;
    float areg[32];
    {
        const float* myrow = ckv + jb + (size_t)i*48;
#pragma unroll
        for (int k=0;k<4;k++) *(float4*)&areg[4*k]    = *(const float4*)(myrow + 16 + 4*k);
#pragma unroll
        for (int k=0;k<4;k++) *(float4*)&areg[16+4*k] = *(const float4*)(pos + h*4096 + i*16 + 4*k);
    }
    float mrun = -1e30f, l = 0.f;
    float accv[16];
#pragma unroll
    for (int d=0;d<16;d++) accv[d]=0.f;

    const int jend = jc*64 + 64;
    for (int j0=jc*64; j0<jend; j0+=2){
        const float* r0 = ckv + jb + (size_t)j0*48;
        const float* r1 = r0 + 48;
        float s0a=0.f, s0b=0.f, s1a=0.f, s1b=0.f;
#pragma unroll
        for (int dd=0; dd<16; ++dd){
            s0a += areg[2*dd]  *r0[2*dd];
            s0b += areg[2*dd+1]*r0[2*dd+1];
            s1a += areg[2*dd]  *r1[2*dd];
            s1b += areg[2*dd+1]*r1[2*dd+1];
        }
        const float s0 = s0a+s0b, s1 = s1a+s1b;
        const float mnew = fmaxf(mrun, fmaxf(s0,s1));
        const float al = __expf(mrun - mnew);
        const float e0 = __expf(s0 - mnew), e1 = __expf(s1 - mnew);
        mrun = mnew;
        l = l*al + e0 + e1;
        const float* v0 = r0 + 32;
        const float* v1 = r1 + 32;
#pragma unroll
        for (int d=0;d<16;d++) accv[d] = accv[d]*al + e0*v0[d] + e1*v1[d];
    }
    float* pp = part + ((((size_t)img*4 + h)*4 + jc)*18)*256;
    pp[i]       = mrun;
    pp[256 + i] = l;
#pragma unroll
    for (int d=0;d<16;d++) pp[(2+d)*256 + i] = accv[d];
}

// ---------------- fused post-attention (XCD-aligned with attnp's partials + conv16's C4) --------
__global__ __launch_bounds__(256) void post_k(const float* __restrict__ part,
        const float* __restrict__ lng, const float* __restrict__ lnb,
        const float* __restrict__ c4,
        const float* __restrict__ sums4, const float* __restrict__ gw4, const float* __restrict__ bw4,
        const float* __restrict__ w1, const float* __restrict__ b1,
        const float* __restrict__ w2, const float* __restrict__ b2,
        const float* __restrict__ sw, const float* __restrict__ sb,
        float* __restrict__ res, float* __restrict__ qn)
{
    __shared__ float mh_l[16384];          // 64 KB merged attention [c][i]
    __shared__ float r1[256], r2[256];
    __shared__ float favg[64], fmx[64], z1s[8], ca[64];
    __shared__ float sf[512];
    __shared__ float wl[98];
    __shared__ float mh_s[2];
    __shared__ float aA[64], aB[64];
    __shared__ float sa_l[256];
    const int img = xcd_map(blockIdx.x, 11, 1);    // 89 = 8*11+1
    const int t = threadIdx.x;
    const float* fbr = c4 + (size_t)img*16384;
    const float* pb_img = part + (size_t)img*73728;   // 4h * 4jc * 18 * 256

    if (t<64){
        const int gi = bn_group(img);
        const float nin = (float)(((gi==0)?64:5) * 256);
        float a, b;
        bn_ab_s8(sums4, gi, t, nin, gw4[t], bw4[t], a, b);
        aA[t]=a; aB[t]=b;
    }
    if (t<98) wl[t] = sw[t];

    // merge 4 j-chunk partials (i = t) + accumulate mean/var of merged output
    {
        float wgt[4][4], rl4[4];
#pragma unroll
        for (int h=0;h<4;h++){
            const float* pbh = pb_img + h*18432;
            float mc[4], lc[4];
#pragma unroll
            for (int c=0;c<4;c++){ mc[c] = pbh[c*4608 + t]; lc[c] = pbh[c*4608 + 256 + t]; }
            const float ms = fmaxf(fmaxf(mc[0],mc[1]), fmaxf(mc[2],mc[3]));
            float ls = 0.f;
#pragma unroll
            for (int c=0;c<4;c++){ wgt[h][c] = __expf(mc[c]-ms); ls += wgt[h][c]*lc[c]; }
            rl4[h] = 1.f/ls;
        }
        float s=0.f, ss=0.f;
#pragma unroll 4
        for (int c=0;c<64;c++){
            const int h = c>>4, d = c&15;
            const float* pa = pb_img + h*18432 + (2+d)*256 + t;
            const float v = (wgt[h][0]*pa[0] + wgt[h][1]*pa[4608]
                           + wgt[h][2]*pa[9216] + wgt[h][3]*pa[13824]) * rl4[h];
            mh_l[c*256 + t] = v;
            s += v; ss += v*v;
        }
        r1[t]=s; r2[t]=ss; __syncthreads();
        for (int st=128;st>0;st>>=1){ if(t<st){r1[t]+=r1[t+st]; r2[t]+=r2[t+st];} __syncthreads(); }
        if (t==0){
            const float m = r1[0]/16384.f;
            const float var = fmaxf(r2[0]/16384.f - m*m, 0.f);
            mh_s[0]=m; mh_s[1]=1.f/sqrtf(var+1e-5f);
        }
    }
    {
        const int c = t>>2, part4 = t&3;
        const float a = aA[c], b = aB[c];
        const float4* p4 = (const float4*)(fbr + c*256 + part4*64);
        float s=0.f, mx=-1e30f;
        for (int k=0;k<16;k++){
            const float4 v = p4[k];
            const float f0=lrelu(a*v.x+b), f1=lrelu(a*v.y+b), f2=lrelu(a*v.z+b), f3=lrelu(a*v.w+b);
            s += f0+f1+f2+f3;
            mx = fmaxf(mx, fmaxf(fmaxf(f0,f1),fmaxf(f2,f3)));
        }
        __syncthreads();
        r1[t]=s; r2[t]=mx;
        __syncthreads();
        if (t<64){
            favg[t] = (r1[t*4]+r1[t*4+1]+r1[t*4+2]+r1[t*4+3])/256.f;
            fmx[t]  = fmaxf(fmaxf(r2[t*4],r2[t*4+1]),fmaxf(r2[t*4+2],r2[t*4+3]));
        }
    }
    __syncthreads();
    if (t<8){
        const int which = t>>2, o = t&3;
        const float* f = which? fmx : favg;
        float z = b1[o];
        for (int c=0;c<64;c++) z += w1[o*64+c]*f[c];
        z1s[t] = fmaxf(z, 0.f);
    }
    __syncthreads();
    if (t<64){
        float z = 2.f*b2[t];
#pragma unroll
        for (int k=0;k<4;k++) z += w2[t*4+k]*(z1s[k]+z1s[4+k]);
        ca[t] = sigm(z);
    }
    __syncthreads();
    {
        float s=0.f, mx=-1e30f;
        for (int c=0;c<64;c++){
            const float fv = lrelu(aA[c]*fbr[c*256+t] + aB[c]);
            const float v = ca[c]*fv;
            s += v; mx = fmaxf(mx, v);
        }
        sf[t]     = s/64.f;
        sf[256+t] = mx;
    }
    __syncthreads();
    {
        float sacc = sb[0];
        const int y = t>>4, x = t&15;
        for (int ch=0; ch<2; ++ch)
          for (int ky=0; ky<7; ++ky){
            const int yy = y+ky-3;
            if (yy<0||yy>=16) continue;
            for (int kx=0; kx<7; ++kx){
                const int xx = x+kx-3;
                if (xx<0||xx>=16) continue;
                sacc += sf[ch*256 + yy*16 + xx]*wl[ch*49 + ky*7 + kx];
            }
          }
        sa_l[t] = sigm(sacc);
    }
    __syncthreads();
    {
        const int q = t & 63;
        const int cb = t >> 6;
        const float m = mh_s[0], istd = mh_s[1];
        const float4* fb4 = (const float4*)fbr;
        const float4* lg4 = (const float4*)lng;
        const float4* lb4 = (const float4*)lnb;
        float4* res4 = (float4*)(res + (size_t)img*16384);
        float*  qnb  = qn + (size_t)img*16384;
        const bool isq = (img < 64);       // block-uniform branch
        const float sa0=sa_l[4*q], sa1=sa_l[4*q+1], sa2=sa_l[4*q+2], sa3=sa_l[4*q+3];
#pragma unroll 4
        for (int cc=0; cc<16; ++cc){
            const int c = cb*16 + cc;
            const int i4 = c*64 + q;
            const float4 mv = *(const float4*)&mh_l[c*256 + q*4];
            const float4 fv = fb4[i4], gv = lg4[i4], bv = lb4[i4];
            const float a = aA[c], b = aB[c], cf = ca[c];
            float4 r;
            r.x = (mv.x-m)*istd*gv.x + bv.x + lrelu(a*fv.x+b)*(2.f + sa0*cf);
            r.y = (mv.y-m)*istd*gv.y + bv.y + lrelu(a*fv.y+b)*(2.f + sa1*cf);
            r.z = (mv.z-m)*istd*gv.z + bv.z + lrelu(a*fv.z+b)*(2.f + sa2*cf);
            r.w = (mv.w-m)*istd*gv.w + bv.w + lrelu(a*fv.w+b)*(2.f + sa3*cf);
            if (isq){
                float ssq = r.x*r.x + r.y*r.y + r.z*r.z + r.w*r.w;
#pragma unroll
                for (int off=32; off>0; off>>=1) ssq += __shfl_xor(ssq, off);
                const float inv = 1.f/sqrtf(ssq);
                float4 o;
                o.x=r.x*inv; o.y=r.y*inv; o.z=r.z*inv; o.w=r.w*inv;
                *(float4*)(qnb + c*256 + q*4) = o;
            } else {
                res4[i4] = r;
            }
        }
    }
}

// ---------------- covariance ----------------
__global__ __launch_bounds__(256) void covmu_k(const float* __restrict__ res, float* __restrict__ mu)
{
    __shared__ float r1[256];
    const int n = blockIdx.x, c = blockIdx.y, t = threadIdx.x;
    float s=0.f;
    for (int sh=0; sh<5; ++sh)
        s += res[((size_t)(64 + n*5 + sh)*64 + c)*256 + t];
    r1[t]=s; __syncthreads();
    for (int st=128;st>0;st>>=1){ if(t<st) r1[t]+=r1[t+st]; __syncthreads(); }
    if (t==0) mu[n*64+c] = r1[0]/1280.f;
}

__global__ __launch_bounds__(256) void cov_k(const float* __restrict__ res, const float* __restrict__ mu,
                                             float* __restrict__ cov)
{
    __shared__ float Xl[64*129];   // 33 KB
    const int n = blockIdx.x, by = blockIdx.y, sh = blockIdx.z, t = threadIdx.x;
    const int c = by*16 + (t>>4);
    const int d0 = (t&15)*4;
    float acc[4] = {0.f,0.f,0.f,0.f};
    for (int half=0; half<2; ++half){
        __syncthreads();
        for (int idx=t; idx<8192; idx+=256){
            const int ch = idx>>7, p = idx&127;
            Xl[ch*129+p] = res[((size_t)(64+n*5+sh)*64 + ch)*256 + half*128 + p] - mu[n*64+ch];
        }
        __syncthreads();
        for (int p=0;p<128;p++){
            const float xc = Xl[c*129+p];
#pragma unroll
            for (int k=0;k<4;k++) acc[k] += xc*Xl[(d0+k)*129+p];
        }
    }
#pragma unroll
    for (int k=0;k<4;k++) atomicAdd(&cov[((size_t)n*64 + c)*64 + d0+k], acc[k]*(1.f/1279.f));
}

// ---------------- sim[b,j,i] = Qn(:,i)^T cov_j Qn(:,i) ----------------
__global__ __launch_bounds__(256) void sim_k(const float* __restrict__ qn, const float* __restrict__ cov,
                                             float* __restrict__ sim)
{
    __shared__ float covj[64*65];
    __shared__ float Vl[64*68];
    __shared__ float simred[320];
    const int b = blockIdx.x, iq = blockIdx.y, t = threadIdx.x;
    const int i0g = iq*64;
    for (int idx=t; idx<4096; idx+=256){
        const int c = idx>>6, il = idx&63;
        Vl[c*68+il] = qn[((size_t)b*64+c)*256 + i0g + il];
    }
    for (int idx=t; idx<320; idx+=256) simred[idx]=0.f;
    const int c0 = (t>>4)*4, i0 = (t&15)*4;
    for (int j=0;j<5;j++){
        __syncthreads();
        for (int idx=t; idx<4096; idx+=256)
            covj[(idx>>6)*65 + (idx&63)] = cov[(size_t)j*4096 + idx];
        __syncthreads();
        float pt[4][4];
#pragma unroll
        for (int a=0;a<4;a++)
#pragma unroll
          for (int bb=0;bb<4;bb++) pt[a][bb]=0.f;
        for (int d=0; d<64; ++d){
            const float4 vv = *(const float4*)&Vl[d*68 + i0];
            float cw[4];
#pragma unroll
            for (int cc=0;cc<4;cc++) cw[cc] = covj[(c0+cc)*65 + d];
#pragma unroll
            for (int cc=0;cc<4;cc++){
                pt[cc][0] += cw[cc]*vv.x;
                pt[cc][1] += cw[cc]*vv.y;
                pt[cc][2] += cw[cc]*vv.z;
                pt[cc][3] += cw[cc]*vv.w;
            }
        }
#pragma unroll
        for (int ii=0;ii<4;ii++){
            float s = 0.f;
#pragma unroll
            for (int cc=0;cc<4;cc++) s += pt[cc][ii]*Vl[(c0+cc)*68 + i0+ii];
            atomicAdd(&simred[j*64 + i0 + ii], s);
        }
    }
    __syncthreads();
    for (int idx=t; idx<320; idx+=256){
        const int j = idx>>6, il = idx&63;
        sim[((size_t)b*5 + j)*256 + i0g + il] = simred[idx];
    }
}

// ---------------- classifier ----------------
__global__ __launch_bounds__(256) void cls_k(const float* __restrict__ sim, const float* __restrict__ cw,
                                             float* __restrict__ out)
{
    __shared__ float red[256];
    const int b = blockIdx.x, t = threadIdx.x;
    const float w = cw[t];
    for (int j=0;j<5;j++){
        const float v = sim[((size_t)b*5 + j)*256 + t];
        red[t] = lrelu(v)*w;
        __syncthreads();
        for (int st=128;st>0;st>>=1){ if(t<st) red[t]+=red[t+st]; __syncthreads(); }
        if (t==0) out[b*5+j] = red[0];
        __syncthreads();
    }
}

// ---------------- launch ----------------
extern "C" void kernel_launch(void* const* d_in, const int* in_sizes, int n_in,
                              void* d_out, int out_size, void* d_ws, size_t ws_size,
                              hipStream_t stream)
{
    const float* IN[31];
    for (int i=0;i<31;i++) IN[i] = (const float*)d_in[i];
    float* W = (float*)d_ws;
    float* OUT = (float*)d_out;
    const unsigned short* WHp  = (const unsigned short*)(W + OFF_WH);
    const unsigned short* WLp  = (const unsigned short*)(W + OFF_WL);
    const unsigned short* WH3p = (const unsigned short*)(W + OFF_WH3);
    const unsigned short* WL3p = (const unsigned short*)(W + OFF_WL3);
    const unsigned short* WH4p = (const unsigned short*)(W + OFF_WH4);
    const unsigned short* WL4p = (const unsigned short*)(W + OFF_WL4);
    unsigned short* P1P = (unsigned short*)(W + OFF_P1);
    unsigned short* P2P = (unsigned short*)(W + OFF_P2);
    unsigned short* C3P = (unsigned short*)(W + OFF_C3P);

    prep_k<<<8074,256,0,stream>>>(IN[0],IN[1],IN[20],IN[21],IN[14],IN[16],IN[18],
                                  IN[5],IN[8],IN[11],W);

    // stage 1: conv1 stats (XCD-chunked: all 16 och-blks of an img on one XCD) -> fused BN+pool
    conv3x3_k<64,64,1,1,4,4,false,false,true><<<1424,256,0,stream>>>(W+OFF_X0, IN[2], nullptr, W+OFF_STATS, nullptr,nullptr,nullptr,0);
    bnpoolconv1_k<<<712,256,0,stream>>>(W+OFF_X0, IN[2], W+OFF_STATS, IN[3], IN[4], P1P);

    // stage 2: MFMA conv2 (XCD-chunked) -> per-image reduce -> pack (all XCD-aligned)
    conv2mfma_k<<<1424,256,0,stream>>>(P1P, WHp, WLp, W+OFF_PMM, W+OFF_PBS);
    bnred_k<<<89,128,0,stream>>>(W+OFF_PBS, W+OFF_S2);
    bnpool_pack_k<<<178,256,0,stream>>>(W+OFF_PMM, W+OFF_S2, IN[6], IN[7], P2P);

    // stage 3: MFMA conv3 (XCD-chunked) -> raw C3; then BN3+lrelu pack (aligned)
    conv16mfma_k<<<356,256,0,stream>>>(P2P, WH3p, WL3p, W+OFF_C3, W+OFF_S3);
    c3pack_k<<<178,256,0,stream>>>(W+OFF_C3, W+OFF_S3, IN[9], IN[10], C3P);

    // stage 4: MFMA conv4 (XCD-chunked) -> raw C4
    conv16mfma_k<<<356,256,0,stream>>>(C3P, WH4p, WL4p, W+OFF_C4, W+OFF_S4);

    // MHSA: proj (aligned with C4) -> attention partials (aligned with ckv) -> fused post (aligned)
    proj_k<<<267,256,0,stream>>>(W+OFF_C4, W+OFF_WQT, IN[15], IN[17], IN[19],
                                 W+OFF_S4, IN[12], IN[13], W+OFF_CKV);
    attnp_k<<<1424,256,0,stream>>>(W+OFF_CKV, W+OFF_POS, W+OFF_ATP);

    post_k<<<89,256,0,stream>>>(W+OFF_ATP, IN[22], IN[23], W+OFF_C4,
                                W+OFF_S4, IN[12], IN[13],
                                IN[24], IN[25], IN[26], IN[27], IN[28], IN[29],
                                W+OFF_RES, W+OFF_QN);

    // covariance metric + classifier
    covmu_k<<<dim3(5,64),256,0,stream>>>(W+OFF_RES, W+OFF_MU);
    cov_k<<<dim3(5,4,5),256,0,stream>>>(W+OFF_RES, W+OFF_MU, W+OFF_COV);
    sim_k<<<dim3(64,4),256,0,stream>>>(W+OFF_QN, W+OFF_COV, W+OFF_SIM);
    cls_k<<<64,256,0,stream>>>(W+OFF_SIM, IN[30], OUT);
}